// Round 5
// baseline (405.897 us; speedup 1.0000x reference)
//
#include <hip/hip_runtime.h>

// ---------------------------------------------------------------------------
// ChannelAttentionLayer on MI355X (gfx950). Input dtype (fp32 vs bf16) is
// DETECTED ON DEVICE (k_detect); core pipeline is FP16 MFMA + fp32 accumulate.
// R15->R16: M=32qt/wave is the proven LDS-traffic lever but KVBLK=128 made
// acc_s[2][8]=64 VGPRs -> spill (R14/R15 both pinned at 256). KVBLK=64 halves
// acc_s to 32: peak ~210 VGPRs, fits. Structure simplifies to 2 phases/tile:
// {stage V | S from lK | softmax} barrier {stage K(t+1) | PV from lV} barrier.
// Plain __syncthreads (counted vmcnt proven null R13); stages hide under the
// opposite compute phase. Q in LDS (64KB, stride 512B = bank-aligned, XOR
// swizzle -> 2-way = free). LDS 32K lK + 32K lV + 16K lP + 64K lQ = 144KB,
// 1 block/CU. Per-CU LDS traffic ~14.6MB vs R13's ~24MB. Convs = R6.
// ---------------------------------------------------------------------------

typedef unsigned short u16;
typedef _Float16 f16x8 __attribute__((ext_vector_type(8)));
typedef __attribute__((ext_vector_type(4))) float f32x4;

__device__ __forceinline__ u16 f2h(float f) {
  _Float16 h = (_Float16)f;
  return *(const u16*)&h;
}
__device__ __forceinline__ float bf2f(u16 h) {
  return __uint_as_float(((unsigned)h) << 16);
}
__device__ __forceinline__ float ldin(const void* p, size_t i, int f32) {
  return f32 ? ((const float*)p)[i] : bf2f(((const u16*)p)[i]);
}
__device__ __forceinline__ u16 f2bf(float f) {
  unsigned u = __float_as_uint(f);
  u += 0x7fffu + ((u >> 16) & 1u);
  return (u16)(u >> 16);
}
__device__ __forceinline__ void gld16(const void* g, void* l) {
  __builtin_amdgcn_global_load_lds(
      (const __attribute__((address_space(1))) unsigned int*)g,
      (__attribute__((address_space(3))) unsigned int*)l, 16, 0, 0);
}

// ---- 1) dtype detection on Wq: 2048 sampled words, 8 independent loads ----
__global__ __launch_bounds__(256) void k_detect(const unsigned* __restrict__ w,
                                                int* __restrict__ flag) {
  __shared__ int red[4];
  int tid = threadIdx.x, cnt = 0;
#pragma unroll
  for (int j = 0; j < 8; j++) {
    unsigned e = (w[tid + j * 8192] >> 7) & 0xFFu;
    cnt += (e >= 118u && e <= 127u) ? 1 : 0;
  }
#pragma unroll
  for (int off = 32; off; off >>= 1) cnt += __shfl_down(cnt, off);
  if ((tid & 63) == 0) red[tid >> 6] = cnt;
  __syncthreads();
  if (tid == 0)
    flag[0] = (red[0] + red[1] + red[2] + red[3] < 625) ? 1 : 0;  // 1 = fp32
}

// ---- 2) pad+transpose x -> fp16 [b][66*66 pix][256c], zero border ----
__global__ __launch_bounds__(256) void k_txp(const void* __restrict__ x,
                                             const int* __restrict__ flag,
                                             u16* __restrict__ xbTp) {
  __shared__ float tile[32][33];
  int f32 = flag[0];
  int b = blockIdx.z, p0 = blockIdx.x * 32, c0 = blockIdx.y * 32;
  int tx = threadIdx.x, ty = threadIdx.y;
#pragma unroll
  for (int i = 0; i < 4; i++) {
    int c = c0 + ty + i * 8, pp = p0 + tx;
    float v = 0.f;
    if (pp < 4356) {
      int yy = pp / 66, xx = pp - yy * 66;
      if (yy >= 1 && yy <= 64 && xx >= 1 && xx <= 64)
        v = ldin(x, ((size_t)b * 256 + c) * 4096 + (yy - 1) * 64 + (xx - 1), f32);
    }
    tile[ty + i * 8][tx] = v;
  }
  __syncthreads();
#pragma unroll
  for (int i = 0; i < 4; i++) {
    int pp = p0 + ty + i * 8;
    if (pp >= 4356) continue;
    xbTp[((size_t)b * 4356 + pp) * 256 + c0 + tx] = f2h(tile[tx][ty + i * 8]);
  }
}

// ---- 3) weight reorders (fp16) ----
__global__ __launch_bounds__(256) void k_wq(const void* __restrict__ Wq,
                                            const int* __restrict__ flag,
                                            u16* __restrict__ WqB) {
  int idx = blockIdx.x * 256 + threadIdx.x;  // 256*2304
  int oc = idx / 2304, rem = idx - oc * 2304;
  int tap = rem >> 8, c = rem & 255;
  WqB[idx] = f2h(ldin(Wq, oc * 2304 + c * 9 + tap, flag[0]));
}
__global__ __launch_bounds__(256) void k_wkv(const void* __restrict__ Wk,
                                             const void* __restrict__ Wv,
                                             const int* __restrict__ flag,
                                             u16* __restrict__ WkvB) {
  int idx = blockIdx.x * 256 + threadIdx.x;  // 512*256
  int m = idx >> 8, c = idx & 255;
  float w = (m < 256) ? ldin(Wk, m * 256 + c, flag[0])
                      : ldin(Wv, (m - 256) * 256 + c, flag[0]);
  WkvB[idx] = f2h(w);
}

// ---- GEMM (fp16): C[M][N] = A[M][K] . Bt[N][K]^T  (R6 1-buf structure) ----
template <bool IMC, int EPI, int SWZ>
__global__ __launch_bounds__(256, 3) void gemm_bt(
    const u16* __restrict__ A, const u16* __restrict__ Bt, void* __restrict__ Cptr,
    int M, int N, int K, int ldB, int tapBase, long long cOff, int kChunk,
    int sw1, int sw2, int nSplit, long long zA, long long zB, long long zC) {
  __shared__ u16 lA[128 * 64];
  __shared__ u16 lB[128 * 64];
  int tm, tn, b = 0, kz = 0;
  if (SWZ == 1) {
    int lin = blockIdx.x, xcd = lin & 7, per = lin >> 3;
    tm = xcd * sw1 + (per % sw1);
    tn = per / sw1;
    b = blockIdx.y;
  } else if (SWZ == 2) {
    int lin = blockIdx.x, xcd = lin & 7, per = lin >> 3;
    tm = per % sw1;
    tn = xcd * sw2 + per / sw1;
    kz = blockIdx.z;
  } else {
    tm = blockIdx.x;
    tn = blockIdx.y;
    b = blockIdx.z / nSplit;
    kz = blockIdx.z % nSplit;
  }
  int k0 = 0, k1 = K;
  if (kChunk) {
    k0 = kz * kChunk;
    k1 = min(k0 + kChunk, K);
  }
  const int tid = threadIdx.x, wave = tid >> 6, lane = tid & 63;
  const int sr = lane >> 3;         // source row within 8-row issue group
  const int scw = (lane & 7) ^ sr;  // XOR-swizzled source chunk
  const int wm = (wave >> 1) * 64, wn = (wave & 1) * 64;
  const int r16 = lane & 15, q = lane >> 4;
  const u16* gA = A + (size_t)b * zA + (size_t)(tm * 128 + wave * 32 + sr) * K +
                  scw * 8;
  const u16* gB = nullptr;
  int pyI[4], pxI[4];
  size_t bOffI[4];
  if (IMC) {
#pragma unroll
    for (int i = 0; i < 4; i++) {
      int n = tn * 128 + wave * 32 + i * 8 + sr;  // global output pixel
      int bb = n >> 12, pix = n & 4095;
      pyI[i] = pix >> 6;
      pxI[i] = pix & 63;
      bOffI[i] = (size_t)bb * 4356;
    }
  } else {
    gB = Bt + (size_t)b * zB + (size_t)(tn * 128 + wave * 32 + sr) * ldB +
         scw * 8;
  }
  f32x4 acc[4][4] = {};

  for (int kt = k0; kt < k1; kt += 64) {
    int dy = 0, dx = 0, chunk = 0;
    if (IMC) {
      int tap = tapBase + (kt >> 8);
      chunk = kt & 255;
      dy = tap / 3;
      dx = tap - dy * 3;
    }
#pragma unroll
    for (int i = 0; i < 4; i++) {
      gld16(gA + (size_t)(i * 8) * K + kt, &lA[(wave * 32 + i * 8) * 64]);
      if (IMC) {
        int spix = (pyI[i] + dy) * 66 + pxI[i] + dx;
        gld16(Bt + (bOffI[i] + spix) * 256 + chunk + scw * 8,
              &lB[(wave * 32 + i * 8) * 64]);
      } else {
        gld16(gB + (size_t)(i * 8) * ldB + kt, &lB[(wave * 32 + i * 8) * 64]);
      }
    }
    __syncthreads();
#pragma unroll
    for (int ks = 0; ks < 64; ks += 32) {
      f16x8 af[4], bfr[4];
#pragma unroll
      for (int f = 0; f < 4; f++) {
        int ma = wm + f * 16 + r16;
        int g = (ks >> 3) + q;
        af[f] = *(const f16x8*)&lA[ma * 64 + ((g ^ (ma & 7)) << 3)];
        int nb = wn + f * 16 + r16;
        bfr[f] = *(const f16x8*)&lB[nb * 64 + ((g ^ (nb & 7)) << 3)];
      }
#pragma unroll
      for (int fi = 0; fi < 4; fi++)
#pragma unroll
        for (int fj = 0; fj < 4; fj++)
          acc[fi][fj] = __builtin_amdgcn_mfma_f32_16x16x32_f16(
              af[fi], bfr[fj], acc[fi][fj], 0, 0, 0);
    }
    __syncthreads();
  }

  const int colB = tn * 128 + wn + r16;
  const int rowB = tm * 128 + wm + q * 4;
  float* C = (float*)Cptr + cOff + (size_t)b * zC;
  if (EPI == 0) {
#pragma unroll
    for (int fi = 0; fi < 4; fi++)
#pragma unroll
      for (int r = 0; r < 4; r++) {
        size_t ro = (size_t)(rowB + fi * 16 + r) * N;
#pragma unroll
        for (int fj = 0; fj < 4; fj++) C[ro + colB + fj * 16] = acc[fi][fj][r];
      }
  } else {
#pragma unroll
    for (int fi = 0; fi < 4; fi++)
#pragma unroll
      for (int r = 0; r < 4; r++) {
        size_t ro = (size_t)(rowB + fi * 16 + r) * N;
#pragma unroll
        for (int fj = 0; fj < 4; fj++)
          atomicAdd(&C[ro + colB + fj * 16], acc[fi][fj][r]);
      }
  }
}

// ---- 5) BN stats (biases cancel; K/V border conv-value 0, count 17424) ----
__global__ __launch_bounds__(256) void k_stats(
    const float* __restrict__ bufQ, const float* __restrict__ bufKV,
    const void* __restrict__ gq, const void* __restrict__ betaq,
    const void* __restrict__ gk, const void* __restrict__ betak,
    const void* __restrict__ gv, const void* __restrict__ betav,
    const int* __restrict__ flag, float* __restrict__ nrm) {
  int f32 = flag[0];
  int ch = blockIdx.x, t = blockIdx.y, tid = threadIdx.x;
  const float* row = (t == 0) ? bufQ + (size_t)ch * 16384
                              : bufKV + (size_t)(t == 1 ? ch : 256 + ch) * 16384;
  float s = 0.f, ss = 0.f;
  for (int i = tid; i < 16384; i += 256) {
    float v = row[i];
    s += v;
    ss += v * v;
  }
#pragma unroll
  for (int off = 32; off; off >>= 1) {
    s += __shfl_down(s, off);
    ss += __shfl_down(ss, off);
  }
  __shared__ float ls[4], lss[4];
  if ((tid & 63) == 0) {
    ls[tid >> 6] = s;
    lss[tid >> 6] = ss;
  }
  __syncthreads();
  if (tid == 0) {
    s = ls[0] + ls[1] + ls[2] + ls[3];
    ss = lss[0] + lss[1] + lss[2] + lss[3];
    float cnt = (t == 0) ? 16384.f : 17424.f;
    float mean = s / cnt;
    float var = fmaxf(ss / cnt - mean * mean, 0.f);  // NaN-proof
    const void* g = (t == 0) ? gq : (t == 1 ? gk : gv);
    const void* be = (t == 0) ? betaq : (t == 1 ? betak : betav);
    float sc = ldin(g, ch, f32) * rsqrtf(var + 1e-5f);
    nrm[(t * 256 + ch) * 2] = sc;
    nrm[(t * 256 + ch) * 2 + 1] = ldin(be, ch, f32) - mean * sc;
  }
}

// ---- 6) normalize + transpose to fp16 (K=256 rows) ----
__global__ __launch_bounds__(256) void k_qTs(const float* __restrict__ bufQ,
                                             const float* __restrict__ nrm,
                                             u16* __restrict__ qTs) {
  __shared__ u16 th[32][33];
  int b = blockIdx.z, q0 = blockIdx.x * 32, c0 = blockIdx.y * 32;
  int tx = threadIdx.x, ty = threadIdx.y;
#pragma unroll
  for (int i = 0; i < 4; i++) {
    int c = c0 + ty + i * 8;
    float sc = nrm[c * 2], sh = nrm[c * 2 + 1];
    th[ty + i * 8][tx] =
        f2h(bufQ[(size_t)c * 16384 + b * 4096 + q0 + tx] * sc + sh);
  }
  __syncthreads();
#pragma unroll
  for (int i = 0; i < 4; i++)
    qTs[((size_t)b * 4096 + q0 + ty + i * 8) * 256 + c0 + tx] =
        th[tx][ty + i * 8];
}
__global__ __launch_bounds__(256) void k_kTs(const float* __restrict__ bufKV,
                                             const float* __restrict__ nrm,
                                             u16* __restrict__ kTs) {
  __shared__ u16 th[32][33];
  int b = blockIdx.z, k0 = blockIdx.x * 32, c0 = blockIdx.y * 32;
  int tx = threadIdx.x, ty = threadIdx.y;
#pragma unroll
  for (int i = 0; i < 4; i++) {
    int c = c0 + ty + i * 8;
    int kt = k0 + tx;
    float v = 0.f;
    if (kt < 4356) {
      float sc = nrm[(256 + c) * 2], sh = nrm[(256 + c) * 2 + 1];
      int yy = kt / 66, xx = kt - yy * 66;
      if (yy >= 1 && yy <= 64 && xx >= 1 && xx <= 64)
        v = bufKV[(size_t)c * 16384 + b * 4096 + (yy - 1) * 64 + (xx - 1)] * sc + sh;
      else
        v = sh;  // border: conv value 0
    }
    th[ty + i * 8][tx] = f2h(v);  // kt >= 4356 rows -> exact zeros
  }
  __syncthreads();
#pragma unroll
  for (int i = 0; i < 4; i++)
    kTs[((size_t)b * 4480 + k0 + ty + i * 8) * 256 + c0 + tx] =
        th[tx][ty + i * 8];
}

// ---- 7) normalized V fp16, [b][c][4480], pads zero ----
__global__ __launch_bounds__(256) void k_vP(const float* __restrict__ bufKV,
                                            const float* __restrict__ nrm,
                                            u16* __restrict__ vP) {
  int b = blockIdx.z, ch = blockIdx.y;
  int kt = blockIdx.x * 256 + threadIdx.x;
  if (kt >= 4480) return;
  float v = 0.f;
  if (kt < 4356) {
    float sc = nrm[(512 + ch) * 2], sh = nrm[(512 + ch) * 2 + 1];
    int yy = kt / 66, xx = kt - yy * 66;
    if (yy >= 1 && yy <= 64 && xx >= 1 && xx <= 64)
      v = bufKV[(size_t)(256 + ch) * 16384 + b * 4096 + (yy - 1) * 64 + (xx - 1)] * sc + sh;
    else
      v = sh;
  }
  vP[((size_t)b * 256 + ch) * 4480 + kt] = f2h(v);
}

// ---- 8) fused flash attention: 32 qt/wave, KVBLK=64, Q in LDS, 144KB ----
// grid 256: xcd = lin&7 -> (h = xcd&1, b = xcd>>1); per = lin>>3 -> qt0.
// Block = 128 qt x 256 c, 4 waves x 32 qt (fi=2 strips of 16). Per kt-tile
// (64 keys): phase A {stage V | S = Q.K^T from lK+lQ | softmax -> lP},
// __syncthreads, phase B {stage K(t+1) | PV from lV+lP}, __syncthreads.
// acc_s[2][4]=32 + acc_o[2][16]=128 + m/l 16 -> ~210 VGPR peak, no spill.
// All LDS tiles XOR-swizzled (chunk ^= row&7); row strides 128B/512B are
// bank-aligned so reads are 2-way max (free).
__global__ __launch_bounds__(256, 1) void k_flash(
    const u16* __restrict__ qTs, const u16* __restrict__ kTs,
    const u16* __restrict__ vP, float* __restrict__ Op,
    float* __restrict__ ml) {
  __shared__ u16 lK[64 * 256];   // 32KB K tile [kt][c]
  __shared__ u16 lV[256 * 64];   // 32KB V tile [c][kt]
  __shared__ u16 lP[128 * 64];   // 16KB P tile [qt][kt]
  __shared__ u16 lQ[128 * 256];  // 64KB Q tile [qt][c]
  const int lin = blockIdx.x;
  const int xcd = lin & 7, per = lin >> 3;
  const int h = xcd & 1, b = xcd >> 1;
  const int qt0 = per * 128;
  const int tid = threadIdx.x, wave = tid >> 6, lane = tid & 63;
  const int r16 = lane & 15, q = lane >> 4;
  const int s7 = r16 & 7;
  const int qr0 = wave * 32 + r16, qr1 = qr0 + 16;

  const int ktBeg = h ? 2304 : 0, ktEnd = h ? 4480 : 2304;
  const u16* gQb = qTs + ((size_t)b * 4096 + qt0) * 256;
  const u16* gKb = kTs + (size_t)b * 4480 * 256;
  const u16* gVb = vP + (size_t)b * 256 * 4480;

  // ---- staging macros: linear LDS dest (lane*16B), inverse-swizzled src ----
  // K tile: row kt (64), 32 c-chunks; LDS[kt][cw] = K[kt0+kt][cw ^ (kt&7)]
#define STAGE_K(kt0)                                                          \
  {                                                                           \
    _Pragma("unroll") for (int i = 0; i < 8; i++) {                           \
      int kt = (i * 4 + wave) * 2 + (lane >> 5);                              \
      int cw = lane & 31;                                                     \
      gld16(gKb + (size_t)((kt0) + kt) * 256 + ((cw ^ (kt & 7)) << 3),        \
            &lK[(i * 4 + wave) * 512]);                                       \
    }                                                                         \
  }
  // V tile: row c (256), 8 kt-chunks; LDS[c][cw] = V[c][kt0 + (cw ^ (c&7))*8]
#define STAGE_V(kt0)                                                          \
  {                                                                           \
    _Pragma("unroll") for (int i = 0; i < 8; i++) {                           \
      int c = (i * 4 + wave) * 8 + (lane >> 3);                               \
      int cw = lane & 7;                                                      \
      gld16(gVb + (size_t)c * 4480 + (kt0) + ((cw ^ (c & 7)) << 3),           \
            &lV[(i * 4 + wave) * 512]);                                       \
    }                                                                         \
  }

  // ---- prologue: stage Q (once) + first K tile ----
#pragma unroll
  for (int i = 0; i < 16; i++) {
    int row = (i * 4 + wave) * 2 + (lane >> 5);
    int cw = lane & 31;
    gld16(gQb + (size_t)row * 256 + ((cw ^ (row & 7)) << 3),
          &lQ[(i * 4 + wave) * 512]);
  }
  STAGE_K(ktBeg);
  __syncthreads();  // drains vmcnt: lQ + first lK ready

  f32x4 acc_o[2][16];
#pragma unroll
  for (int fi = 0; fi < 2; fi++)
#pragma unroll
    for (int i = 0; i < 16; i++) acc_o[fi][i] = (f32x4){0.f, 0.f, 0.f, 0.f};
  f32x4 m_v[2], l_v[2];
#pragma unroll
  for (int fi = 0; fi < 2; fi++) {
    m_v[fi] = (f32x4){-3e38f, -3e38f, -3e38f, -3e38f};
    l_v[fi] = (f32x4){0.f, 0.f, 0.f, 0.f};
  }

  for (int kt0 = ktBeg; kt0 < ktEnd; kt0 += 64) {
    // ---- phase A: stage V(t) | S = Q.K^T (64 MFMA) | softmax -> lP ----
    STAGE_V(kt0);
    f32x4 acc_s[2][4];
#pragma unroll
    for (int fi = 0; fi < 2; fi++)
#pragma unroll
      for (int i = 0; i < 4; i++) acc_s[fi][i] = (f32x4){0.f, 0.f, 0.f, 0.f};
#pragma unroll
    for (int ks = 0; ks < 8; ks++) {  // c-chunks of 32
      int cq = ks * 4 + q;
      f16x8 a0 = *(const f16x8*)&lQ[qr0 * 256 + ((cq ^ s7) << 3)];
      f16x8 a1 = *(const f16x8*)&lQ[qr1 * 256 + ((cq ^ s7) << 3)];
#pragma unroll
      for (int fj = 0; fj < 4; fj++) {
        int kr = fj * 16 + r16;
        f16x8 bf = *(const f16x8*)&lK[kr * 256 + ((cq ^ (kr & 7)) << 3)];
        acc_s[0][fj] = __builtin_amdgcn_mfma_f32_16x16x32_f16(a0, bf, acc_s[0][fj], 0, 0, 0);
        acc_s[1][fj] = __builtin_amdgcn_mfma_f32_16x16x32_f16(a1, bf, acc_s[1][fj], 0, 0, 0);
      }
    }
    // ---- mask pad keys (kTs pad rows are zeros, no NaN) ----
    if (kt0 + 64 > 4356) {
#pragma unroll
      for (int fj = 0; fj < 4; fj++)
        if (kt0 + fj * 16 + r16 >= 4356) {
          acc_s[0][fj] = (f32x4){-1e30f, -1e30f, -1e30f, -1e30f};
          acc_s[1][fj] = (f32x4){-1e30f, -1e30f, -1e30f, -1e30f};
        }
    }
    // ---- online softmax; lane owns rows fi*16+q*4+rr ----
    f32x4 pm[2];
#pragma unroll
    for (int fi = 0; fi < 2; fi++) {
      pm[fi] = acc_s[fi][0];
#pragma unroll
      for (int fj = 1; fj < 4; fj++)
#pragma unroll
        for (int rr = 0; rr < 4; rr++)
          pm[fi][rr] = fmaxf(pm[fi][rr], acc_s[fi][fj][rr]);
#pragma unroll
      for (int d = 1; d < 16; d <<= 1)
#pragma unroll
        for (int rr = 0; rr < 4; rr++)
          pm[fi][rr] = fmaxf(pm[fi][rr], __shfl_xor(pm[fi][rr], d));
    }
    // T13 defer-max: skip O/l rescale while tile max grows <= 8 (p <= e^8)
    int need = !__all(
        pm[0][0] - m_v[0][0] <= 8.f && pm[0][1] - m_v[0][1] <= 8.f &&
        pm[0][2] - m_v[0][2] <= 8.f && pm[0][3] - m_v[0][3] <= 8.f &&
        pm[1][0] - m_v[1][0] <= 8.f && pm[1][1] - m_v[1][1] <= 8.f &&
        pm[1][2] - m_v[1][2] <= 8.f && pm[1][3] - m_v[1][3] <= 8.f);
    if (need) {
#pragma unroll
      for (int fi = 0; fi < 2; fi++) {
        f32x4 fac;
#pragma unroll
        for (int rr = 0; rr < 4; rr++) {
          float mn = fmaxf(m_v[fi][rr], pm[fi][rr]);
          fac[rr] = __expf(m_v[fi][rr] - mn);
          m_v[fi][rr] = mn;
          l_v[fi][rr] *= fac[rr];
        }
#pragma unroll
        for (int fj = 0; fj < 16; fj++)
#pragma unroll
          for (int rr = 0; rr < 4; rr++) acc_o[fi][fj][rr] *= fac[rr];
      }
    }
#pragma unroll
    for (int fi = 0; fi < 2; fi++) {
      f32x4 rs = {0.f, 0.f, 0.f, 0.f};
#pragma unroll
      for (int fj = 0; fj < 4; fj++)
#pragma unroll
        for (int rr = 0; rr < 4; rr++) {
          _Float16 hp = (_Float16)__expf(acc_s[fi][fj][rr] - m_v[fi][rr]);
          rs[rr] += (float)hp;  // denominator sums the rounded p
          int row = wave * 32 + fi * 16 + q * 4 + rr;
          int c8 = fj * 2 + (r16 >> 3);
          lP[row * 64 + (((c8 ^ (row & 7)) << 3) | (r16 & 7))] = *(const u16*)&hp;
        }
#pragma unroll
      for (int d = 1; d < 16; d <<= 1)
#pragma unroll
        for (int rr = 0; rr < 4; rr++) rs[rr] += __shfl_xor(rs[rr], d);
#pragma unroll
      for (int rr = 0; rr < 4; rr++) l_v[fi][rr] += rs[rr];
    }
    __syncthreads();  // V(t) ready; lK reads + lP writes drained
    // ---- phase B: stage K(t+1) | PV: O += P.V^T (64 MFMA) ----
    if (kt0 + 64 < ktEnd) STAGE_K(kt0 + 64);
#pragma unroll
    for (int ks = 0; ks < 2; ks++) {  // kt-chunks of 32
      int k8 = ks * 4 + q;
      f16x8 ap0 = *(const f16x8*)&lP[qr0 * 64 + ((k8 ^ s7) << 3)];
      f16x8 ap1 = *(const f16x8*)&lP[qr1 * 64 + ((k8 ^ s7) << 3)];
#pragma unroll
      for (int fj = 0; fj < 16; fj++) {
        int cr = fj * 16 + r16;
        f16x8 bv = *(const f16x8*)&lV[cr * 64 + ((k8 ^ (cr & 7)) << 3)];
        acc_o[0][fj] = __builtin_amdgcn_mfma_f32_16x16x32_f16(ap0, bv, acc_o[0][fj], 0, 0, 0);
        acc_o[1][fj] = __builtin_amdgcn_mfma_f32_16x16x32_f16(ap1, bv, acc_o[1][fj], 0, 0, 0);
      }
    }
    __syncthreads();  // K(t+1) ready; lV + lP reads drained
  }
#undef STAGE_K
#undef STAGE_V
  // ---- store partials ----
#pragma unroll
  for (int fi = 0; fi < 2; fi++) {
    size_t ob = ((size_t)(h * 4 + b) * 4096 + qt0 + wave * 32 + fi * 16) * 256;
#pragma unroll
    for (int rr = 0; rr < 4; rr++) {
      size_t rowo = ob + (size_t)(q * 4 + rr) * 256;
#pragma unroll
      for (int fj = 0; fj < 16; fj++) Op[rowo + fj * 16 + r16] = acc_o[fi][fj][rr];
    }
    if (r16 == 0) {
      int base = (h * 4 + b) * 4096 + qt0 + wave * 32 + fi * 16 + q * 4;
      *(f32x4*)&ml[base] = m_v[fi];
      *(f32x4*)&ml[32768 + base] = l_v[fi];
    }
  }
}

// ---- 9) merge two kt-half partials, divide, transpose to out[b][c][qt] ----
__global__ __launch_bounds__(256) void k_merge(const float* __restrict__ Op,
                                               const float* __restrict__ ml,
                                               const int* __restrict__ flag,
                                               void* __restrict__ out) {
  __shared__ float th[32][33];
  int b = blockIdx.z, qt0 = blockIdx.x * 32, c0 = blockIdx.y * 32;
  int tx = threadIdx.x, ty = threadIdx.y;
#pragma unroll
  for (int i = 0; i < 4; i++) {
    int qt = qt0 + ty + i * 8;
    float m0 = ml[b * 4096 + qt], m1 = ml[(4 + b) * 4096 + qt];
    float l0 = ml[32768 + b * 4096 + qt], l1 = ml[32768 + (4 + b) * 4096 + qt];
    float M = fmaxf(m0, m1);
    float e0 = __expf(m0 - M), e1 = __expf(m1 - M);
    float inv = 1.f / (l0 * e0 + l1 * e1);  // >= 1, safe
    float v = (Op[((size_t)b * 4096 + qt) * 256 + c0 + tx] * e0 +
               Op[((size_t)(4 + b) * 4096 + qt) * 256 + c0 + tx] * e1) * inv;
    v = (v == v) ? v : 0.f;  // NaN scrub: keep failures diagnostic
    th[ty + i * 8][tx] = v;
  }
  __syncthreads();
#pragma unroll
  for (int i = 0; i < 4; i++) {
    int c = c0 + ty + i * 8, qt = qt0 + tx;
    float v = th[tx][ty + i * 8];
    size_t oidx = ((size_t)b * 256 + c) * 4096 + qt;
    if (flag[0])
      ((float*)out)[oidx] = v;
    else
      ((u16*)out)[oidx] = f2bf(v);
  }
}

// ---- 10) split-K support for conv ----
__global__ __launch_bounds__(256) void k_zeroacc(float* __restrict__ accF) {
  accF[blockIdx.x * 256 + threadIdx.x] = 0.f;
}

// ---------------------------------------------------------------------------
extern "C" void kernel_launch(void* const* d_in, const int* in_sizes, int n_in,
                              void* d_out, int out_size, void* d_ws, size_t ws_size,
                              hipStream_t stream) {
  const void* x = d_in[0];
  const void* Wq = d_in[1];
  const void* gq = d_in[3];
  const void* betaq = d_in[4];
  const void* Wk = d_in[5];
  const void* gk = d_in[7];
  const void* betak = d_in[8];
  const void* Wv = d_in[9];
  const void* gv = d_in[11];
  const void* betav = d_in[12];

  char* ws = (char*)d_ws;
  int* flag = (int*)ws;  // 256 B
  // Region A (conv phase; dead once qTs/kTs/vP built -> overlaid by Opart/ml):
  u16* xbTp = (u16*)(ws + 256);            //  8,921,088
  u16* WqB = (u16*)(ws + 8921344);         //  1,179,648
  u16* WkvB = (u16*)(ws + 10100992);       //    262,144
  float* bufQ = (float*)(ws + 10363136);   // 16,777,216
  float* bufKV = (float*)(ws + 27140352);  // 33,554,432 -> A ends 60,694,784
  u16* qTs = (u16*)(ws + 60694784);        //  8,388,608 (4*4096*256*2)
  u16* kTs = (u16*)(ws + 69083392);        //  9,175,040 (4*4480*256*2)
  u16* vP = (u16*)(ws + 78258432);         //  9,175,040
  float* nrm = (float*)(ws + 87433472);    //      6,144 -> total 87,439,616 B
  // Overlay region A (dead by flash time):
  float* Opart = (float*)(ws + 256);       // 33,554,432 (2*4*4096*256*4)
  float* mlbuf = (float*)(ws + 33554688);  //    262,144 (m: 32768 f, l: 32768 f)

  dim3 b32x8(32, 8);
  k_detect<<<1, 256, 0, stream>>>((const unsigned*)Wq, flag);
  k_txp<<<dim3(137, 8, 4), b32x8, 0, stream>>>(x, flag, xbTp);
  k_wq<<<2304, 256, 0, stream>>>(Wq, flag, WqB);
  k_wkv<<<512, 256, 0, stream>>>(Wk, Wv, flag, WkvB);
  // conv3x3: K=2304 split-K x3 (chunk 768) into zeroed bufQ; 768 blocks.
  k_zeroacc<<<16384, 256, 0, stream>>>(bufQ);
  gemm_bt<true, 1, 2><<<dim3(256, 1, 3), 256, 0, stream>>>(
      WqB, xbTp, bufQ, 256, 16384, 2304, 0, 0, 0, 768, 2, 16, 1, 0, 0, 0);
  // conv1x1: K=256; grid 512 = 8 XCD x (4 tm x 16 tn-band)
  gemm_bt<true, 0, 2><<<512, 256, 0, stream>>>(
      WkvB, xbTp, bufKV, 512, 16384, 256, 0, 4, 0, 0, 4, 16, 1, 0, 0, 0);
  k_stats<<<dim3(256, 3), 256, 0, stream>>>(bufQ, bufKV, gq, betaq, gk, betak,
                                            gv, betav, flag, nrm);
  k_qTs<<<dim3(128, 8, 4), b32x8, 0, stream>>>(bufQ, nrm, qTs);
  k_kTs<<<dim3(140, 8, 4), b32x8, 0, stream>>>(bufKV, nrm, kTs);
  k_vP<<<dim3(18, 256, 4), 256, 0, stream>>>(bufKV, nrm, vP);
  // fused attention: 256 blocks = 8 XCD-combos x 32 qt tiles, 1 block/CU
  k_flash<<<256, 256, 0, stream>>>(qTs, kTs, vP, Opart, mlbuf);
  k_merge<<<dim3(128, 8, 4), b32x8, 0, stream>>>(Opart, mlbuf, flag, d_out);
}

// Round 6
// 349.287 us; speedup vs baseline: 1.1621x; 1.1621x over previous
//
#include <hip/hip_runtime.h>

// ---------------------------------------------------------------------------
// ChannelAttentionLayer on MI355X (gfx950). Input dtype (fp32 vs bf16) is
// DETECTED ON DEVICE (k_detect); core pipeline is FP16 MFMA + fp32 accumulate.
// R16->R17: M=32qt/wave avenue CLOSED (acc_o=128 VGPR forces 1 wave/SIMD ->
// R16 201us; spill at KVBLK=128 -> R14/R15). k_flash restored to the R13
// version verbatim (131us, VGPR 120, 2 blocks/CU). New: conv GEMM was
// staging-LATENCY bound (MfmaUtil 12%, ~3.7Kcy/iter vs 150cy MFMA) -> gemm_bt
// gains DB=true: 2x32KB LDS double-buffer, next K-step's 8 gld16 issued
// BEFORE current compute, counted "s_waitcnt vmcnt(8)" + raw barrier (never
// drain mid-loop). conv3x3 splitK 3->4 (1024 blocks = 2 clean rounds of
// 2/CU at 64KB LDS). conv1x1 DB too (512 blocks, was already 2/CU).
// ---------------------------------------------------------------------------

typedef unsigned short u16;
typedef _Float16 f16x8 __attribute__((ext_vector_type(8)));
typedef __attribute__((ext_vector_type(4))) float f32x4;

__device__ __forceinline__ u16 f2h(float f) {
  _Float16 h = (_Float16)f;
  return *(const u16*)&h;
}
__device__ __forceinline__ float bf2f(u16 h) {
  return __uint_as_float(((unsigned)h) << 16);
}
__device__ __forceinline__ float ldin(const void* p, size_t i, int f32) {
  return f32 ? ((const float*)p)[i] : bf2f(((const u16*)p)[i]);
}
__device__ __forceinline__ u16 f2bf(float f) {
  unsigned u = __float_as_uint(f);
  u += 0x7fffu + ((u >> 16) & 1u);
  return (u16)(u >> 16);
}
__device__ __forceinline__ void gld16(const void* g, void* l) {
  __builtin_amdgcn_global_load_lds(
      (const __attribute__((address_space(1))) unsigned int*)g,
      (__attribute__((address_space(3))) unsigned int*)l, 16, 0, 0);
}

// ---- 1) dtype detection on Wq: 2048 sampled words, 8 independent loads ----
__global__ __launch_bounds__(256) void k_detect(const unsigned* __restrict__ w,
                                                int* __restrict__ flag) {
  __shared__ int red[4];
  int tid = threadIdx.x, cnt = 0;
#pragma unroll
  for (int j = 0; j < 8; j++) {
    unsigned e = (w[tid + j * 8192] >> 7) & 0xFFu;
    cnt += (e >= 118u && e <= 127u) ? 1 : 0;
  }
#pragma unroll
  for (int off = 32; off; off >>= 1) cnt += __shfl_down(cnt, off);
  if ((tid & 63) == 0) red[tid >> 6] = cnt;
  __syncthreads();
  if (tid == 0)
    flag[0] = (red[0] + red[1] + red[2] + red[3] < 625) ? 1 : 0;  // 1 = fp32
}

// ---- 2) pad+transpose x -> fp16 [b][66*66 pix][256c], zero border ----
__global__ __launch_bounds__(256) void k_txp(const void* __restrict__ x,
                                             const int* __restrict__ flag,
                                             u16* __restrict__ xbTp) {
  __shared__ float tile[32][33];
  int f32 = flag[0];
  int b = blockIdx.z, p0 = blockIdx.x * 32, c0 = blockIdx.y * 32;
  int tx = threadIdx.x, ty = threadIdx.y;
#pragma unroll
  for (int i = 0; i < 4; i++) {
    int c = c0 + ty + i * 8, pp = p0 + tx;
    float v = 0.f;
    if (pp < 4356) {
      int yy = pp / 66, xx = pp - yy * 66;
      if (yy >= 1 && yy <= 64 && xx >= 1 && xx <= 64)
        v = ldin(x, ((size_t)b * 256 + c) * 4096 + (yy - 1) * 64 + (xx - 1), f32);
    }
    tile[ty + i * 8][tx] = v;
  }
  __syncthreads();
#pragma unroll
  for (int i = 0; i < 4; i++) {
    int pp = p0 + ty + i * 8;
    if (pp >= 4356) continue;
    xbTp[((size_t)b * 4356 + pp) * 256 + c0 + tx] = f2h(tile[tx][ty + i * 8]);
  }
}

// ---- 3) weight reorders (fp16) ----
__global__ __launch_bounds__(256) void k_wq(const void* __restrict__ Wq,
                                            const int* __restrict__ flag,
                                            u16* __restrict__ WqB) {
  int idx = blockIdx.x * 256 + threadIdx.x;  // 256*2304
  int oc = idx / 2304, rem = idx - oc * 2304;
  int tap = rem >> 8, c = rem & 255;
  WqB[idx] = f2h(ldin(Wq, oc * 2304 + c * 9 + tap, flag[0]));
}
__global__ __launch_bounds__(256) void k_wkv(const void* __restrict__ Wk,
                                             const void* __restrict__ Wv,
                                             const int* __restrict__ flag,
                                             u16* __restrict__ WkvB) {
  int idx = blockIdx.x * 256 + threadIdx.x;  // 512*256
  int m = idx >> 8, c = idx & 255;
  float w = (m < 256) ? ldin(Wk, m * 256 + c, flag[0])
                      : ldin(Wv, (m - 256) * 256 + c, flag[0]);
  WkvB[idx] = f2h(w);
}

// ---- GEMM (fp16): C[M][N] = A[M][K] . Bt[N][K]^T ----
// DB=0: R6 1-buf structure (stage -> sync -> compute -> sync). DB=1: 2x32KB
// double-buffer, next K-step staged BEFORE current compute, counted vmcnt(8)
// + raw barrier (T3/T4; convs are staging-latency bound, MfmaUtil 12% at DB=0).
template <bool IMC, int EPI, int SWZ, bool DB>
__global__ __launch_bounds__(256, 3) void gemm_bt(
    const u16* __restrict__ A, const u16* __restrict__ Bt, void* __restrict__ Cptr,
    int M, int N, int K, int ldB, int tapBase, long long cOff, int kChunk,
    int sw1, int sw2, int nSplit, long long zA, long long zB, long long zC) {
  __shared__ u16 lA[(DB ? 2 : 1) * 128 * 64];
  __shared__ u16 lB[(DB ? 2 : 1) * 128 * 64];
  int tm, tn, b = 0, kz = 0;
  if (SWZ == 1) {
    int lin = blockIdx.x, xcd = lin & 7, per = lin >> 3;
    tm = xcd * sw1 + (per % sw1);
    tn = per / sw1;
    b = blockIdx.y;
  } else if (SWZ == 2) {
    int lin = blockIdx.x, xcd = lin & 7, per = lin >> 3;
    tm = per % sw1;
    tn = xcd * sw2 + per / sw1;
    kz = blockIdx.z;
  } else {
    tm = blockIdx.x;
    tn = blockIdx.y;
    b = blockIdx.z / nSplit;
    kz = blockIdx.z % nSplit;
  }
  int k0 = 0, k1 = K;
  if (kChunk) {
    k0 = kz * kChunk;
    k1 = min(k0 + kChunk, K);
  }
  const int tid = threadIdx.x, wave = tid >> 6, lane = tid & 63;
  const int sr = lane >> 3;         // source row within 8-row issue group
  const int scw = (lane & 7) ^ sr;  // XOR-swizzled source chunk
  const int wm = (wave >> 1) * 64, wn = (wave & 1) * 64;
  const int r16 = lane & 15, q = lane >> 4;
  const u16* gA = A + (size_t)b * zA + (size_t)(tm * 128 + wave * 32 + sr) * K +
                  scw * 8;
  const u16* gB = nullptr;
  int pyI[4], pxI[4];
  size_t bOffI[4];
  if (IMC) {
#pragma unroll
    for (int i = 0; i < 4; i++) {
      int n = tn * 128 + wave * 32 + i * 8 + sr;  // global output pixel
      int bb = n >> 12, pix = n & 4095;
      pyI[i] = pix >> 6;
      pxI[i] = pix & 63;
      bOffI[i] = (size_t)bb * 4356;
    }
  } else {
    gB = Bt + (size_t)b * zB + (size_t)(tn * 128 + wave * 32 + sr) * ldB +
         scw * 8;
  }
  f32x4 acc[4][4] = {};

  // stage one 64-K chunk into the given buffers (8 gld16 / thread)
  auto stage = [&](u16* dA, u16* dB, int kt) {
    int dy = 0, dx = 0, chunk = 0;
    if (IMC) {
      int tap = tapBase + (kt >> 8);
      chunk = kt & 255;
      dy = tap / 3;
      dx = tap - dy * 3;
    }
#pragma unroll
    for (int i = 0; i < 4; i++) {
      gld16(gA + (size_t)(i * 8) * K + kt, &dA[(wave * 32 + i * 8) * 64]);
      if (IMC) {
        int spix = (pyI[i] + dy) * 66 + pxI[i] + dx;
        gld16(Bt + (bOffI[i] + spix) * 256 + chunk + scw * 8,
              &dB[(wave * 32 + i * 8) * 64]);
      } else {
        gld16(gB + (size_t)(i * 8) * ldB + kt, &dB[(wave * 32 + i * 8) * 64]);
      }
    }
  };
  auto compute = [&](const u16* sA, const u16* sB) {
#pragma unroll
    for (int ks = 0; ks < 64; ks += 32) {
      f16x8 af[4], bfr[4];
#pragma unroll
      for (int f = 0; f < 4; f++) {
        int ma = wm + f * 16 + r16;
        int g = (ks >> 3) + q;
        af[f] = *(const f16x8*)&sA[ma * 64 + ((g ^ (ma & 7)) << 3)];
        int nb = wn + f * 16 + r16;
        bfr[f] = *(const f16x8*)&sB[nb * 64 + ((g ^ (nb & 7)) << 3)];
      }
#pragma unroll
      for (int fi = 0; fi < 4; fi++)
#pragma unroll
        for (int fj = 0; fj < 4; fj++)
          acc[fi][fj] = __builtin_amdgcn_mfma_f32_16x16x32_f16(
              af[fi], bfr[fj], acc[fi][fj], 0, 0, 0);
    }
  };

  if (DB) {
    stage(lA, lB, k0);  // prologue into buffer 0
    int cur = 0;
    for (int kt = k0; kt < k1; kt += 64) {
      if (kt + 64 < k1) {
        stage(&lA[(cur ^ 1) * 8192], &lB[(cur ^ 1) * 8192], kt + 64);
        asm volatile("s_waitcnt vmcnt(8)" ::: "memory");  // cur loads done
      } else {
        asm volatile("s_waitcnt vmcnt(0)" ::: "memory");
      }
      __builtin_amdgcn_s_barrier();
      __builtin_amdgcn_sched_barrier(0);
      compute(&lA[cur * 8192], &lB[cur * 8192]);
      __builtin_amdgcn_sched_barrier(0);
      asm volatile("s_waitcnt lgkmcnt(0)" ::: "memory");  // reads done
      __builtin_amdgcn_s_barrier();                       // before re-stage
      cur ^= 1;
    }
  } else {
    for (int kt = k0; kt < k1; kt += 64) {
      stage(lA, lB, kt);
      __syncthreads();
      compute(lA, lB);
      __syncthreads();
    }
  }

  const int colB = tn * 128 + wn + r16;
  const int rowB = tm * 128 + wm + q * 4;
  float* C = (float*)Cptr + cOff + (size_t)b * zC;
  if (EPI == 0) {
#pragma unroll
    for (int fi = 0; fi < 4; fi++)
#pragma unroll
      for (int r = 0; r < 4; r++) {
        size_t ro = (size_t)(rowB + fi * 16 + r) * N;
#pragma unroll
        for (int fj = 0; fj < 4; fj++) C[ro + colB + fj * 16] = acc[fi][fj][r];
      }
  } else {
#pragma unroll
    for (int fi = 0; fi < 4; fi++)
#pragma unroll
      for (int r = 0; r < 4; r++) {
        size_t ro = (size_t)(rowB + fi * 16 + r) * N;
#pragma unroll
        for (int fj = 0; fj < 4; fj++)
          atomicAdd(&C[ro + colB + fj * 16], acc[fi][fj][r]);
      }
  }
}

// ---- 5) BN stats (biases cancel; K/V border conv-value 0, count 17424) ----
__global__ __launch_bounds__(256) void k_stats(
    const float* __restrict__ bufQ, const float* __restrict__ bufKV,
    const void* __restrict__ gq, const void* __restrict__ betaq,
    const void* __restrict__ gk, const void* __restrict__ betak,
    const void* __restrict__ gv, const void* __restrict__ betav,
    const int* __restrict__ flag, float* __restrict__ nrm) {
  int f32 = flag[0];
  int ch = blockIdx.x, t = blockIdx.y, tid = threadIdx.x;
  const float* row = (t == 0) ? bufQ + (size_t)ch * 16384
                              : bufKV + (size_t)(t == 1 ? ch : 256 + ch) * 16384;
  float s = 0.f, ss = 0.f;
  for (int i = tid; i < 16384; i += 256) {
    float v = row[i];
    s += v;
    ss += v * v;
  }
#pragma unroll
  for (int off = 32; off; off >>= 1) {
    s += __shfl_down(s, off);
    ss += __shfl_down(ss, off);
  }
  __shared__ float ls[4], lss[4];
  if ((tid & 63) == 0) {
    ls[tid >> 6] = s;
    lss[tid >> 6] = ss;
  }
  __syncthreads();
  if (tid == 0) {
    s = ls[0] + ls[1] + ls[2] + ls[3];
    ss = lss[0] + lss[1] + lss[2] + lss[3];
    float cnt = (t == 0) ? 16384.f : 17424.f;
    float mean = s / cnt;
    float var = fmaxf(ss / cnt - mean * mean, 0.f);  // NaN-proof
    const void* g = (t == 0) ? gq : (t == 1 ? gk : gv);
    const void* be = (t == 0) ? betaq : (t == 1 ? betak : betav);
    float sc = ldin(g, ch, f32) * rsqrtf(var + 1e-5f);
    nrm[(t * 256 + ch) * 2] = sc;
    nrm[(t * 256 + ch) * 2 + 1] = ldin(be, ch, f32) - mean * sc;
  }
}

// ---- 6) normalize + transpose to fp16 (K=256 rows) ----
__global__ __launch_bounds__(256) void k_qTs(const float* __restrict__ bufQ,
                                             const float* __restrict__ nrm,
                                             u16* __restrict__ qTs) {
  __shared__ u16 th[32][33];
  int b = blockIdx.z, q0 = blockIdx.x * 32, c0 = blockIdx.y * 32;
  int tx = threadIdx.x, ty = threadIdx.y;
#pragma unroll
  for (int i = 0; i < 4; i++) {
    int c = c0 + ty + i * 8;
    float sc = nrm[c * 2], sh = nrm[c * 2 + 1];
    th[ty + i * 8][tx] =
        f2h(bufQ[(size_t)c * 16384 + b * 4096 + q0 + tx] * sc + sh);
  }
  __syncthreads();
#pragma unroll
  for (int i = 0; i < 4; i++)
    qTs[((size_t)b * 4096 + q0 + ty + i * 8) * 256 + c0 + tx] =
        th[tx][ty + i * 8];
}
__global__ __launch_bounds__(256) void k_kTs(const float* __restrict__ bufKV,
                                             const float* __restrict__ nrm,
                                             u16* __restrict__ kTs) {
  __shared__ u16 th[32][33];
  int b = blockIdx.z, k0 = blockIdx.x * 32, c0 = blockIdx.y * 32;
  int tx = threadIdx.x, ty = threadIdx.y;
#pragma unroll
  for (int i = 0; i < 4; i++) {
    int c = c0 + ty + i * 8;
    int kt = k0 + tx;
    float v = 0.f;
    if (kt < 4356) {
      float sc = nrm[(256 + c) * 2], sh = nrm[(256 + c) * 2 + 1];
      int yy = kt / 66, xx = kt - yy * 66;
      if (yy >= 1 && yy <= 64 && xx >= 1 && xx <= 64)
        v = bufKV[(size_t)c * 16384 + b * 4096 + (yy - 1) * 64 + (xx - 1)] * sc + sh;
      else
        v = sh;  // border: conv value 0
    }
    th[ty + i * 8][tx] = f2h(v);  // kt >= 4356 rows -> exact zeros
  }
  __syncthreads();
#pragma unroll
  for (int i = 0; i < 4; i++)
    kTs[((size_t)b * 4480 + k0 + ty + i * 8) * 256 + c0 + tx] =
        th[tx][ty + i * 8];
}

// ---- 7) normalized V fp16, [b][c][4480], pads zero ----
__global__ __launch_bounds__(256) void k_vP(const float* __restrict__ bufKV,
                                            const float* __restrict__ nrm,
                                            u16* __restrict__ vP) {
  int b = blockIdx.z, ch = blockIdx.y;
  int kt = blockIdx.x * 256 + threadIdx.x;
  if (kt >= 4480) return;
  float v = 0.f;
  if (kt < 4356) {
    float sc = nrm[(512 + ch) * 2], sh = nrm[(512 + ch) * 2 + 1];
    int yy = kt / 66, xx = kt - yy * 66;
    if (yy >= 1 && yy <= 64 && xx >= 1 && xx <= 64)
      v = bufKV[(size_t)(256 + ch) * 16384 + b * 4096 + (yy - 1) * 64 + (xx - 1)] * sc + sh;
    else
      v = sh;
  }
  vP[((size_t)b * 256 + ch) * 4480 + kt] = f2h(v);
}

// ---- 8) fused flash attention, 2-deep pipelined (R13 version, verbatim) ----
// grid 512 linear: xcd = lin&7 pins (h = xcd&1, b = xcd>>1) per XCD; per -> qt.
// Per tile, 4 phases {A: S c-half0 | B: S c-half1 | C: PV kt0..64 | D: PV
// 64..128}. buf0 holds A/C data, buf1 holds B/D (fixed parity). Each phase's
// stage is issued BEFORE the previous compute's barrier-wait; counted
// "s_waitcnt vmcnt(8)" keeps the newest 8 loads in flight across barriers.
__global__ __launch_bounds__(256, 2) void k_flash(
    const u16* __restrict__ qTs, const u16* __restrict__ kTs,
    const u16* __restrict__ vP, float* __restrict__ Op,
    float* __restrict__ ml) {
  __shared__ u16 lS[2][16384];  // 2 x 32KB staging (K-half or V-chunk)
  __shared__ u16 lP[64 * 128];  // 16KB P tile fp16, XOR-swizzled
  const int lin = blockIdx.x;
  const int xcd = lin & 7, per = lin >> 3;
  const int h = xcd & 1, b = xcd >> 1;
  const int qt0 = per * 64;
  const int tid = threadIdx.x, wave = tid >> 6, lane = tid & 63;
  const int sr = lane >> 3, scw = (lane & 7) ^ sr;
  const int r16 = lane & 15, q = lane >> 4;

  // Q fragments in registers: aq[kk] = Q[qt0+wave*16+r16][kk*32 + q*8 ..+7]
  const u16* gQ = qTs + ((size_t)b * 4096 + qt0 + wave * 16 + r16) * 256;
  f16x8 aq[8];
#pragma unroll
  for (int kk = 0; kk < 8; kk++) aq[kk] = *(const f16x8*)&gQ[kk * 32 + q * 8];
  // drain Q loads so in-loop vmcnt counting is exact (one-time cost)
  asm volatile("s_waitcnt vmcnt(0)" ::: "memory");

  const u16* gK = kTs + (size_t)b * 4480 * 256 + (size_t)(wave * 32 + sr) * 256 + scw * 8;
  const u16* gV = vP + ((size_t)b * 256 + wave * 64 + sr) * 4480 + scw * 8;

// 8 gld16/thread per stage (32KB/block). K half c2: rows=kt, 2 kcL chunks.
#define STAGE_K(buf, kt, c2)                                                 \
  {                                                                          \
    _Pragma("unroll") for (int i = 0; i < 4; i++) {                          \
      const u16* src = gK + (size_t)((kt) + i * 8) * 256 + (c2) * 128;       \
      gld16(src, &lS[buf][(wave * 32 + i * 8) * 64]);                        \
      gld16(src + 64, &lS[buf][8192 + (wave * 32 + i * 8) * 64]);            \
    }                                                                        \
  }
#define STAGE_V(buf, kt, vc)                                                 \
  {                                                                          \
    _Pragma("unroll") for (int i = 0; i < 8; i++)                            \
        gld16(gV + (size_t)(i * 8) * 4480 + (kt) + (vc) * 64,                \
              &lS[buf][(wave * 64 + i * 8) * 64]);                           \
  }
#define WAITB(n)                                                             \
  asm volatile("s_waitcnt vmcnt(" #n ")" ::: "memory");                      \
  __builtin_amdgcn_s_barrier();                                              \
  __builtin_amdgcn_sched_barrier(0);
#define CLOSEB()                                                             \
  __builtin_amdgcn_sched_barrier(0);                                         \
  asm volatile("s_waitcnt lgkmcnt(0)" ::: "memory");                         \
  __builtin_amdgcn_s_barrier();

  f32x4 acc_o[16];
#pragma unroll
  for (int i = 0; i < 16; i++) acc_o[i] = (f32x4){0.f, 0.f, 0.f, 0.f};
  f32x4 m_v = {-3e38f, -3e38f, -3e38f, -3e38f};
  f32x4 l_v = {0.f, 0.f, 0.f, 0.f};

  const int ktBeg = h ? 2304 : 0, ktEnd = h ? 4480 : 2304;
  STAGE_K(0, ktBeg, 0);  // prologue: phase A of first tile
  for (int kt0 = ktBeg; kt0 < ktEnd; kt0 += 128) {
    f32x4 acc_s[8];
#pragma unroll
    for (int i = 0; i < 8; i++) acc_s[i] = (f32x4){0.f, 0.f, 0.f, 0.f};
    // ---- phase A: S (c 0..127) from buf0; prefetch B ----
    STAGE_K(1, kt0, 1);
    WAITB(8);
    __builtin_amdgcn_s_setprio(1);
#pragma unroll
    for (int kcL = 0; kcL < 2; kcL++)
#pragma unroll
      for (int ks = 0; ks < 64; ks += 32)
#pragma unroll
        for (int fj = 0; fj < 8; fj++) {
          int nb = fj * 16 + r16;
          int g = (ks >> 3) + q;
          f16x8 bf = *(const f16x8*)&lS[0][kcL * 8192 + nb * 64 + ((g ^ (nb & 7)) << 3)];
          acc_s[fj] = __builtin_amdgcn_mfma_f32_16x16x32_f16(
              aq[kcL * 2 + (ks >> 5)], bf, acc_s[fj], 0, 0, 0);
        }
    __builtin_amdgcn_s_setprio(0);
    CLOSEB();
    // ---- phase B: S (c 128..255) from buf1; prefetch C (V kt-chunk 0) ----
    STAGE_V(0, kt0, 0);
    WAITB(8);
    __builtin_amdgcn_s_setprio(1);
#pragma unroll
    for (int kcL = 0; kcL < 2; kcL++)
#pragma unroll
      for (int ks = 0; ks < 64; ks += 32)
#pragma unroll
        for (int fj = 0; fj < 8; fj++) {
          int nb = fj * 16 + r16;
          int g = (ks >> 3) + q;
          f16x8 bf = *(const f16x8*)&lS[1][kcL * 8192 + nb * 64 + ((g ^ (nb & 7)) << 3)];
          acc_s[fj] = __builtin_amdgcn_mfma_f32_16x16x32_f16(
              aq[4 + kcL * 2 + (ks >> 5)], bf, acc_s[fj], 0, 0, 0);
        }
    __builtin_amdgcn_s_setprio(0);
    CLOSEB();
    // ---- prefetch D (V kt-chunk 1) so it flies under the softmax VALU ----
    STAGE_V(1, kt0, 1);
    // ---- mask pad keys (only last tile; kTs pad rows are zeros, no NaN) ----
    if (kt0 + 128 > 4356) {
#pragma unroll
      for (int fj = 0; fj < 8; fj++)
        if (kt0 + fj * 16 + r16 >= 4356)
          acc_s[fj] = (f32x4){-1e30f, -1e30f, -1e30f, -1e30f};
    }
    // ---- online softmax; lane owns rows q*4+rr of wave's 16-qt strip ----
    f32x4 pm = acc_s[0];
#pragma unroll
    for (int fj = 1; fj < 8; fj++)
#pragma unroll
      for (int rr = 0; rr < 4; rr++) pm[rr] = fmaxf(pm[rr], acc_s[fj][rr]);
#pragma unroll
    for (int d = 1; d < 16; d <<= 1)
#pragma unroll
      for (int rr = 0; rr < 4; rr++)
        pm[rr] = fmaxf(pm[rr], __shfl_xor(pm[rr], d));
    // T13 defer-max: skip O/l rescale while tile max grows <= 8 (p <= e^8
    // fits fp16; merge math is exact for any consistent reference m).
    int need = !__all(pm[0] - m_v[0] <= 8.f && pm[1] - m_v[1] <= 8.f &&
                      pm[2] - m_v[2] <= 8.f && pm[3] - m_v[3] <= 8.f);
    if (need) {
      f32x4 fac;
#pragma unroll
      for (int rr = 0; rr < 4; rr++) {
        float mn = fmaxf(m_v[rr], pm[rr]);
        fac[rr] = __expf(m_v[rr] - mn);
        m_v[rr] = mn;
        l_v[rr] *= fac[rr];
      }
#pragma unroll
      for (int fj = 0; fj < 16; fj++)
#pragma unroll
        for (int rr = 0; rr < 4; rr++) acc_o[fj][rr] *= fac[rr];
    }
    f32x4 rs = {0.f, 0.f, 0.f, 0.f};
#pragma unroll
    for (int fj = 0; fj < 8; fj++)
#pragma unroll
      for (int rr = 0; rr < 4; rr++) {
        _Float16 hp = (_Float16)__expf(acc_s[fj][rr] - m_v[rr]);
        rs[rr] += (float)hp;  // denominator sums the rounded p (consistency)
        int row = wave * 16 + q * 4 + rr;
        int c8 = fj * 2 + (r16 >> 3);
        lP[row * 128 + (((c8 ^ (row & 15)) << 3) | (r16 & 7))] = *(const u16*)&hp;
      }
#pragma unroll
    for (int d = 1; d < 16; d <<= 1)
#pragma unroll
      for (int rr = 0; rr < 4; rr++) rs[rr] += __shfl_xor(rs[rr], d);
#pragma unroll
    for (int rr = 0; rr < 4; rr++) l_v[rr] += rs[rr];
    // ---- phase C: PV kt-chunk 0 from buf0 (P is wave-private in lP) ----
    WAITB(8);
    __builtin_amdgcn_s_setprio(1);
#pragma unroll
    for (int ks = 0; ks < 64; ks += 32) {
      int k8 = (ks >> 3) + q;
      f16x8 ap = *(const f16x8*)&lP[(wave * 16 + r16) * 128 + ((k8 ^ r16) << 3)];
#pragma unroll
      for (int fj = 0; fj < 16; fj++) {
        int nb = fj * 16 + r16;
        int g = (ks >> 3) + q;
        f16x8 bv = *(const f16x8*)&lS[0][nb * 64 + ((g ^ (nb & 7)) << 3)];
        acc_o[fj] = __builtin_amdgcn_mfma_f32_16x16x32_f16(ap, bv, acc_o[fj], 0, 0, 0);
      }
    }
    __builtin_amdgcn_s_setprio(0);
    CLOSEB();
    // ---- phase D: PV kt-chunk 1 from buf1; prefetch next tile's A ----
    if (kt0 + 128 < ktEnd) {
      STAGE_K(0, kt0 + 128, 0);
      WAITB(8);
    } else {
      WAITB(0);
    }
    __builtin_amdgcn_s_setprio(1);
#pragma unroll
    for (int ks = 0; ks < 64; ks += 32) {
      int k8 = 8 + (ks >> 3) + q;
      f16x8 ap = *(const f16x8*)&lP[(wave * 16 + r16) * 128 + ((k8 ^ r16) << 3)];
#pragma unroll
      for (int fj = 0; fj < 16; fj++) {
        int nb = fj * 16 + r16;
        int g = (ks >> 3) + q;
        f16x8 bv = *(const f16x8*)&lS[1][nb * 64 + ((g ^ (nb & 7)) << 3)];
        acc_o[fj] = __builtin_amdgcn_mfma_f32_16x16x32_f16(ap, bv, acc_o[fj], 0, 0, 0);
      }
    }
    __builtin_amdgcn_s_setprio(0);
    CLOSEB();
  }
#undef STAGE_K
#undef STAGE_V
#undef WAITB
#undef CLOSEB
  // ---- store partials ----
  size_t ob = ((size_t)(h * 4 + b) * 4096 + qt0 + wave * 16) * 256;
#pragma unroll
  for (int rr = 0; rr < 4; rr++) {
    size_t rowo = ob + (size_t)(q * 4 + rr) * 256;
#pragma unroll
    for (int fj = 0; fj < 16; fj++) Op[rowo + fj * 16 + r16] = acc_o[fj][rr];
  }
  if (r16 == 0) {
    int base = (h * 4 + b) * 4096 + qt0 + wave * 16 + q * 4;
    *(f32x4*)&ml[base] = m_v;
    *(f32x4*)&ml[32768 + base] = l_v;
  }
}

// ---- 9) merge two kt-half partials, divide, transpose to out[b][c][qt] ----
__global__ __launch_bounds__(256) void k_merge(const float* __restrict__ Op,
                                               const float* __restrict__ ml,
                                               const int* __restrict__ flag,
                                               void* __restrict__ out) {
  __shared__ float th[32][33];
  int b = blockIdx.z, qt0 = blockIdx.x * 32, c0 = blockIdx.y * 32;
  int tx = threadIdx.x, ty = threadIdx.y;
#pragma unroll
  for (int i = 0; i < 4; i++) {
    int qt = qt0 + ty + i * 8;
    float m0 = ml[b * 4096 + qt], m1 = ml[(4 + b) * 4096 + qt];
    float l0 = ml[32768 + b * 4096 + qt], l1 = ml[32768 + (4 + b) * 4096 + qt];
    float M = fmaxf(m0, m1);
    float e0 = __expf(m0 - M), e1 = __expf(m1 - M);
    float inv = 1.f / (l0 * e0 + l1 * e1);  // >= 1, safe
    float v = (Op[((size_t)b * 4096 + qt) * 256 + c0 + tx] * e0 +
               Op[((size_t)(4 + b) * 4096 + qt) * 256 + c0 + tx] * e1) * inv;
    v = (v == v) ? v : 0.f;  // NaN scrub: keep failures diagnostic
    th[ty + i * 8][tx] = v;
  }
  __syncthreads();
#pragma unroll
  for (int i = 0; i < 4; i++) {
    int c = c0 + ty + i * 8, qt = qt0 + tx;
    float v = th[tx][ty + i * 8];
    size_t oidx = ((size_t)b * 256 + c) * 4096 + qt;
    if (flag[0])
      ((float*)out)[oidx] = v;
    else
      ((u16*)out)[oidx] = f2bf(v);
  }
}

// ---- 10) split-K support for conv ----
__global__ __launch_bounds__(256) void k_zeroacc(float* __restrict__ accF) {
  accF[blockIdx.x * 256 + threadIdx.x] = 0.f;
}

// ---------------------------------------------------------------------------
extern "C" void kernel_launch(void* const* d_in, const int* in_sizes, int n_in,
                              void* d_out, int out_size, void* d_ws, size_t ws_size,
                              hipStream_t stream) {
  const void* x = d_in[0];
  const void* Wq = d_in[1];
  const void* gq = d_in[3];
  const void* betaq = d_in[4];
  const void* Wk = d_in[5];
  const void* gk = d_in[7];
  const void* betak = d_in[8];
  const void* Wv = d_in[9];
  const void* gv = d_in[11];
  const void* betav = d_in[12];

  char* ws = (char*)d_ws;
  int* flag = (int*)ws;  // 256 B
  // Region A (conv phase; dead once qTs/kTs/vP built -> overlaid by Opart/ml):
  u16* xbTp = (u16*)(ws + 256);            //  8,921,088
  u16* WqB = (u16*)(ws + 8921344);         //  1,179,648
  u16* WkvB = (u16*)(ws + 10100992);       //    262,144
  float* bufQ = (float*)(ws + 10363136);   // 16,777,216
  float* bufKV = (float*)(ws + 27140352);  // 33,554,432 -> A ends 60,694,784
  u16* qTs = (u16*)(ws + 60694784);        //  8,388,608 (4*4096*256*2)
  u16* kTs = (u16*)(ws + 69083392);        //  9,175,040 (4*4480*256*2)
  u16* vP = (u16*)(ws + 78258432);         //  9,175,040
  float* nrm = (float*)(ws + 87433472);    //      6,144 -> total 87,439,616 B
  // Overlay region A (dead by flash time):
  float* Opart = (float*)(ws + 256);       // 33,554,432 (2*4*4096*256*4)
  float* mlbuf = (float*)(ws + 33554688);  //    262,144 (m: 32768 f, l: 32768 f)

  dim3 b32x8(32, 8);
  k_detect<<<1, 256, 0, stream>>>((const unsigned*)Wq, flag);
  k_txp<<<dim3(137, 8, 4), b32x8, 0, stream>>>(x, flag, xbTp);
  k_wq<<<2304, 256, 0, stream>>>(Wq, flag, WqB);
  k_wkv<<<512, 256, 0, stream>>>(Wk, Wv, flag, WkvB);
  // conv3x3: K=2304 split-K x4 (chunk 576) into zeroed bufQ; 1024 blocks,
  // DB pipeline (64KB LDS -> 2 blocks/CU, 2 clean rounds).
  k_zeroacc<<<16384, 256, 0, stream>>>(bufQ);
  gemm_bt<true, 1, 2, true><<<dim3(256, 1, 4), 256, 0, stream>>>(
      WqB, xbTp, bufQ, 256, 16384, 2304, 0, 0, 0, 576, 2, 16, 1, 0, 0, 0);
  // conv1x1: K=256; grid 512 = 8 XCD x (4 tm x 16 tn-band), DB pipeline.
  gemm_bt<true, 0, 2, true><<<512, 256, 0, stream>>>(
      WkvB, xbTp, bufKV, 512, 16384, 256, 0, 4, 0, 0, 4, 16, 1, 0, 0, 0);
  k_stats<<<dim3(256, 3), 256, 0, stream>>>(bufQ, bufKV, gq, betaq, gk, betak,
                                            gv, betav, flag, nrm);
  k_qTs<<<dim3(128, 8, 4), b32x8, 0, stream>>>(bufQ, nrm, qTs);
  k_kTs<<<dim3(140, 8, 4), b32x8, 0, stream>>>(bufKV, nrm, kTs);
  k_vP<<<dim3(18, 256, 4), 256, 0, stream>>>(bufKV, nrm, vP);
  // fused attention: 512 blocks = 8 XCD-combos x 64 qt tiles, 2 blocks/CU
  k_flash<<<512, 256, 0, stream>>>(qTs, kTs, vP, Opart, mlbuf);
  k_merge<<<dim3(128, 8, 4), b32x8, 0, stream>>>(Opart, mlbuf, flag, d_out);
}

// Round 7
// 347.707 us; speedup vs baseline: 1.1674x; 1.0045x over previous
//
#include <hip/hip_runtime.h>

// ---------------------------------------------------------------------------
// ChannelAttentionLayer on MI355X (gfx950). Input dtype (fp32 vs bf16) is
// DETECTED ON DEVICE (k_detect); core pipeline is FP16 MFMA + fp32 accumulate.
// R17->R18: convs reverted to R12 exact (DB experiment cost +17us). k_flash
// is LDS-port bound (22.4MB/CU at 85B/cy ~= 110us of its 130us): the 4 waves
// redundantly read identical V B-frags in PV. Fix: PV re-decomposed by
// CHANNELS (wave w owns c [64w,64w+64) x all 64 qt) -> V-frags wave-unique,
// P-frags amortized x4: PV reads 272->128/tile (total 640->512KB, -20%).
// P is now cross-wave: lP shrunk to 8KB half-tile (fj>=4 kept in regs,
// refilled pre-D), lgkmcnt(0) added to WAITB, rescale factors broadcast via
// lFac[64] (fac==1.0 exact when defer-max skips -> bitwise-identical math).
// LDS 72.25KB -> still 2 blocks/CU. S phase + softmax unchanged from R13.
// ---------------------------------------------------------------------------

typedef unsigned short u16;
typedef _Float16 f16x8 __attribute__((ext_vector_type(8)));
typedef __attribute__((ext_vector_type(4))) float f32x4;

__device__ __forceinline__ u16 f2h(float f) {
  _Float16 h = (_Float16)f;
  return *(const u16*)&h;
}
__device__ __forceinline__ float bf2f(u16 h) {
  return __uint_as_float(((unsigned)h) << 16);
}
__device__ __forceinline__ float ldin(const void* p, size_t i, int f32) {
  return f32 ? ((const float*)p)[i] : bf2f(((const u16*)p)[i]);
}
__device__ __forceinline__ u16 f2bf(float f) {
  unsigned u = __float_as_uint(f);
  u += 0x7fffu + ((u >> 16) & 1u);
  return (u16)(u >> 16);
}
__device__ __forceinline__ void gld16(const void* g, void* l) {
  __builtin_amdgcn_global_load_lds(
      (const __attribute__((address_space(1))) unsigned int*)g,
      (__attribute__((address_space(3))) unsigned int*)l, 16, 0, 0);
}

// ---- 1) dtype detection on Wq: 2048 sampled words, 8 independent loads ----
__global__ __launch_bounds__(256) void k_detect(const unsigned* __restrict__ w,
                                                int* __restrict__ flag) {
  __shared__ int red[4];
  int tid = threadIdx.x, cnt = 0;
#pragma unroll
  for (int j = 0; j < 8; j++) {
    unsigned e = (w[tid + j * 8192] >> 7) & 0xFFu;
    cnt += (e >= 118u && e <= 127u) ? 1 : 0;
  }
#pragma unroll
  for (int off = 32; off; off >>= 1) cnt += __shfl_down(cnt, off);
  if ((tid & 63) == 0) red[tid >> 6] = cnt;
  __syncthreads();
  if (tid == 0)
    flag[0] = (red[0] + red[1] + red[2] + red[3] < 625) ? 1 : 0;  // 1 = fp32
}

// ---- 2) pad+transpose x -> fp16 [b][66*66 pix][256c], zero border ----
__global__ __launch_bounds__(256) void k_txp(const void* __restrict__ x,
                                             const int* __restrict__ flag,
                                             u16* __restrict__ xbTp) {
  __shared__ float tile[32][33];
  int f32 = flag[0];
  int b = blockIdx.z, p0 = blockIdx.x * 32, c0 = blockIdx.y * 32;
  int tx = threadIdx.x, ty = threadIdx.y;
#pragma unroll
  for (int i = 0; i < 4; i++) {
    int c = c0 + ty + i * 8, pp = p0 + tx;
    float v = 0.f;
    if (pp < 4356) {
      int yy = pp / 66, xx = pp - yy * 66;
      if (yy >= 1 && yy <= 64 && xx >= 1 && xx <= 64)
        v = ldin(x, ((size_t)b * 256 + c) * 4096 + (yy - 1) * 64 + (xx - 1), f32);
    }
    tile[ty + i * 8][tx] = v;
  }
  __syncthreads();
#pragma unroll
  for (int i = 0; i < 4; i++) {
    int pp = p0 + ty + i * 8;
    if (pp >= 4356) continue;
    xbTp[((size_t)b * 4356 + pp) * 256 + c0 + tx] = f2h(tile[tx][ty + i * 8]);
  }
}

// ---- 3) weight reorders (fp16) ----
__global__ __launch_bounds__(256) void k_wq(const void* __restrict__ Wq,
                                            const int* __restrict__ flag,
                                            u16* __restrict__ WqB) {
  int idx = blockIdx.x * 256 + threadIdx.x;  // 256*2304
  int oc = idx / 2304, rem = idx - oc * 2304;
  int tap = rem >> 8, c = rem & 255;
  WqB[idx] = f2h(ldin(Wq, oc * 2304 + c * 9 + tap, flag[0]));
}
__global__ __launch_bounds__(256) void k_wkv(const void* __restrict__ Wk,
                                             const void* __restrict__ Wv,
                                             const int* __restrict__ flag,
                                             u16* __restrict__ WkvB) {
  int idx = blockIdx.x * 256 + threadIdx.x;  // 512*256
  int m = idx >> 8, c = idx & 255;
  float w = (m < 256) ? ldin(Wk, m * 256 + c, flag[0])
                      : ldin(Wv, (m - 256) * 256 + c, flag[0]);
  WkvB[idx] = f2h(w);
}

// ---- GEMM (fp16): C[M][N] = A[M][K] . Bt[N][K]^T  (R6 1-buf structure) ----
template <bool IMC, int EPI, int SWZ>
__global__ __launch_bounds__(256, 3) void gemm_bt(
    const u16* __restrict__ A, const u16* __restrict__ Bt, void* __restrict__ Cptr,
    int M, int N, int K, int ldB, int tapBase, long long cOff, int kChunk,
    int sw1, int sw2, int nSplit, long long zA, long long zB, long long zC) {
  __shared__ u16 lA[128 * 64];
  __shared__ u16 lB[128 * 64];
  int tm, tn, b = 0, kz = 0;
  if (SWZ == 1) {
    int lin = blockIdx.x, xcd = lin & 7, per = lin >> 3;
    tm = xcd * sw1 + (per % sw1);
    tn = per / sw1;
    b = blockIdx.y;
  } else if (SWZ == 2) {
    int lin = blockIdx.x, xcd = lin & 7, per = lin >> 3;
    tm = per % sw1;
    tn = xcd * sw2 + per / sw1;
    kz = blockIdx.z;
  } else {
    tm = blockIdx.x;
    tn = blockIdx.y;
    b = blockIdx.z / nSplit;
    kz = blockIdx.z % nSplit;
  }
  int k0 = 0, k1 = K;
  if (kChunk) {
    k0 = kz * kChunk;
    k1 = min(k0 + kChunk, K);
  }
  const int tid = threadIdx.x, wave = tid >> 6, lane = tid & 63;
  const int sr = lane >> 3;         // source row within 8-row issue group
  const int scw = (lane & 7) ^ sr;  // XOR-swizzled source chunk
  const int wm = (wave >> 1) * 64, wn = (wave & 1) * 64;
  const int r16 = lane & 15, q = lane >> 4;
  const u16* gA = A + (size_t)b * zA + (size_t)(tm * 128 + wave * 32 + sr) * K +
                  scw * 8;
  const u16* gB = nullptr;
  int pyI[4], pxI[4];
  size_t bOffI[4];
  if (IMC) {
#pragma unroll
    for (int i = 0; i < 4; i++) {
      int n = tn * 128 + wave * 32 + i * 8 + sr;  // global output pixel
      int bb = n >> 12, pix = n & 4095;
      pyI[i] = pix >> 6;
      pxI[i] = pix & 63;
      bOffI[i] = (size_t)bb * 4356;
    }
  } else {
    gB = Bt + (size_t)b * zB + (size_t)(tn * 128 + wave * 32 + sr) * ldB +
         scw * 8;
  }
  f32x4 acc[4][4] = {};

  for (int kt = k0; kt < k1; kt += 64) {
    int dy = 0, dx = 0, chunk = 0;
    if (IMC) {
      int tap = tapBase + (kt >> 8);
      chunk = kt & 255;
      dy = tap / 3;
      dx = tap - dy * 3;
    }
#pragma unroll
    for (int i = 0; i < 4; i++) {
      gld16(gA + (size_t)(i * 8) * K + kt, &lA[(wave * 32 + i * 8) * 64]);
      if (IMC) {
        int spix = (pyI[i] + dy) * 66 + pxI[i] + dx;
        gld16(Bt + (bOffI[i] + spix) * 256 + chunk + scw * 8,
              &lB[(wave * 32 + i * 8) * 64]);
      } else {
        gld16(gB + (size_t)(i * 8) * ldB + kt, &lB[(wave * 32 + i * 8) * 64]);
      }
    }
    __syncthreads();
#pragma unroll
    for (int ks = 0; ks < 64; ks += 32) {
      f16x8 af[4], bfr[4];
#pragma unroll
      for (int f = 0; f < 4; f++) {
        int ma = wm + f * 16 + r16;
        int g = (ks >> 3) + q;
        af[f] = *(const f16x8*)&lA[ma * 64 + ((g ^ (ma & 7)) << 3)];
        int nb = wn + f * 16 + r16;
        bfr[f] = *(const f16x8*)&lB[nb * 64 + ((g ^ (nb & 7)) << 3)];
      }
#pragma unroll
      for (int fi = 0; fi < 4; fi++)
#pragma unroll
        for (int fj = 0; fj < 4; fj++)
          acc[fi][fj] = __builtin_amdgcn_mfma_f32_16x16x32_f16(
              af[fi], bfr[fj], acc[fi][fj], 0, 0, 0);
    }
    __syncthreads();
  }

  const int colB = tn * 128 + wn + r16;
  const int rowB = tm * 128 + wm + q * 4;
  float* C = (float*)Cptr + cOff + (size_t)b * zC;
  if (EPI == 0) {
#pragma unroll
    for (int fi = 0; fi < 4; fi++)
#pragma unroll
      for (int r = 0; r < 4; r++) {
        size_t ro = (size_t)(rowB + fi * 16 + r) * N;
#pragma unroll
        for (int fj = 0; fj < 4; fj++) C[ro + colB + fj * 16] = acc[fi][fj][r];
      }
  } else {
#pragma unroll
    for (int fi = 0; fi < 4; fi++)
#pragma unroll
      for (int r = 0; r < 4; r++) {
        size_t ro = (size_t)(rowB + fi * 16 + r) * N;
#pragma unroll
        for (int fj = 0; fj < 4; fj++)
          atomicAdd(&C[ro + colB + fj * 16], acc[fi][fj][r]);
      }
  }
}

// ---- 5) BN stats (biases cancel; K/V border conv-value 0, count 17424) ----
__global__ __launch_bounds__(256) void k_stats(
    const float* __restrict__ bufQ, const float* __restrict__ bufKV,
    const void* __restrict__ gq, const void* __restrict__ betaq,
    const void* __restrict__ gk, const void* __restrict__ betak,
    const void* __restrict__ gv, const void* __restrict__ betav,
    const int* __restrict__ flag, float* __restrict__ nrm) {
  int f32 = flag[0];
  int ch = blockIdx.x, t = blockIdx.y, tid = threadIdx.x;
  const float* row = (t == 0) ? bufQ + (size_t)ch * 16384
                              : bufKV + (size_t)(t == 1 ? ch : 256 + ch) * 16384;
  float s = 0.f, ss = 0.f;
  for (int i = tid; i < 16384; i += 256) {
    float v = row[i];
    s += v;
    ss += v * v;
  }
#pragma unroll
  for (int off = 32; off; off >>= 1) {
    s += __shfl_down(s, off);
    ss += __shfl_down(ss, off);
  }
  __shared__ float ls[4], lss[4];
  if ((tid & 63) == 0) {
    ls[tid >> 6] = s;
    lss[tid >> 6] = ss;
  }
  __syncthreads();
  if (tid == 0) {
    s = ls[0] + ls[1] + ls[2] + ls[3];
    ss = lss[0] + lss[1] + lss[2] + lss[3];
    float cnt = (t == 0) ? 16384.f : 17424.f;
    float mean = s / cnt;
    float var = fmaxf(ss / cnt - mean * mean, 0.f);  // NaN-proof
    const void* g = (t == 0) ? gq : (t == 1 ? gk : gv);
    const void* be = (t == 0) ? betaq : (t == 1 ? betak : betav);
    float sc = ldin(g, ch, f32) * rsqrtf(var + 1e-5f);
    nrm[(t * 256 + ch) * 2] = sc;
    nrm[(t * 256 + ch) * 2 + 1] = ldin(be, ch, f32) - mean * sc;
  }
}

// ---- 6) normalize + transpose to fp16 (K=256 rows) ----
__global__ __launch_bounds__(256) void k_qTs(const float* __restrict__ bufQ,
                                             const float* __restrict__ nrm,
                                             u16* __restrict__ qTs) {
  __shared__ u16 th[32][33];
  int b = blockIdx.z, q0 = blockIdx.x * 32, c0 = blockIdx.y * 32;
  int tx = threadIdx.x, ty = threadIdx.y;
#pragma unroll
  for (int i = 0; i < 4; i++) {
    int c = c0 + ty + i * 8;
    float sc = nrm[c * 2], sh = nrm[c * 2 + 1];
    th[ty + i * 8][tx] =
        f2h(bufQ[(size_t)c * 16384 + b * 4096 + q0 + tx] * sc + sh);
  }
  __syncthreads();
#pragma unroll
  for (int i = 0; i < 4; i++)
    qTs[((size_t)b * 4096 + q0 + ty + i * 8) * 256 + c0 + tx] =
        th[tx][ty + i * 8];
}
__global__ __launch_bounds__(256) void k_kTs(const float* __restrict__ bufKV,
                                             const float* __restrict__ nrm,
                                             u16* __restrict__ kTs) {
  __shared__ u16 th[32][33];
  int b = blockIdx.z, k0 = blockIdx.x * 32, c0 = blockIdx.y * 32;
  int tx = threadIdx.x, ty = threadIdx.y;
#pragma unroll
  for (int i = 0; i < 4; i++) {
    int c = c0 + ty + i * 8;
    int kt = k0 + tx;
    float v = 0.f;
    if (kt < 4356) {
      float sc = nrm[(256 + c) * 2], sh = nrm[(256 + c) * 2 + 1];
      int yy = kt / 66, xx = kt - yy * 66;
      if (yy >= 1 && yy <= 64 && xx >= 1 && xx <= 64)
        v = bufKV[(size_t)c * 16384 + b * 4096 + (yy - 1) * 64 + (xx - 1)] * sc + sh;
      else
        v = sh;  // border: conv value 0
    }
    th[ty + i * 8][tx] = f2h(v);  // kt >= 4356 rows -> exact zeros
  }
  __syncthreads();
#pragma unroll
  for (int i = 0; i < 4; i++)
    kTs[((size_t)b * 4480 + k0 + ty + i * 8) * 256 + c0 + tx] =
        th[tx][ty + i * 8];
}

// ---- 7) normalized V fp16, [b][c][4480], pads zero ----
__global__ __launch_bounds__(256) void k_vP(const float* __restrict__ bufKV,
                                            const float* __restrict__ nrm,
                                            u16* __restrict__ vP) {
  int b = blockIdx.z, ch = blockIdx.y;
  int kt = blockIdx.x * 256 + threadIdx.x;
  if (kt >= 4480) return;
  float v = 0.f;
  if (kt < 4356) {
    float sc = nrm[(512 + ch) * 2], sh = nrm[(512 + ch) * 2 + 1];
    int yy = kt / 66, xx = kt - yy * 66;
    if (yy >= 1 && yy <= 64 && xx >= 1 && xx <= 64)
      v = bufKV[(size_t)(256 + ch) * 16384 + b * 4096 + (yy - 1) * 64 + (xx - 1)] * sc + sh;
    else
      v = sh;
  }
  vP[((size_t)b * 256 + ch) * 4480 + kt] = f2h(v);
}

// ---- 8) fused flash attention, 2-deep pipelined, PV split by CHANNELS ----
// grid 512 linear: xcd = lin&7 pins (h = xcd&1, b = xcd>>1) per XCD; per->qt.
// S phase (per tile halves A/B) and softmax: per-wave 16 qt (R13, unchanged).
// PV (phases C/D): wave w owns c [64w,64w+64) x ALL 64 qt -> V-frags are
// wave-unique (reads 272->128/tile). P crosses waves via lP (8KB half-tile:
// fj<4 written in softmax, fj>=4 kept in hq[] regs, refilled after C).
// Rescale fac broadcast via lFac[64]; fac==1.0 exact when defer-max skips.
// WAITB drains lgkmcnt(0) so cross-wave ds_writes are visible post-barrier.
__global__ __launch_bounds__(256, 2) void k_flash(
    const u16* __restrict__ qTs, const u16* __restrict__ kTs,
    const u16* __restrict__ vP, float* __restrict__ Op,
    float* __restrict__ ml) {
  __shared__ u16 lS[2][16384];  // 2 x 32KB staging (K-half or V-chunk)
  __shared__ u16 lP[64 * 64];   // 8KB P half-tile (64 qt x 64 kt), swizzled
  __shared__ float lFac[64];    // per-qt-row rescale factor broadcast
  const int lin = blockIdx.x;
  const int xcd = lin & 7, per = lin >> 3;
  const int h = xcd & 1, b = xcd >> 1;
  const int qt0 = per * 64;
  const int tid = threadIdx.x, wave = tid >> 6, lane = tid & 63;
  const int sr = lane >> 3, scw = (lane & 7) ^ sr;
  const int r16 = lane & 15, q = lane >> 4;

  // Q fragments in registers: aq[kk] = Q[qt0+wave*16+r16][kk*32 + q*8 ..+7]
  const u16* gQ = qTs + ((size_t)b * 4096 + qt0 + wave * 16 + r16) * 256;
  f16x8 aq[8];
#pragma unroll
  for (int kk = 0; kk < 8; kk++) aq[kk] = *(const f16x8*)&gQ[kk * 32 + q * 8];
  // drain Q loads so in-loop vmcnt counting is exact (one-time cost)
  asm volatile("s_waitcnt vmcnt(0)" ::: "memory");

  const u16* gK = kTs + (size_t)b * 4480 * 256 + (size_t)(wave * 32 + sr) * 256 + scw * 8;
  const u16* gV = vP + ((size_t)b * 256 + wave * 64 + sr) * 4480 + scw * 8;

// 8 gld16/thread per stage (32KB/block). K half c2: rows=kt, 2 kcL chunks.
#define STAGE_K(buf, kt, c2)                                                 \
  {                                                                          \
    _Pragma("unroll") for (int i = 0; i < 4; i++) {                          \
      const u16* src = gK + (size_t)((kt) + i * 8) * 256 + (c2) * 128;       \
      gld16(src, &lS[buf][(wave * 32 + i * 8) * 64]);                        \
      gld16(src + 64, &lS[buf][8192 + (wave * 32 + i * 8) * 64]);            \
    }                                                                        \
  }
#define STAGE_V(buf, kt, vc)                                                 \
  {                                                                          \
    _Pragma("unroll") for (int i = 0; i < 8; i++)                            \
        gld16(gV + (size_t)(i * 8) * 4480 + (kt) + (vc) * 64,                \
              &lS[buf][(wave * 64 + i * 8) * 64]);                           \
  }
#define WAITB(n)                                                             \
  asm volatile("s_waitcnt vmcnt(" #n ") lgkmcnt(0)" ::: "memory");           \
  __builtin_amdgcn_s_barrier();                                              \
  __builtin_amdgcn_sched_barrier(0);
#define CLOSEB()                                                             \
  __builtin_amdgcn_sched_barrier(0);                                         \
  asm volatile("s_waitcnt lgkmcnt(0)" ::: "memory");                         \
  __builtin_amdgcn_s_barrier();

  // acc_o[mt][fj]: qt-tile mt (rows mt*16+q*4+rr), c-tile fj (wave*64+fj*16+r16)
  f32x4 acc_o[4][4];
#pragma unroll
  for (int mt = 0; mt < 4; mt++)
#pragma unroll
    for (int fj = 0; fj < 4; fj++) acc_o[mt][fj] = (f32x4){0.f, 0.f, 0.f, 0.f};
  f32x4 m_v = {-3e38f, -3e38f, -3e38f, -3e38f};
  f32x4 l_v = {0.f, 0.f, 0.f, 0.f};

  const int ktBeg = h ? 2304 : 0, ktEnd = h ? 4480 : 2304;
  STAGE_K(0, ktBeg, 0);  // prologue: phase A of first tile
  for (int kt0 = ktBeg; kt0 < ktEnd; kt0 += 128) {
    f32x4 acc_s[8];
#pragma unroll
    for (int i = 0; i < 8; i++) acc_s[i] = (f32x4){0.f, 0.f, 0.f, 0.f};
    // ---- phase A: S (c 0..127) from buf0; prefetch B ----
    STAGE_K(1, kt0, 1);
    WAITB(8);
    __builtin_amdgcn_s_setprio(1);
#pragma unroll
    for (int kcL = 0; kcL < 2; kcL++)
#pragma unroll
      for (int ks = 0; ks < 64; ks += 32)
#pragma unroll
        for (int fj = 0; fj < 8; fj++) {
          int nb = fj * 16 + r16;
          int g = (ks >> 3) + q;
          f16x8 bf = *(const f16x8*)&lS[0][kcL * 8192 + nb * 64 + ((g ^ (nb & 7)) << 3)];
          acc_s[fj] = __builtin_amdgcn_mfma_f32_16x16x32_f16(
              aq[kcL * 2 + (ks >> 5)], bf, acc_s[fj], 0, 0, 0);
        }
    __builtin_amdgcn_s_setprio(0);
    CLOSEB();
    // ---- phase B: S (c 128..255) from buf1; prefetch C (V kt-chunk 0) ----
    STAGE_V(0, kt0, 0);
    WAITB(8);
    __builtin_amdgcn_s_setprio(1);
#pragma unroll
    for (int kcL = 0; kcL < 2; kcL++)
#pragma unroll
      for (int ks = 0; ks < 64; ks += 32)
#pragma unroll
        for (int fj = 0; fj < 8; fj++) {
          int nb = fj * 16 + r16;
          int g = (ks >> 3) + q;
          f16x8 bf = *(const f16x8*)&lS[1][kcL * 8192 + nb * 64 + ((g ^ (nb & 7)) << 3)];
          acc_s[fj] = __builtin_amdgcn_mfma_f32_16x16x32_f16(
              aq[4 + kcL * 2 + (ks >> 5)], bf, acc_s[fj], 0, 0, 0);
        }
    __builtin_amdgcn_s_setprio(0);
    CLOSEB();
    // ---- prefetch D (V kt-chunk 1) so it flies under the softmax VALU ----
    STAGE_V(1, kt0, 1);
    // ---- mask pad keys (only last tile; kTs pad rows are zeros, no NaN) ----
    if (kt0 + 128 > 4356) {
#pragma unroll
      for (int fj = 0; fj < 8; fj++)
        if (kt0 + fj * 16 + r16 >= 4356)
          acc_s[fj] = (f32x4){-1e30f, -1e30f, -1e30f, -1e30f};
    }
    // ---- online softmax; lane owns rows q*4+rr of wave's 16-qt strip ----
    f32x4 pm = acc_s[0];
#pragma unroll
    for (int fj = 1; fj < 8; fj++)
#pragma unroll
      for (int rr = 0; rr < 4; rr++) pm[rr] = fmaxf(pm[rr], acc_s[fj][rr]);
#pragma unroll
    for (int d = 1; d < 16; d <<= 1)
#pragma unroll
      for (int rr = 0; rr < 4; rr++)
        pm[rr] = fmaxf(pm[rr], __shfl_xor(pm[rr], d));
    // T13 defer-max: keep m while tile max grows <= 8; fac = 1.0 exactly then.
    int need = !__all(pm[0] - m_v[0] <= 8.f && pm[1] - m_v[1] <= 8.f &&
                      pm[2] - m_v[2] <= 8.f && pm[3] - m_v[3] <= 8.f);
    f32x4 fac = {1.f, 1.f, 1.f, 1.f};
    if (need) {
#pragma unroll
      for (int rr = 0; rr < 4; rr++) {
        float mn = fmaxf(m_v[rr], pm[rr]);
        fac[rr] = __expf(m_v[rr] - mn);
        m_v[rr] = mn;
        l_v[rr] *= fac[rr];
      }
    }
    if (r16 == 0) *(f32x4*)&lFac[wave * 16 + q * 4] = fac;  // broadcast
    // hp: fj<4 -> lP (kt 0..63); fj>=4 kept in hq regs, written pre-D.
    _Float16 hq[4][4];
    f32x4 rs = {0.f, 0.f, 0.f, 0.f};
#pragma unroll
    for (int fj = 0; fj < 8; fj++)
#pragma unroll
      for (int rr = 0; rr < 4; rr++) {
        _Float16 hp = (_Float16)__expf(acc_s[fj][rr] - m_v[rr]);
        rs[rr] += (float)hp;  // denominator sums the rounded p (consistency)
        int row = wave * 16 + q * 4 + rr;
        if (fj < 4) {
          int c8 = fj * 2 + (r16 >> 3);
          lP[row * 64 + (((c8 ^ (row & 7)) << 3) | (r16 & 7))] = *(const u16*)&hp;
        } else {
          hq[fj - 4][rr] = hp;
        }
      }
#pragma unroll
    for (int d = 1; d < 16; d <<= 1)
#pragma unroll
      for (int rr = 0; rr < 4; rr++) rs[rr] += __shfl_xor(rs[rr], d);
#pragma unroll
    for (int rr = 0; rr < 4; rr++) l_v[rr] += rs[rr];
    // ---- phase C: PV kt 0..63 from buf0; wave owns c [64w, 64w+64) ----
    WAITB(8);  // V0 ready; P(fj<4) + lFac visible (lgkm drained)
    f32x4 facv[4];
#pragma unroll
    for (int mt = 0; mt < 4; mt++)
      facv[mt] = *(const f32x4*)&lFac[mt * 16 + q * 4];
#pragma unroll
    for (int mt = 0; mt < 4; mt++)
#pragma unroll
      for (int fj = 0; fj < 4; fj++)
#pragma unroll
        for (int rr = 0; rr < 4; rr++) acc_o[mt][fj][rr] *= facv[mt][rr];
    __builtin_amdgcn_s_setprio(1);
#pragma unroll
    for (int ks = 0; ks < 64; ks += 32) {
      int k8 = (ks >> 3) + q;
      f16x8 ap[4];
#pragma unroll
      for (int mt = 0; mt < 4; mt++)
        ap[mt] = *(const f16x8*)&lP[(mt * 16 + r16) * 64 + ((k8 ^ (r16 & 7)) << 3)];
#pragma unroll
      for (int fj = 0; fj < 4; fj++) {
        int cr = wave * 64 + fj * 16 + r16;
        f16x8 bv = *(const f16x8*)&lS[0][cr * 64 + ((k8 ^ (cr & 7)) << 3)];
#pragma unroll
        for (int mt = 0; mt < 4; mt++)
          acc_o[mt][fj] = __builtin_amdgcn_mfma_f32_16x16x32_f16(
              ap[mt], bv, acc_o[mt][fj], 0, 0, 0);
      }
    }
    __builtin_amdgcn_s_setprio(0);
    CLOSEB();  // all C-phase lP/lS reads done before refill
    // ---- refill lP with kt 64..127 (hq), prefetch next tile's A ----
#pragma unroll
    for (int fj = 0; fj < 4; fj++)
#pragma unroll
      for (int rr = 0; rr < 4; rr++) {
        int row = wave * 16 + q * 4 + rr;
        int c8 = fj * 2 + (r16 >> 3);
        lP[row * 64 + (((c8 ^ (row & 7)) << 3) | (r16 & 7))] =
            *(const u16*)&hq[fj][rr];
      }
    if (kt0 + 128 < ktEnd) {
      STAGE_K(0, kt0 + 128, 0);
      WAITB(8);  // V1 ready; refilled P visible
    } else {
      WAITB(0);
    }
    __builtin_amdgcn_s_setprio(1);
#pragma unroll
    for (int ks = 0; ks < 64; ks += 32) {
      int k8 = (ks >> 3) + q;
      f16x8 ap[4];
#pragma unroll
      for (int mt = 0; mt < 4; mt++)
        ap[mt] = *(const f16x8*)&lP[(mt * 16 + r16) * 64 + ((k8 ^ (r16 & 7)) << 3)];
#pragma unroll
      for (int fj = 0; fj < 4; fj++) {
        int cr = wave * 64 + fj * 16 + r16;
        f16x8 bv = *(const f16x8*)&lS[1][cr * 64 + ((k8 ^ (cr & 7)) << 3)];
#pragma unroll
        for (int mt = 0; mt < 4; mt++)
          acc_o[mt][fj] = __builtin_amdgcn_mfma_f32_16x16x32_f16(
              ap[mt], bv, acc_o[mt][fj], 0, 0, 0);
      }
    }
    __builtin_amdgcn_s_setprio(0);
    CLOSEB();  // D-phase lP reads done before next tile's softmax writes
  }
#undef STAGE_K
#undef STAGE_V
#undef WAITB
#undef CLOSEB
  // ---- store partials: wave's c-slice for all 64 qt ----
  size_t obase = ((size_t)(h * 4 + b) * 4096 + qt0) * 256;
#pragma unroll
  for (int mt = 0; mt < 4; mt++)
#pragma unroll
    for (int rr = 0; rr < 4; rr++) {
      size_t rowo = obase + (size_t)(mt * 16 + q * 4 + rr) * 256;
#pragma unroll
      for (int fj = 0; fj < 4; fj++)
        Op[rowo + wave * 64 + fj * 16 + r16] = acc_o[mt][fj][rr];
    }
  if (r16 == 0) {
    int base = (h * 4 + b) * 4096 + qt0 + wave * 16 + q * 4;
    *(f32x4*)&ml[base] = m_v;
    *(f32x4*)&ml[32768 + base] = l_v;
  }
}

// ---- 9) merge two kt-half partials, divide, transpose to out[b][c][qt] ----
__global__ __launch_bounds__(256) void k_merge(const float* __restrict__ Op,
                                               const float* __restrict__ ml,
                                               const int* __restrict__ flag,
                                               void* __restrict__ out) {
  __shared__ float th[32][33];
  int b = blockIdx.z, qt0 = blockIdx.x * 32, c0 = blockIdx.y * 32;
  int tx = threadIdx.x, ty = threadIdx.y;
#pragma unroll
  for (int i = 0; i < 4; i++) {
    int qt = qt0 + ty + i * 8;
    float m0 = ml[b * 4096 + qt], m1 = ml[(4 + b) * 4096 + qt];
    float l0 = ml[32768 + b * 4096 + qt], l1 = ml[32768 + (4 + b) * 4096 + qt];
    float M = fmaxf(m0, m1);
    float e0 = __expf(m0 - M), e1 = __expf(m1 - M);
    float inv = 1.f / (l0 * e0 + l1 * e1);  // >= 1, safe
    float v = (Op[((size_t)b * 4096 + qt) * 256 + c0 + tx] * e0 +
               Op[((size_t)(4 + b) * 4096 + qt) * 256 + c0 + tx] * e1) * inv;
    v = (v == v) ? v : 0.f;  // NaN scrub: keep failures diagnostic
    th[ty + i * 8][tx] = v;
  }
  __syncthreads();
#pragma unroll
  for (int i = 0; i < 4; i++) {
    int c = c0 + ty + i * 8, qt = qt0 + tx;
    float v = th[tx][ty + i * 8];
    size_t oidx = ((size_t)b * 256 + c) * 4096 + qt;
    if (flag[0])
      ((float*)out)[oidx] = v;
    else
      ((u16*)out)[oidx] = f2bf(v);
  }
}

// ---- 10) split-K support for conv ----
__global__ __launch_bounds__(256) void k_zeroacc(float* __restrict__ accF) {
  accF[blockIdx.x * 256 + threadIdx.x] = 0.f;
}

// ---------------------------------------------------------------------------
extern "C" void kernel_launch(void* const* d_in, const int* in_sizes, int n_in,
                              void* d_out, int out_size, void* d_ws, size_t ws_size,
                              hipStream_t stream) {
  const void* x = d_in[0];
  const void* Wq = d_in[1];
  const void* gq = d_in[3];
  const void* betaq = d_in[4];
  const void* Wk = d_in[5];
  const void* gk = d_in[7];
  const void* betak = d_in[8];
  const void* Wv = d_in[9];
  const void* gv = d_in[11];
  const void* betav = d_in[12];

  char* ws = (char*)d_ws;
  int* flag = (int*)ws;  // 256 B
  // Region A (conv phase; dead once qTs/kTs/vP built -> overlaid by Opart/ml):
  u16* xbTp = (u16*)(ws + 256);            //  8,921,088
  u16* WqB = (u16*)(ws + 8921344);         //  1,179,648
  u16* WkvB = (u16*)(ws + 10100992);       //    262,144
  float* bufQ = (float*)(ws + 10363136);   // 16,777,216
  float* bufKV = (float*)(ws + 27140352);  // 33,554,432 -> A ends 60,694,784
  u16* qTs = (u16*)(ws + 60694784);        //  8,388,608 (4*4096*256*2)
  u16* kTs = (u16*)(ws + 69083392);        //  9,175,040 (4*4480*256*2)
  u16* vP = (u16*)(ws + 78258432);         //  9,175,040
  float* nrm = (float*)(ws + 87433472);    //      6,144 -> total 87,439,616 B
  // Overlay region A (dead by flash time):
  float* Opart = (float*)(ws + 256);       // 33,554,432 (2*4*4096*256*4)
  float* mlbuf = (float*)(ws + 33554688);  //    262,144 (m: 32768 f, l: 32768 f)

  dim3 b32x8(32, 8);
  k_detect<<<1, 256, 0, stream>>>((const unsigned*)Wq, flag);
  k_txp<<<dim3(137, 8, 4), b32x8, 0, stream>>>(x, flag, xbTp);
  k_wq<<<2304, 256, 0, stream>>>(Wq, flag, WqB);
  k_wkv<<<512, 256, 0, stream>>>(Wk, Wv, flag, WkvB);
  // conv3x3: K=2304 split-K x3 (chunk 768) into zeroed bufQ; 768 blocks (R12).
  k_zeroacc<<<16384, 256, 0, stream>>>(bufQ);
  gemm_bt<true, 1, 2><<<dim3(256, 1, 3), 256, 0, stream>>>(
      WqB, xbTp, bufQ, 256, 16384, 2304, 0, 0, 0, 768, 2, 16, 1, 0, 0, 0);
  // conv1x1: K=256; grid 512 = 8 XCD x (4 tm x 16 tn-band) (R12).
  gemm_bt<true, 0, 2><<<512, 256, 0, stream>>>(
      WkvB, xbTp, bufKV, 512, 16384, 256, 0, 4, 0, 0, 4, 16, 1, 0, 0, 0);
  k_stats<<<dim3(256, 3), 256, 0, stream>>>(bufQ, bufKV, gq, betaq, gk, betak,
                                            gv, betav, flag, nrm);
  k_qTs<<<dim3(128, 8, 4), b32x8, 0, stream>>>(bufQ, nrm, qTs);
  k_kTs<<<dim3(140, 8, 4), b32x8, 0, stream>>>(bufKV, nrm, kTs);
  k_vP<<<dim3(18, 256, 4), 256, 0, stream>>>(bufKV, nrm, vP);
  // fused attention: 512 blocks = 8 XCD-combos x 64 qt tiles, 2 blocks/CU
  k_flash<<<512, 256, 0, stream>>>(qTs, kTs, vP, Opart, mlbuf);
  k_merge<<<dim3(128, 8, 4), b32x8, 0, stream>>>(Opart, mlbuf, flag, d_out);
}

// Round 8
// 325.320 us; speedup vs baseline: 1.2477x; 1.0688x over previous
//
#include <hip/hip_runtime.h>

// ---------------------------------------------------------------------------
// ChannelAttentionLayer on MI355X (gfx950). Input dtype (fp32 vs bf16) is
// DETECTED ON DEVICE (k_detect); core pipeline is FP16 MFMA + fp32 accumulate.
// R18->R19: k_flash kept at R18 (125.7us, PV split by channels — best known;
// further LDS cuts break the 2-blocks/CU budget, analyzed dead end). Conv
// phase: both convs ran at ~12% MfmaUtil / ~34% HBM with a full drain between
// launches -> fused into ONE k_convs dispatch (blocks 0..767 = conv3x3
// splitK x3, 768..1279 = conv1x1; same 32KB-LDS body, occupancy 3) so
// conv1x1 backfills CUs during conv3x3's drain. k_zeroacc launch deleted:
// bufQ zeroing folded into k_wq (had idle thread capacity). gemm_bt
// standalone kernel removed (attention no longer uses it).
// ---------------------------------------------------------------------------

typedef unsigned short u16;
typedef _Float16 f16x8 __attribute__((ext_vector_type(8)));
typedef __attribute__((ext_vector_type(4))) float f32x4;

__device__ __forceinline__ u16 f2h(float f) {
  _Float16 h = (_Float16)f;
  return *(const u16*)&h;
}
__device__ __forceinline__ float bf2f(u16 h) {
  return __uint_as_float(((unsigned)h) << 16);
}
__device__ __forceinline__ float ldin(const void* p, size_t i, int f32) {
  return f32 ? ((const float*)p)[i] : bf2f(((const u16*)p)[i]);
}
__device__ __forceinline__ u16 f2bf(float f) {
  unsigned u = __float_as_uint(f);
  u += 0x7fffu + ((u >> 16) & 1u);
  return (u16)(u >> 16);
}
__device__ __forceinline__ void gld16(const void* g, void* l) {
  __builtin_amdgcn_global_load_lds(
      (const __attribute__((address_space(1))) unsigned int*)g,
      (__attribute__((address_space(3))) unsigned int*)l, 16, 0, 0);
}

// ---- 1) dtype detection on Wq: 2048 sampled words, 8 independent loads ----
__global__ __launch_bounds__(256) void k_detect(const unsigned* __restrict__ w,
                                                int* __restrict__ flag) {
  __shared__ int red[4];
  int tid = threadIdx.x, cnt = 0;
#pragma unroll
  for (int j = 0; j < 8; j++) {
    unsigned e = (w[tid + j * 8192] >> 7) & 0xFFu;
    cnt += (e >= 118u && e <= 127u) ? 1 : 0;
  }
#pragma unroll
  for (int off = 32; off; off >>= 1) cnt += __shfl_down(cnt, off);
  if ((tid & 63) == 0) red[tid >> 6] = cnt;
  __syncthreads();
  if (tid == 0)
    flag[0] = (red[0] + red[1] + red[2] + red[3] < 625) ? 1 : 0;  // 1 = fp32
}

// ---- 2) pad+transpose x -> fp16 [b][66*66 pix][256c], zero border ----
__global__ __launch_bounds__(256) void k_txp(const void* __restrict__ x,
                                             const int* __restrict__ flag,
                                             u16* __restrict__ xbTp) {
  __shared__ float tile[32][33];
  int f32 = flag[0];
  int b = blockIdx.z, p0 = blockIdx.x * 32, c0 = blockIdx.y * 32;
  int tx = threadIdx.x, ty = threadIdx.y;
#pragma unroll
  for (int i = 0; i < 4; i++) {
    int c = c0 + ty + i * 8, pp = p0 + tx;
    float v = 0.f;
    if (pp < 4356) {
      int yy = pp / 66, xx = pp - yy * 66;
      if (yy >= 1 && yy <= 64 && xx >= 1 && xx <= 64)
        v = ldin(x, ((size_t)b * 256 + c) * 4096 + (yy - 1) * 64 + (xx - 1), f32);
    }
    tile[ty + i * 8][tx] = v;
  }
  __syncthreads();
#pragma unroll
  for (int i = 0; i < 4; i++) {
    int pp = p0 + ty + i * 8;
    if (pp >= 4356) continue;
    xbTp[((size_t)b * 4356 + pp) * 256 + c0 + tx] = f2h(tile[tx][ty + i * 8]);
  }
}

// ---- 3) weight reorders (fp16); k_wq also zeroes bufQ (splitK acc) ----
__global__ __launch_bounds__(256) void k_wq(const void* __restrict__ Wq,
                                            const int* __restrict__ flag,
                                            u16* __restrict__ WqB,
                                            float* __restrict__ bufQ) {
  int idx = blockIdx.x * 256 + threadIdx.x;  // 2304*256 threads
  int oc = idx / 2304, rem = idx - oc * 2304;
  int tap = rem >> 8, c = rem & 255;
  WqB[idx] = f2h(ldin(Wq, oc * 2304 + c * 9 + tap, flag[0]));
  // zero bufQ: 4,194,304 floats = 1,048,576 f32x4; 589,824 threads
  f32x4* bz = (f32x4*)bufQ;
  for (int i = idx; i < 1048576; i += 589824)
    bz[i] = (f32x4){0.f, 0.f, 0.f, 0.f};
}
__global__ __launch_bounds__(256) void k_wkv(const void* __restrict__ Wk,
                                             const void* __restrict__ Wv,
                                             const int* __restrict__ flag,
                                             u16* __restrict__ WkvB) {
  int idx = blockIdx.x * 256 + threadIdx.x;  // 512*256
  int m = idx >> 8, c = idx & 255;
  float w = (m < 256) ? ldin(Wk, m * 256 + c, flag[0])
                      : ldin(Wv, (m - 256) * 256 + c, flag[0]);
  WkvB[idx] = f2h(w);
}

// ---- 4) conv GEMM body (fp16): C[M][N] = A . im2col(xbTp) (R6 1-buf) ----
// EPI 0: fp32 store. EPI 1: fp32 atomicAdd (split-K partials into zeroed C).
// SWZ-2 mapping: xcd = lin&7, per = lin>>3; tm = per%sw1, tn = xcd*sw2+per/sw1.
template <int EPI>
__device__ __forceinline__ void gemm_body(
    const u16* __restrict__ A, const u16* __restrict__ Bt,
    float* __restrict__ C, u16* lA, u16* lB, int N, int K, int tapBase,
    int kChunk, int sw1, int sw2, int lin, int kz) {
  int xcd = lin & 7, per = lin >> 3;
  int tm = per % sw1;
  int tn = xcd * sw2 + per / sw1;
  int k0 = 0, k1 = K;
  if (kChunk) {
    k0 = kz * kChunk;
    k1 = min(k0 + kChunk, K);
  }
  const int tid = threadIdx.x, wave = tid >> 6, lane = tid & 63;
  const int sr = lane >> 3;         // source row within 8-row issue group
  const int scw = (lane & 7) ^ sr;  // XOR-swizzled source chunk
  const int wm = (wave >> 1) * 64, wn = (wave & 1) * 64;
  const int r16 = lane & 15, q = lane >> 4;
  const u16* gA = A + (size_t)(tm * 128 + wave * 32 + sr) * K + scw * 8;
  int pyI[4], pxI[4];
  size_t bOffI[4];
#pragma unroll
  for (int i = 0; i < 4; i++) {
    int n = tn * 128 + wave * 32 + i * 8 + sr;  // global output pixel
    int bb = n >> 12, pix = n & 4095;
    pyI[i] = pix >> 6;
    pxI[i] = pix & 63;
    bOffI[i] = (size_t)bb * 4356;
  }
  f32x4 acc[4][4] = {};

  for (int kt = k0; kt < k1; kt += 64) {
    int tap = tapBase + (kt >> 8);
    int chunk = kt & 255;
    int dy = tap / 3, dx = tap - dy * 3;
#pragma unroll
    for (int i = 0; i < 4; i++) {
      gld16(gA + (size_t)(i * 8) * K + kt, &lA[(wave * 32 + i * 8) * 64]);
      int spix = (pyI[i] + dy) * 66 + pxI[i] + dx;
      gld16(Bt + (bOffI[i] + spix) * 256 + chunk + scw * 8,
            &lB[(wave * 32 + i * 8) * 64]);
    }
    __syncthreads();
#pragma unroll
    for (int ks = 0; ks < 64; ks += 32) {
      f16x8 af[4], bfr[4];
#pragma unroll
      for (int f = 0; f < 4; f++) {
        int ma = wm + f * 16 + r16;
        int g = (ks >> 3) + q;
        af[f] = *(const f16x8*)&lA[ma * 64 + ((g ^ (ma & 7)) << 3)];
        int nb = wn + f * 16 + r16;
        bfr[f] = *(const f16x8*)&lB[nb * 64 + ((g ^ (nb & 7)) << 3)];
      }
#pragma unroll
      for (int fi = 0; fi < 4; fi++)
#pragma unroll
        for (int fj = 0; fj < 4; fj++)
          acc[fi][fj] = __builtin_amdgcn_mfma_f32_16x16x32_f16(
              af[fi], bfr[fj], acc[fi][fj], 0, 0, 0);
    }
    __syncthreads();
  }

  const int colB = tn * 128 + wn + r16;
  const int rowB = tm * 128 + wm + q * 4;
  if (EPI == 0) {
#pragma unroll
    for (int fi = 0; fi < 4; fi++)
#pragma unroll
      for (int r = 0; r < 4; r++) {
        size_t ro = (size_t)(rowB + fi * 16 + r) * N;
#pragma unroll
        for (int fj = 0; fj < 4; fj++) C[ro + colB + fj * 16] = acc[fi][fj][r];
      }
  } else {
#pragma unroll
    for (int fi = 0; fi < 4; fi++)
#pragma unroll
      for (int r = 0; r < 4; r++) {
        size_t ro = (size_t)(rowB + fi * 16 + r) * N;
#pragma unroll
        for (int fj = 0; fj < 4; fj++)
          atomicAdd(&C[ro + colB + fj * 16], acc[fi][fj][r]);
      }
  }
}

// Fused conv dispatch: blocks [0,768) = conv3x3 (splitK x3: lin = idx&255,
// kz = idx>>8, matching the old dim3(256,1,3) dispatch order); blocks
// [768,1280) = conv1x1. conv1x1 blocks backfill CUs as conv3x3 retires.
__global__ __launch_bounds__(256, 3) void k_convs(
    const u16* __restrict__ WqB, const u16* __restrict__ WkvB,
    const u16* __restrict__ xbTp, float* __restrict__ bufQ,
    float* __restrict__ bufKV) {
  __shared__ u16 lA[128 * 64];
  __shared__ u16 lB[128 * 64];
  int idx = blockIdx.x;
  if (idx < 768)
    gemm_body<1>(WqB, xbTp, bufQ, lA, lB, 16384, 2304, 0, 768, 2, 16,
                 idx & 255, idx >> 8);
  else
    gemm_body<0>(WkvB, xbTp, bufKV, lA, lB, 16384, 256, 4, 0, 4, 16,
                 idx - 768, 0);
}

// ---- 5) BN stats (biases cancel; K/V border conv-value 0, count 17424) ----
__global__ __launch_bounds__(256) void k_stats(
    const float* __restrict__ bufQ, const float* __restrict__ bufKV,
    const void* __restrict__ gq, const void* __restrict__ betaq,
    const void* __restrict__ gk, const void* __restrict__ betak,
    const void* __restrict__ gv, const void* __restrict__ betav,
    const int* __restrict__ flag, float* __restrict__ nrm) {
  int f32 = flag[0];
  int ch = blockIdx.x, t = blockIdx.y, tid = threadIdx.x;
  const float* row = (t == 0) ? bufQ + (size_t)ch * 16384
                              : bufKV + (size_t)(t == 1 ? ch : 256 + ch) * 16384;
  float s = 0.f, ss = 0.f;
  for (int i = tid; i < 16384; i += 256) {
    float v = row[i];
    s += v;
    ss += v * v;
  }
#pragma unroll
  for (int off = 32; off; off >>= 1) {
    s += __shfl_down(s, off);
    ss += __shfl_down(ss, off);
  }
  __shared__ float ls[4], lss[4];
  if ((tid & 63) == 0) {
    ls[tid >> 6] = s;
    lss[tid >> 6] = ss;
  }
  __syncthreads();
  if (tid == 0) {
    s = ls[0] + ls[1] + ls[2] + ls[3];
    ss = lss[0] + lss[1] + lss[2] + lss[3];
    float cnt = (t == 0) ? 16384.f : 17424.f;
    float mean = s / cnt;
    float var = fmaxf(ss / cnt - mean * mean, 0.f);  // NaN-proof
    const void* g = (t == 0) ? gq : (t == 1 ? gk : gv);
    const void* be = (t == 0) ? betaq : (t == 1 ? betak : betav);
    float sc = ldin(g, ch, f32) * rsqrtf(var + 1e-5f);
    nrm[(t * 256 + ch) * 2] = sc;
    nrm[(t * 256 + ch) * 2 + 1] = ldin(be, ch, f32) - mean * sc;
  }
}

// ---- 6) normalize + transpose to fp16 (K=256 rows) ----
__global__ __launch_bounds__(256) void k_qTs(const float* __restrict__ bufQ,
                                             const float* __restrict__ nrm,
                                             u16* __restrict__ qTs) {
  __shared__ u16 th[32][33];
  int b = blockIdx.z, q0 = blockIdx.x * 32, c0 = blockIdx.y * 32;
  int tx = threadIdx.x, ty = threadIdx.y;
#pragma unroll
  for (int i = 0; i < 4; i++) {
    int c = c0 + ty + i * 8;
    float sc = nrm[c * 2], sh = nrm[c * 2 + 1];
    th[ty + i * 8][tx] =
        f2h(bufQ[(size_t)c * 16384 + b * 4096 + q0 + tx] * sc + sh);
  }
  __syncthreads();
#pragma unroll
  for (int i = 0; i < 4; i++)
    qTs[((size_t)b * 4096 + q0 + ty + i * 8) * 256 + c0 + tx] =
        th[tx][ty + i * 8];
}
__global__ __launch_bounds__(256) void k_kTs(const float* __restrict__ bufKV,
                                             const float* __restrict__ nrm,
                                             u16* __restrict__ kTs) {
  __shared__ u16 th[32][33];
  int b = blockIdx.z, k0 = blockIdx.x * 32, c0 = blockIdx.y * 32;
  int tx = threadIdx.x, ty = threadIdx.y;
#pragma unroll
  for (int i = 0; i < 4; i++) {
    int c = c0 + ty + i * 8;
    int kt = k0 + tx;
    float v = 0.f;
    if (kt < 4356) {
      float sc = nrm[(256 + c) * 2], sh = nrm[(256 + c) * 2 + 1];
      int yy = kt / 66, xx = kt - yy * 66;
      if (yy >= 1 && yy <= 64 && xx >= 1 && xx <= 64)
        v = bufKV[(size_t)c * 16384 + b * 4096 + (yy - 1) * 64 + (xx - 1)] * sc + sh;
      else
        v = sh;  // border: conv value 0
    }
    th[ty + i * 8][tx] = f2h(v);  // kt >= 4356 rows -> exact zeros
  }
  __syncthreads();
#pragma unroll
  for (int i = 0; i < 4; i++)
    kTs[((size_t)b * 4480 + k0 + ty + i * 8) * 256 + c0 + tx] =
        th[tx][ty + i * 8];
}

// ---- 7) normalized V fp16, [b][c][4480], pads zero ----
__global__ __launch_bounds__(256) void k_vP(const float* __restrict__ bufKV,
                                            const float* __restrict__ nrm,
                                            u16* __restrict__ vP) {
  int b = blockIdx.z, ch = blockIdx.y;
  int kt = blockIdx.x * 256 + threadIdx.x;
  if (kt >= 4480) return;
  float v = 0.f;
  if (kt < 4356) {
    float sc = nrm[(512 + ch) * 2], sh = nrm[(512 + ch) * 2 + 1];
    int yy = kt / 66, xx = kt - yy * 66;
    if (yy >= 1 && yy <= 64 && xx >= 1 && xx <= 64)
      v = bufKV[(size_t)(256 + ch) * 16384 + b * 4096 + (yy - 1) * 64 + (xx - 1)] * sc + sh;
    else
      v = sh;
  }
  vP[((size_t)b * 256 + ch) * 4480 + kt] = f2h(v);
}

// ---- 8) fused flash attention, 2-deep pipelined, PV split by CHANNELS ----
// grid 512 linear: xcd = lin&7 pins (h = xcd&1, b = xcd>>1) per XCD; per->qt.
// S phase (per tile halves A/B) and softmax: per-wave 16 qt (R13, unchanged).
// PV (phases C/D): wave w owns c [64w,64w+64) x ALL 64 qt -> V-frags are
// wave-unique (reads 272->128/tile). P crosses waves via lP (8KB half-tile:
// fj<4 written in softmax, fj>=4 kept in hq[] regs, refilled after C).
// Rescale fac broadcast via lFac[64]; fac==1.0 exact when defer-max skips.
// WAITB drains lgkmcnt(0) so cross-wave ds_writes are visible post-barrier.
__global__ __launch_bounds__(256, 2) void k_flash(
    const u16* __restrict__ qTs, const u16* __restrict__ kTs,
    const u16* __restrict__ vP, float* __restrict__ Op,
    float* __restrict__ ml) {
  __shared__ u16 lS[2][16384];  // 2 x 32KB staging (K-half or V-chunk)
  __shared__ u16 lP[64 * 64];   // 8KB P half-tile (64 qt x 64 kt), swizzled
  __shared__ float lFac[64];    // per-qt-row rescale factor broadcast
  const int lin = blockIdx.x;
  const int xcd = lin & 7, per = lin >> 3;
  const int h = xcd & 1, b = xcd >> 1;
  const int qt0 = per * 64;
  const int tid = threadIdx.x, wave = tid >> 6, lane = tid & 63;
  const int sr = lane >> 3, scw = (lane & 7) ^ sr;
  const int r16 = lane & 15, q = lane >> 4;

  // Q fragments in registers: aq[kk] = Q[qt0+wave*16+r16][kk*32 + q*8 ..+7]
  const u16* gQ = qTs + ((size_t)b * 4096 + qt0 + wave * 16 + r16) * 256;
  f16x8 aq[8];
#pragma unroll
  for (int kk = 0; kk < 8; kk++) aq[kk] = *(const f16x8*)&gQ[kk * 32 + q * 8];
  // drain Q loads so in-loop vmcnt counting is exact (one-time cost)
  asm volatile("s_waitcnt vmcnt(0)" ::: "memory");

  const u16* gK = kTs + (size_t)b * 4480 * 256 + (size_t)(wave * 32 + sr) * 256 + scw * 8;
  const u16* gV = vP + ((size_t)b * 256 + wave * 64 + sr) * 4480 + scw * 8;

// 8 gld16/thread per stage (32KB/block). K half c2: rows=kt, 2 kcL chunks.
#define STAGE_K(buf, kt, c2)                                                 \
  {                                                                          \
    _Pragma("unroll") for (int i = 0; i < 4; i++) {                          \
      const u16* src = gK + (size_t)((kt) + i * 8) * 256 + (c2) * 128;       \
      gld16(src, &lS[buf][(wave * 32 + i * 8) * 64]);                        \
      gld16(src + 64, &lS[buf][8192 + (wave * 32 + i * 8) * 64]);            \
    }                                                                        \
  }
#define STAGE_V(buf, kt, vc)                                                 \
  {                                                                          \
    _Pragma("unroll") for (int i = 0; i < 8; i++)                            \
        gld16(gV + (size_t)(i * 8) * 4480 + (kt) + (vc) * 64,                \
              &lS[buf][(wave * 64 + i * 8) * 64]);                           \
  }
#define WAITB(n)                                                             \
  asm volatile("s_waitcnt vmcnt(" #n ") lgkmcnt(0)" ::: "memory");           \
  __builtin_amdgcn_s_barrier();                                              \
  __builtin_amdgcn_sched_barrier(0);
#define CLOSEB()                                                             \
  __builtin_amdgcn_sched_barrier(0);                                         \
  asm volatile("s_waitcnt lgkmcnt(0)" ::: "memory");                         \
  __builtin_amdgcn_s_barrier();

  // acc_o[mt][fj]: qt-tile mt (rows mt*16+q*4+rr), c-tile fj (wave*64+fj*16+r16)
  f32x4 acc_o[4][4];
#pragma unroll
  for (int mt = 0; mt < 4; mt++)
#pragma unroll
    for (int fj = 0; fj < 4; fj++) acc_o[mt][fj] = (f32x4){0.f, 0.f, 0.f, 0.f};
  f32x4 m_v = {-3e38f, -3e38f, -3e38f, -3e38f};
  f32x4 l_v = {0.f, 0.f, 0.f, 0.f};

  const int ktBeg = h ? 2304 : 0, ktEnd = h ? 4480 : 2304;
  STAGE_K(0, ktBeg, 0);  // prologue: phase A of first tile
  for (int kt0 = ktBeg; kt0 < ktEnd; kt0 += 128) {
    f32x4 acc_s[8];
#pragma unroll
    for (int i = 0; i < 8; i++) acc_s[i] = (f32x4){0.f, 0.f, 0.f, 0.f};
    // ---- phase A: S (c 0..127) from buf0; prefetch B ----
    STAGE_K(1, kt0, 1);
    WAITB(8);
    __builtin_amdgcn_s_setprio(1);
#pragma unroll
    for (int kcL = 0; kcL < 2; kcL++)
#pragma unroll
      for (int ks = 0; ks < 64; ks += 32)
#pragma unroll
        for (int fj = 0; fj < 8; fj++) {
          int nb = fj * 16 + r16;
          int g = (ks >> 3) + q;
          f16x8 bf = *(const f16x8*)&lS[0][kcL * 8192 + nb * 64 + ((g ^ (nb & 7)) << 3)];
          acc_s[fj] = __builtin_amdgcn_mfma_f32_16x16x32_f16(
              aq[kcL * 2 + (ks >> 5)], bf, acc_s[fj], 0, 0, 0);
        }
    __builtin_amdgcn_s_setprio(0);
    CLOSEB();
    // ---- phase B: S (c 128..255) from buf1; prefetch C (V kt-chunk 0) ----
    STAGE_V(0, kt0, 0);
    WAITB(8);
    __builtin_amdgcn_s_setprio(1);
#pragma unroll
    for (int kcL = 0; kcL < 2; kcL++)
#pragma unroll
      for (int ks = 0; ks < 64; ks += 32)
#pragma unroll
        for (int fj = 0; fj < 8; fj++) {
          int nb = fj * 16 + r16;
          int g = (ks >> 3) + q;
          f16x8 bf = *(const f16x8*)&lS[1][kcL * 8192 + nb * 64 + ((g ^ (nb & 7)) << 3)];
          acc_s[fj] = __builtin_amdgcn_mfma_f32_16x16x32_f16(
              aq[4 + kcL * 2 + (ks >> 5)], bf, acc_s[fj], 0, 0, 0);
        }
    __builtin_amdgcn_s_setprio(0);
    CLOSEB();
    // ---- prefetch D (V kt-chunk 1) so it flies under the softmax VALU ----
    STAGE_V(1, kt0, 1);
    // ---- mask pad keys (only last tile; kTs pad rows are zeros, no NaN) ----
    if (kt0 + 128 > 4356) {
#pragma unroll
      for (int fj = 0; fj < 8; fj++)
        if (kt0 + fj * 16 + r16 >= 4356)
          acc_s[fj] = (f32x4){-1e30f, -1e30f, -1e30f, -1e30f};
    }
    // ---- online softmax; lane owns rows q*4+rr of wave's 16-qt strip ----
    f32x4 pm = acc_s[0];
#pragma unroll
    for (int fj = 1; fj < 8; fj++)
#pragma unroll
      for (int rr = 0; rr < 4; rr++) pm[rr] = fmaxf(pm[rr], acc_s[fj][rr]);
#pragma unroll
    for (int d = 1; d < 16; d <<= 1)
#pragma unroll
      for (int rr = 0; rr < 4; rr++)
        pm[rr] = fmaxf(pm[rr], __shfl_xor(pm[rr], d));
    // T13 defer-max: keep m while tile max grows <= 8; fac = 1.0 exactly then.
    int need = !__all(pm[0] - m_v[0] <= 8.f && pm[1] - m_v[1] <= 8.f &&
                      pm[2] - m_v[2] <= 8.f && pm[3] - m_v[3] <= 8.f);
    f32x4 fac = {1.f, 1.f, 1.f, 1.f};
    if (need) {
#pragma unroll
      for (int rr = 0; rr < 4; rr++) {
        float mn = fmaxf(m_v[rr], pm[rr]);
        fac[rr] = __expf(m_v[rr] - mn);
        m_v[rr] = mn;
        l_v[rr] *= fac[rr];
      }
    }
    if (r16 == 0) *(f32x4*)&lFac[wave * 16 + q * 4] = fac;  // broadcast
    // hp: fj<4 -> lP (kt 0..63); fj>=4 kept in hq regs, written pre-D.
    _Float16 hq[4][4];
    f32x4 rs = {0.f, 0.f, 0.f, 0.f};
#pragma unroll
    for (int fj = 0; fj < 8; fj++)
#pragma unroll
      for (int rr = 0; rr < 4; rr++) {
        _Float16 hp = (_Float16)__expf(acc_s[fj][rr] - m_v[rr]);
        rs[rr] += (float)hp;  // denominator sums the rounded p (consistency)
        int row = wave * 16 + q * 4 + rr;
        if (fj < 4) {
          int c8 = fj * 2 + (r16 >> 3);
          lP[row * 64 + (((c8 ^ (row & 7)) << 3) | (r16 & 7))] = *(const u16*)&hp;
        } else {
          hq[fj - 4][rr] = hp;
        }
      }
#pragma unroll
    for (int d = 1; d < 16; d <<= 1)
#pragma unroll
      for (int rr = 0; rr < 4; rr++) rs[rr] += __shfl_xor(rs[rr], d);
#pragma unroll
    for (int rr = 0; rr < 4; rr++) l_v[rr] += rs[rr];
    // ---- phase C: PV kt 0..63 from buf0; wave owns c [64w, 64w+64) ----
    WAITB(8);  // V0 ready; P(fj<4) + lFac visible (lgkm drained)
    f32x4 facv[4];
#pragma unroll
    for (int mt = 0; mt < 4; mt++)
      facv[mt] = *(const f32x4*)&lFac[mt * 16 + q * 4];
#pragma unroll
    for (int mt = 0; mt < 4; mt++)
#pragma unroll
      for (int fj = 0; fj < 4; fj++)
#pragma unroll
        for (int rr = 0; rr < 4; rr++) acc_o[mt][fj][rr] *= facv[mt][rr];
    __builtin_amdgcn_s_setprio(1);
#pragma unroll
    for (int ks = 0; ks < 64; ks += 32) {
      int k8 = (ks >> 3) + q;
      f16x8 ap[4];
#pragma unroll
      for (int mt = 0; mt < 4; mt++)
        ap[mt] = *(const f16x8*)&lP[(mt * 16 + r16) * 64 + ((k8 ^ (r16 & 7)) << 3)];
#pragma unroll
      for (int fj = 0; fj < 4; fj++) {
        int cr = wave * 64 + fj * 16 + r16;
        f16x8 bv = *(const f16x8*)&lS[0][cr * 64 + ((k8 ^ (cr & 7)) << 3)];
#pragma unroll
        for (int mt = 0; mt < 4; mt++)
          acc_o[mt][fj] = __builtin_amdgcn_mfma_f32_16x16x32_f16(
              ap[mt], bv, acc_o[mt][fj], 0, 0, 0);
      }
    }
    __builtin_amdgcn_s_setprio(0);
    CLOSEB();  // all C-phase lP/lS reads done before refill
    // ---- refill lP with kt 64..127 (hq), prefetch next tile's A ----
#pragma unroll
    for (int fj = 0; fj < 4; fj++)
#pragma unroll
      for (int rr = 0; rr < 4; rr++) {
        int row = wave * 16 + q * 4 + rr;
        int c8 = fj * 2 + (r16 >> 3);
        lP[row * 64 + (((c8 ^ (row & 7)) << 3) | (r16 & 7))] =
            *(const u16*)&hq[fj][rr];
      }
    if (kt0 + 128 < ktEnd) {
      STAGE_K(0, kt0 + 128, 0);
      WAITB(8);  // V1 ready; refilled P visible
    } else {
      WAITB(0);
    }
    __builtin_amdgcn_s_setprio(1);
#pragma unroll
    for (int ks = 0; ks < 64; ks += 32) {
      int k8 = (ks >> 3) + q;
      f16x8 ap[4];
#pragma unroll
      for (int mt = 0; mt < 4; mt++)
        ap[mt] = *(const f16x8*)&lP[(mt * 16 + r16) * 64 + ((k8 ^ (r16 & 7)) << 3)];
#pragma unroll
      for (int fj = 0; fj < 4; fj++) {
        int cr = wave * 64 + fj * 16 + r16;
        f16x8 bv = *(const f16x8*)&lS[1][cr * 64 + ((k8 ^ (cr & 7)) << 3)];
#pragma unroll
        for (int mt = 0; mt < 4; mt++)
          acc_o[mt][fj] = __builtin_amdgcn_mfma_f32_16x16x32_f16(
              ap[mt], bv, acc_o[mt][fj], 0, 0, 0);
      }
    }
    __builtin_amdgcn_s_setprio(0);
    CLOSEB();  // D-phase lP reads done before next tile's softmax writes
  }
#undef STAGE_K
#undef STAGE_V
#undef WAITB
#undef CLOSEB
  // ---- store partials: wave's c-slice for all 64 qt ----
  size_t obase = ((size_t)(h * 4 + b) * 4096 + qt0) * 256;
#pragma unroll
  for (int mt = 0; mt < 4; mt++)
#pragma unroll
    for (int rr = 0; rr < 4; rr++) {
      size_t rowo = obase + (size_t)(mt * 16 + q * 4 + rr) * 256;
#pragma unroll
      for (int fj = 0; fj < 4; fj++)
        Op[rowo + wave * 64 + fj * 16 + r16] = acc_o[mt][fj][rr];
    }
  if (r16 == 0) {
    int base = (h * 4 + b) * 4096 + qt0 + wave * 16 + q * 4;
    *(f32x4*)&ml[base] = m_v;
    *(f32x4*)&ml[32768 + base] = l_v;
  }
}

// ---- 9) merge two kt-half partials, divide, transpose to out[b][c][qt] ----
__global__ __launch_bounds__(256) void k_merge(const float* __restrict__ Op,
                                               const float* __restrict__ ml,
                                               const int* __restrict__ flag,
                                               void* __restrict__ out) {
  __shared__ float th[32][33];
  int b = blockIdx.z, qt0 = blockIdx.x * 32, c0 = blockIdx.y * 32;
  int tx = threadIdx.x, ty = threadIdx.y;
#pragma unroll
  for (int i = 0; i < 4; i++) {
    int qt = qt0 + ty + i * 8;
    float m0 = ml[b * 4096 + qt], m1 = ml[(4 + b) * 4096 + qt];
    float l0 = ml[32768 + b * 4096 + qt], l1 = ml[32768 + (4 + b) * 4096 + qt];
    float M = fmaxf(m0, m1);
    float e0 = __expf(m0 - M), e1 = __expf(m1 - M);
    float inv = 1.f / (l0 * e0 + l1 * e1);  // >= 1, safe
    float v = (Op[((size_t)b * 4096 + qt) * 256 + c0 + tx] * e0 +
               Op[((size_t)(4 + b) * 4096 + qt) * 256 + c0 + tx] * e1) * inv;
    v = (v == v) ? v : 0.f;  // NaN scrub: keep failures diagnostic
    th[ty + i * 8][tx] = v;
  }
  __syncthreads();
#pragma unroll
  for (int i = 0; i < 4; i++) {
    int c = c0 + ty + i * 8, qt = qt0 + tx;
    float v = th[tx][ty + i * 8];
    size_t oidx = ((size_t)b * 256 + c) * 4096 + qt;
    if (flag[0])
      ((float*)out)[oidx] = v;
    else
      ((u16*)out)[oidx] = f2bf(v);
  }
}

// ---------------------------------------------------------------------------
extern "C" void kernel_launch(void* const* d_in, const int* in_sizes, int n_in,
                              void* d_out, int out_size, void* d_ws, size_t ws_size,
                              hipStream_t stream) {
  const void* x = d_in[0];
  const void* Wq = d_in[1];
  const void* gq = d_in[3];
  const void* betaq = d_in[4];
  const void* Wk = d_in[5];
  const void* gk = d_in[7];
  const void* betak = d_in[8];
  const void* Wv = d_in[9];
  const void* gv = d_in[11];
  const void* betav = d_in[12];

  char* ws = (char*)d_ws;
  int* flag = (int*)ws;  // 256 B
  // Region A (conv phase; dead once qTs/kTs/vP built -> overlaid by Opart/ml):
  u16* xbTp = (u16*)(ws + 256);            //  8,921,088
  u16* WqB = (u16*)(ws + 8921344);         //  1,179,648
  u16* WkvB = (u16*)(ws + 10100992);       //    262,144
  float* bufQ = (float*)(ws + 10363136);   // 16,777,216
  float* bufKV = (float*)(ws + 27140352);  // 33,554,432 -> A ends 60,694,784
  u16* qTs = (u16*)(ws + 60694784);        //  8,388,608 (4*4096*256*2)
  u16* kTs = (u16*)(ws + 69083392);        //  9,175,040 (4*4480*256*2)
  u16* vP = (u16*)(ws + 78258432);         //  9,175,040
  float* nrm = (float*)(ws + 87433472);    //      6,144 -> total 87,439,616 B
  // Overlay region A (dead by flash time):
  float* Opart = (float*)(ws + 256);       // 33,554,432 (2*4*4096*256*4)
  float* mlbuf = (float*)(ws + 33554688);  //    262,144 (m: 32768 f, l: 32768 f)

  dim3 b32x8(32, 8);
  k_detect<<<1, 256, 0, stream>>>((const unsigned*)Wq, flag);
  k_txp<<<dim3(137, 8, 4), b32x8, 0, stream>>>(x, flag, xbTp);
  k_wq<<<2304, 256, 0, stream>>>(Wq, flag, WqB, bufQ);  // also zeroes bufQ
  k_wkv<<<512, 256, 0, stream>>>(Wk, Wv, flag, WkvB);
  // fused convs: [0,768) conv3x3 splitK x3 into zeroed bufQ; [768,1280) 1x1.
  k_convs<<<1280, 256, 0, stream>>>(WqB, WkvB, xbTp, bufQ, bufKV);
  k_stats<<<dim3(256, 3), 256, 0, stream>>>(bufQ, bufKV, gq, betaq, gk, betak,
                                            gv, betav, flag, nrm);
  k_qTs<<<dim3(128, 8, 4), b32x8, 0, stream>>>(bufQ, nrm, qTs);
  k_kTs<<<dim3(140, 8, 4), b32x8, 0, stream>>>(bufKV, nrm, kTs);
  k_vP<<<dim3(18, 256, 4), 256, 0, stream>>>(bufKV, nrm, vP);
  // fused attention: 512 blocks = 8 XCD-combos x 64 qt tiles, 2 blocks/CU
  k_flash<<<512, 256, 0, stream>>>(qTs, kTs, vP, Opart, mlbuf);
  k_merge<<<dim3(128, 8, 4), b32x8, 0, stream>>>(Opart, mlbuf, flag, d_out);
}

// Round 9
// 321.543 us; speedup vs baseline: 1.2623x; 1.0117x over previous
//
#include <hip/hip_runtime.h>

// ---------------------------------------------------------------------------
// ChannelAttentionLayer on MI355X (gfx950). Input dtype (fp32 vs bf16) is
// DETECTED ON DEVICE (k_detect); core pipeline is FP16 MFMA + fp32 accumulate.
// R19->R20: tail consolidation. The ~128us non-conv tail was 8 small
// dispatches with serialization: (a) txp/wq/wkv are mutually independent ->
// fused into ONE k_prep dispatch (7200 blocks, branch by range); (b)
// qTs/kTs/vP fused into ONE k_norm dispatch (10816 blocks); vP branch
// vectorized x8 (16B stores, 18432->2240 blocks); (c) k_stats loads f32x4.
// Dispatches 10 -> 7. k_flash (125-127us, PV-by-channels) and k_convs
// (fused conv3x3 splitK x3 + conv1x1) byte-identical to R19.
// ---------------------------------------------------------------------------

typedef unsigned short u16;
typedef _Float16 f16x8 __attribute__((ext_vector_type(8)));
typedef __attribute__((ext_vector_type(4))) float f32x4;
typedef __attribute__((ext_vector_type(8))) unsigned short u16x8;

__device__ __forceinline__ u16 f2h(float f) {
  _Float16 h = (_Float16)f;
  return *(const u16*)&h;
}
__device__ __forceinline__ float bf2f(u16 h) {
  return __uint_as_float(((unsigned)h) << 16);
}
__device__ __forceinline__ float ldin(const void* p, size_t i, int f32) {
  return f32 ? ((const float*)p)[i] : bf2f(((const u16*)p)[i]);
}
__device__ __forceinline__ u16 f2bf(float f) {
  unsigned u = __float_as_uint(f);
  u += 0x7fffu + ((u >> 16) & 1u);
  return (u16)(u >> 16);
}
__device__ __forceinline__ void gld16(const void* g, void* l) {
  __builtin_amdgcn_global_load_lds(
      (const __attribute__((address_space(1))) unsigned int*)g,
      (__attribute__((address_space(3))) unsigned int*)l, 16, 0, 0);
}

// ---- 1) dtype detection on Wq: 2048 sampled words, 8 independent loads ----
__global__ __launch_bounds__(256) void k_detect(const unsigned* __restrict__ w,
                                                int* __restrict__ flag) {
  __shared__ int red[4];
  int tid = threadIdx.x, cnt = 0;
#pragma unroll
  for (int j = 0; j < 8; j++) {
    unsigned e = (w[tid + j * 8192] >> 7) & 0xFFu;
    cnt += (e >= 118u && e <= 127u) ? 1 : 0;
  }
#pragma unroll
  for (int off = 32; off; off >>= 1) cnt += __shfl_down(cnt, off);
  if ((tid & 63) == 0) red[tid >> 6] = cnt;
  __syncthreads();
  if (tid == 0)
    flag[0] = (red[0] + red[1] + red[2] + red[3] < 625) ? 1 : 0;  // 1 = fp32
}

// ---- 2) fused prep: [0,4384) txp | [4384,6688) wq+zero | [6688,7200) wkv ---
// txp: pad+transpose x -> fp16 [b][66*66 pix][256c], zero border.
// wq: Wq reorder to [oc][tap][c] fp16 + zero bufQ (splitK accumulator).
// wkv: Wk/Wv reorder to [m][c] fp16. All three are independent -> backfill.
__global__ __launch_bounds__(256) void k_prep(
    const void* __restrict__ x, const void* __restrict__ Wq,
    const void* __restrict__ Wk, const void* __restrict__ Wv,
    const int* __restrict__ flag, u16* __restrict__ xbTp,
    u16* __restrict__ WqB, u16* __restrict__ WkvB, float* __restrict__ bufQ) {
  __shared__ float tile[32][33];
  const int blk = blockIdx.x, tid = threadIdx.x;
  const int f32 = flag[0];
  if (blk < 4384) {
    int u = blk;
    int p0 = (u % 137) * 32;
    u /= 137;
    int c0 = (u % 8) * 32;
    int b = u / 8;
    int tx = tid & 31, ty = tid >> 5;
#pragma unroll
    for (int i = 0; i < 4; i++) {
      int c = c0 + ty + i * 8, pp = p0 + tx;
      float v = 0.f;
      if (pp < 4356) {
        int yy = pp / 66, xx = pp - yy * 66;
        if (yy >= 1 && yy <= 64 && xx >= 1 && xx <= 64)
          v = ldin(x, ((size_t)b * 256 + c) * 4096 + (yy - 1) * 64 + (xx - 1), f32);
      }
      tile[ty + i * 8][tx] = v;
    }
    __syncthreads();
#pragma unroll
    for (int i = 0; i < 4; i++) {
      int pp = p0 + ty + i * 8;
      if (pp >= 4356) continue;
      xbTp[((size_t)b * 4356 + pp) * 256 + c0 + tx] = f2h(tile[tx][ty + i * 8]);
    }
  } else if (blk < 6688) {
    int idx = (blk - 4384) * 256 + tid;  // 2304*256
    int oc = idx / 2304, rem = idx - oc * 2304;
    int tap = rem >> 8, c = rem & 255;
    WqB[idx] = f2h(ldin(Wq, oc * 2304 + c * 9 + tap, f32));
    // zero bufQ: 1,048,576 f32x4 over 589,824 threads
    f32x4* bz = (f32x4*)bufQ;
    for (int i = idx; i < 1048576; i += 589824)
      bz[i] = (f32x4){0.f, 0.f, 0.f, 0.f};
  } else {
    int idx = (blk - 6688) * 256 + tid;  // 512*256
    int m = idx >> 8, c = idx & 255;
    float w = (m < 256) ? ldin(Wk, m * 256 + c, f32)
                        : ldin(Wv, (m - 256) * 256 + c, f32);
    WkvB[idx] = f2h(w);
  }
}

// ---- 4) conv GEMM body (fp16): C[M][N] = A . im2col(xbTp) (R6 1-buf) ----
// EPI 0: fp32 store. EPI 1: fp32 atomicAdd (split-K partials into zeroed C).
// SWZ-2 mapping: xcd = lin&7, per = lin>>3; tm = per%sw1, tn = xcd*sw2+per/sw1.
template <int EPI>
__device__ __forceinline__ void gemm_body(
    const u16* __restrict__ A, const u16* __restrict__ Bt,
    float* __restrict__ C, u16* lA, u16* lB, int N, int K, int tapBase,
    int kChunk, int sw1, int sw2, int lin, int kz) {
  int xcd = lin & 7, per = lin >> 3;
  int tm = per % sw1;
  int tn = xcd * sw2 + per / sw1;
  int k0 = 0, k1 = K;
  if (kChunk) {
    k0 = kz * kChunk;
    k1 = min(k0 + kChunk, K);
  }
  const int tid = threadIdx.x, wave = tid >> 6, lane = tid & 63;
  const int sr = lane >> 3;         // source row within 8-row issue group
  const int scw = (lane & 7) ^ sr;  // XOR-swizzled source chunk
  const int wm = (wave >> 1) * 64, wn = (wave & 1) * 64;
  const int r16 = lane & 15, q = lane >> 4;
  const u16* gA = A + (size_t)(tm * 128 + wave * 32 + sr) * K + scw * 8;
  int pyI[4], pxI[4];
  size_t bOffI[4];
#pragma unroll
  for (int i = 0; i < 4; i++) {
    int n = tn * 128 + wave * 32 + i * 8 + sr;  // global output pixel
    int bb = n >> 12, pix = n & 4095;
    pyI[i] = pix >> 6;
    pxI[i] = pix & 63;
    bOffI[i] = (size_t)bb * 4356;
  }
  f32x4 acc[4][4] = {};

  for (int kt = k0; kt < k1; kt += 64) {
    int tap = tapBase + (kt >> 8);
    int chunk = kt & 255;
    int dy = tap / 3, dx = tap - dy * 3;
#pragma unroll
    for (int i = 0; i < 4; i++) {
      gld16(gA + (size_t)(i * 8) * K + kt, &lA[(wave * 32 + i * 8) * 64]);
      int spix = (pyI[i] + dy) * 66 + pxI[i] + dx;
      gld16(Bt + (bOffI[i] + spix) * 256 + chunk + scw * 8,
            &lB[(wave * 32 + i * 8) * 64]);
    }
    __syncthreads();
#pragma unroll
    for (int ks = 0; ks < 64; ks += 32) {
      f16x8 af[4], bfr[4];
#pragma unroll
      for (int f = 0; f < 4; f++) {
        int ma = wm + f * 16 + r16;
        int g = (ks >> 3) + q;
        af[f] = *(const f16x8*)&lA[ma * 64 + ((g ^ (ma & 7)) << 3)];
        int nb = wn + f * 16 + r16;
        bfr[f] = *(const f16x8*)&lB[nb * 64 + ((g ^ (nb & 7)) << 3)];
      }
#pragma unroll
      for (int fi = 0; fi < 4; fi++)
#pragma unroll
        for (int fj = 0; fj < 4; fj++)
          acc[fi][fj] = __builtin_amdgcn_mfma_f32_16x16x32_f16(
              af[fi], bfr[fj], acc[fi][fj], 0, 0, 0);
    }
    __syncthreads();
  }

  const int colB = tn * 128 + wn + r16;
  const int rowB = tm * 128 + wm + q * 4;
  if (EPI == 0) {
#pragma unroll
    for (int fi = 0; fi < 4; fi++)
#pragma unroll
      for (int r = 0; r < 4; r++) {
        size_t ro = (size_t)(rowB + fi * 16 + r) * N;
#pragma unroll
        for (int fj = 0; fj < 4; fj++) C[ro + colB + fj * 16] = acc[fi][fj][r];
      }
  } else {
#pragma unroll
    for (int fi = 0; fi < 4; fi++)
#pragma unroll
      for (int r = 0; r < 4; r++) {
        size_t ro = (size_t)(rowB + fi * 16 + r) * N;
#pragma unroll
        for (int fj = 0; fj < 4; fj++)
          atomicAdd(&C[ro + colB + fj * 16], acc[fi][fj][r]);
      }
  }
}

// Fused conv dispatch: blocks [0,768) = conv3x3 (splitK x3: lin = idx&255,
// kz = idx>>8); blocks [768,1280) = conv1x1 (backfills as conv3x3 retires).
__global__ __launch_bounds__(256, 3) void k_convs(
    const u16* __restrict__ WqB, const u16* __restrict__ WkvB,
    const u16* __restrict__ xbTp, float* __restrict__ bufQ,
    float* __restrict__ bufKV) {
  __shared__ u16 lA[128 * 64];
  __shared__ u16 lB[128 * 64];
  int idx = blockIdx.x;
  if (idx < 768)
    gemm_body<1>(WqB, xbTp, bufQ, lA, lB, 16384, 2304, 0, 768, 2, 16,
                 idx & 255, idx >> 8);
  else
    gemm_body<0>(WkvB, xbTp, bufKV, lA, lB, 16384, 256, 4, 0, 4, 16,
                 idx - 768, 0);
}

// ---- 5) BN stats (biases cancel; K/V border conv-value 0, count 17424) ----
__global__ __launch_bounds__(256) void k_stats(
    const float* __restrict__ bufQ, const float* __restrict__ bufKV,
    const void* __restrict__ gq, const void* __restrict__ betaq,
    const void* __restrict__ gk, const void* __restrict__ betak,
    const void* __restrict__ gv, const void* __restrict__ betav,
    const int* __restrict__ flag, float* __restrict__ nrm) {
  int f32 = flag[0];
  int ch = blockIdx.x, t = blockIdx.y, tid = threadIdx.x;
  const float* row = (t == 0) ? bufQ + (size_t)ch * 16384
                              : bufKV + (size_t)(t == 1 ? ch : 256 + ch) * 16384;
  const f32x4* row4 = (const f32x4*)row;
  float s = 0.f, ss = 0.f;
  for (int i = tid; i < 4096; i += 256) {
    f32x4 v = row4[i];
    s += v[0] + v[1] + v[2] + v[3];
    ss += v[0] * v[0] + v[1] * v[1] + v[2] * v[2] + v[3] * v[3];
  }
#pragma unroll
  for (int off = 32; off; off >>= 1) {
    s += __shfl_down(s, off);
    ss += __shfl_down(ss, off);
  }
  __shared__ float ls[4], lss[4];
  if ((tid & 63) == 0) {
    ls[tid >> 6] = s;
    lss[tid >> 6] = ss;
  }
  __syncthreads();
  if (tid == 0) {
    s = ls[0] + ls[1] + ls[2] + ls[3];
    ss = lss[0] + lss[1] + lss[2] + lss[3];
    float cnt = (t == 0) ? 16384.f : 17424.f;
    float mean = s / cnt;
    float var = fmaxf(ss / cnt - mean * mean, 0.f);  // NaN-proof
    const void* g = (t == 0) ? gq : (t == 1 ? gk : gv);
    const void* be = (t == 0) ? betaq : (t == 1 ? betak : betav);
    float sc = ldin(g, ch, f32) * rsqrtf(var + 1e-5f);
    nrm[(t * 256 + ch) * 2] = sc;
    nrm[(t * 256 + ch) * 2 + 1] = ldin(be, ch, f32) - mean * sc;
  }
}

// ---- 6) fused normalize: [0,4096) qTs | [4096,8576) kTs | [8576,10816) vP --
// qTs/kTs: normalize + 32x32 LDS transpose to fp16 [b][tok][c].
// vP: normalized V fp16 [b][c][4480] (pads zero), x8 vectorized 16B stores.
__global__ __launch_bounds__(256) void k_norm(
    const float* __restrict__ bufQ, const float* __restrict__ bufKV,
    const float* __restrict__ nrm, u16* __restrict__ qTs,
    u16* __restrict__ kTs, u16* __restrict__ vP) {
  __shared__ u16 th[32][33];
  const int blk = blockIdx.x, tid = threadIdx.x;
  const int tx = tid & 31, ty = tid >> 5;
  if (blk < 4096) {
    int u = blk;
    int q0 = (u % 128) * 32;
    u /= 128;
    int c0 = (u % 8) * 32;
    int b = u / 8;
#pragma unroll
    for (int i = 0; i < 4; i++) {
      int c = c0 + ty + i * 8;
      float sc = nrm[c * 2], sh = nrm[c * 2 + 1];
      th[ty + i * 8][tx] =
          f2h(bufQ[(size_t)c * 16384 + b * 4096 + q0 + tx] * sc + sh);
    }
    __syncthreads();
#pragma unroll
    for (int i = 0; i < 4; i++)
      qTs[((size_t)b * 4096 + q0 + ty + i * 8) * 256 + c0 + tx] =
          th[tx][ty + i * 8];
  } else if (blk < 8576) {
    int u = blk - 4096;
    int k0 = (u % 140) * 32;
    u /= 140;
    int c0 = (u % 8) * 32;
    int b = u / 8;
#pragma unroll
    for (int i = 0; i < 4; i++) {
      int c = c0 + ty + i * 8;
      int kt = k0 + tx;
      float v = 0.f;
      if (kt < 4356) {
        float sc = nrm[(256 + c) * 2], sh = nrm[(256 + c) * 2 + 1];
        int yy = kt / 66, xx = kt - yy * 66;
        if (yy >= 1 && yy <= 64 && xx >= 1 && xx <= 64)
          v = bufKV[(size_t)c * 16384 + b * 4096 + (yy - 1) * 64 + (xx - 1)] * sc + sh;
        else
          v = sh;  // border: conv value 0
      }
      th[ty + i * 8][tx] = f2h(v);  // kt >= 4356 rows -> exact zeros
    }
    __syncthreads();
#pragma unroll
    for (int i = 0; i < 4; i++)
      kTs[((size_t)b * 4480 + k0 + ty + i * 8) * 256 + c0 + tx] =
          th[tx][ty + i * 8];
  } else {
    int idx = (blk - 8576) * 256 + tid;  // [b][ch][kt8]: 4*256*560
    int kt8 = idx % 560;
    int rem = idx / 560;
    int ch = rem & 255, b = rem >> 8;
    int kt0 = kt8 * 8;
    float sc = nrm[(512 + ch) * 2], sh = nrm[(512 + ch) * 2 + 1];
    u16x8 v8;
#pragma unroll
    for (int j = 0; j < 8; j++) {
      int kt = kt0 + j;
      float v = 0.f;
      if (kt < 4356) {
        int yy = kt / 66, xx = kt - yy * 66;
        if (yy >= 1 && yy <= 64 && xx >= 1 && xx <= 64)
          v = bufKV[(size_t)(256 + ch) * 16384 + b * 4096 + (yy - 1) * 64 + (xx - 1)] * sc + sh;
        else
          v = sh;
      }
      v8[j] = f2h(v);
    }
    *(u16x8*)&vP[((size_t)b * 256 + ch) * 4480 + kt0] = v8;
  }
}

// ---- 8) fused flash attention, 2-deep pipelined, PV split by CHANNELS ----
// grid 512 linear: xcd = lin&7 pins (h = xcd&1, b = xcd>>1) per XCD; per->qt.
// S phase (per tile halves A/B) and softmax: per-wave 16 qt (R13, unchanged).
// PV (phases C/D): wave w owns c [64w,64w+64) x ALL 64 qt -> V-frags are
// wave-unique (reads 272->128/tile). P crosses waves via lP (8KB half-tile:
// fj<4 written in softmax, fj>=4 kept in hq[] regs, refilled after C).
// Rescale fac broadcast via lFac[64]; fac==1.0 exact when defer-max skips.
// WAITB drains lgkmcnt(0) so cross-wave ds_writes are visible post-barrier.
__global__ __launch_bounds__(256, 2) void k_flash(
    const u16* __restrict__ qTs, const u16* __restrict__ kTs,
    const u16* __restrict__ vP, float* __restrict__ Op,
    float* __restrict__ ml) {
  __shared__ u16 lS[2][16384];  // 2 x 32KB staging (K-half or V-chunk)
  __shared__ u16 lP[64 * 64];   // 8KB P half-tile (64 qt x 64 kt), swizzled
  __shared__ float lFac[64];    // per-qt-row rescale factor broadcast
  const int lin = blockIdx.x;
  const int xcd = lin & 7, per = lin >> 3;
  const int h = xcd & 1, b = xcd >> 1;
  const int qt0 = per * 64;
  const int tid = threadIdx.x, wave = tid >> 6, lane = tid & 63;
  const int sr = lane >> 3, scw = (lane & 7) ^ sr;
  const int r16 = lane & 15, q = lane >> 4;

  // Q fragments in registers: aq[kk] = Q[qt0+wave*16+r16][kk*32 + q*8 ..+7]
  const u16* gQ = qTs + ((size_t)b * 4096 + qt0 + wave * 16 + r16) * 256;
  f16x8 aq[8];
#pragma unroll
  for (int kk = 0; kk < 8; kk++) aq[kk] = *(const f16x8*)&gQ[kk * 32 + q * 8];
  // drain Q loads so in-loop vmcnt counting is exact (one-time cost)
  asm volatile("s_waitcnt vmcnt(0)" ::: "memory");

  const u16* gK = kTs + (size_t)b * 4480 * 256 + (size_t)(wave * 32 + sr) * 256 + scw * 8;
  const u16* gV = vP + ((size_t)b * 256 + wave * 64 + sr) * 4480 + scw * 8;

// 8 gld16/thread per stage (32KB/block). K half c2: rows=kt, 2 kcL chunks.
#define STAGE_K(buf, kt, c2)                                                 \
  {                                                                          \
    _Pragma("unroll") for (int i = 0; i < 4; i++) {                          \
      const u16* src = gK + (size_t)((kt) + i * 8) * 256 + (c2) * 128;       \
      gld16(src, &lS[buf][(wave * 32 + i * 8) * 64]);                        \
      gld16(src + 64, &lS[buf][8192 + (wave * 32 + i * 8) * 64]);            \
    }                                                                        \
  }
#define STAGE_V(buf, kt, vc)                                                 \
  {                                                                          \
    _Pragma("unroll") for (int i = 0; i < 8; i++)                            \
        gld16(gV + (size_t)(i * 8) * 4480 + (kt) + (vc) * 64,                \
              &lS[buf][(wave * 64 + i * 8) * 64]);                           \
  }
#define WAITB(n)                                                             \
  asm volatile("s_waitcnt vmcnt(" #n ") lgkmcnt(0)" ::: "memory");           \
  __builtin_amdgcn_s_barrier();                                              \
  __builtin_amdgcn_sched_barrier(0);
#define CLOSEB()                                                             \
  __builtin_amdgcn_sched_barrier(0);                                         \
  asm volatile("s_waitcnt lgkmcnt(0)" ::: "memory");                         \
  __builtin_amdgcn_s_barrier();

  // acc_o[mt][fj]: qt-tile mt (rows mt*16+q*4+rr), c-tile fj (wave*64+fj*16+r16)
  f32x4 acc_o[4][4];
#pragma unroll
  for (int mt = 0; mt < 4; mt++)
#pragma unroll
    for (int fj = 0; fj < 4; fj++) acc_o[mt][fj] = (f32x4){0.f, 0.f, 0.f, 0.f};
  f32x4 m_v = {-3e38f, -3e38f, -3e38f, -3e38f};
  f32x4 l_v = {0.f, 0.f, 0.f, 0.f};

  const int ktBeg = h ? 2304 : 0, ktEnd = h ? 4480 : 2304;
  STAGE_K(0, ktBeg, 0);  // prologue: phase A of first tile
  for (int kt0 = ktBeg; kt0 < ktEnd; kt0 += 128) {
    f32x4 acc_s[8];
#pragma unroll
    for (int i = 0; i < 8; i++) acc_s[i] = (f32x4){0.f, 0.f, 0.f, 0.f};
    // ---- phase A: S (c 0..127) from buf0; prefetch B ----
    STAGE_K(1, kt0, 1);
    WAITB(8);
    __builtin_amdgcn_s_setprio(1);
#pragma unroll
    for (int kcL = 0; kcL < 2; kcL++)
#pragma unroll
      for (int ks = 0; ks < 64; ks += 32)
#pragma unroll
        for (int fj = 0; fj < 8; fj++) {
          int nb = fj * 16 + r16;
          int g = (ks >> 3) + q;
          f16x8 bf = *(const f16x8*)&lS[0][kcL * 8192 + nb * 64 + ((g ^ (nb & 7)) << 3)];
          acc_s[fj] = __builtin_amdgcn_mfma_f32_16x16x32_f16(
              aq[kcL * 2 + (ks >> 5)], bf, acc_s[fj], 0, 0, 0);
        }
    __builtin_amdgcn_s_setprio(0);
    CLOSEB();
    // ---- phase B: S (c 128..255) from buf1; prefetch C (V kt-chunk 0) ----
    STAGE_V(0, kt0, 0);
    WAITB(8);
    __builtin_amdgcn_s_setprio(1);
#pragma unroll
    for (int kcL = 0; kcL < 2; kcL++)
#pragma unroll
      for (int ks = 0; ks < 64; ks += 32)
#pragma unroll
        for (int fj = 0; fj < 8; fj++) {
          int nb = fj * 16 + r16;
          int g = (ks >> 3) + q;
          f16x8 bf = *(const f16x8*)&lS[1][kcL * 8192 + nb * 64 + ((g ^ (nb & 7)) << 3)];
          acc_s[fj] = __builtin_amdgcn_mfma_f32_16x16x32_f16(
              aq[4 + kcL * 2 + (ks >> 5)], bf, acc_s[fj], 0, 0, 0);
        }
    __builtin_amdgcn_s_setprio(0);
    CLOSEB();
    // ---- prefetch D (V kt-chunk 1) so it flies under the softmax VALU ----
    STAGE_V(1, kt0, 1);
    // ---- mask pad keys (only last tile; kTs pad rows are zeros, no NaN) ----
    if (kt0 + 128 > 4356) {
#pragma unroll
      for (int fj = 0; fj < 8; fj++)
        if (kt0 + fj * 16 + r16 >= 4356)
          acc_s[fj] = (f32x4){-1e30f, -1e30f, -1e30f, -1e30f};
    }
    // ---- online softmax; lane owns rows q*4+rr of wave's 16-qt strip ----
    f32x4 pm = acc_s[0];
#pragma unroll
    for (int fj = 1; fj < 8; fj++)
#pragma unroll
      for (int rr = 0; rr < 4; rr++) pm[rr] = fmaxf(pm[rr], acc_s[fj][rr]);
#pragma unroll
    for (int d = 1; d < 16; d <<= 1)
#pragma unroll
      for (int rr = 0; rr < 4; rr++)
        pm[rr] = fmaxf(pm[rr], __shfl_xor(pm[rr], d));
    // T13 defer-max: keep m while tile max grows <= 8; fac = 1.0 exactly then.
    int need = !__all(pm[0] - m_v[0] <= 8.f && pm[1] - m_v[1] <= 8.f &&
                      pm[2] - m_v[2] <= 8.f && pm[3] - m_v[3] <= 8.f);
    f32x4 fac = {1.f, 1.f, 1.f, 1.f};
    if (need) {
#pragma unroll
      for (int rr = 0; rr < 4; rr++) {
        float mn = fmaxf(m_v[rr], pm[rr]);
        fac[rr] = __expf(m_v[rr] - mn);
        m_v[rr] = mn;
        l_v[rr] *= fac[rr];
      }
    }
    if (r16 == 0) *(f32x4*)&lFac[wave * 16 + q * 4] = fac;  // broadcast
    // hp: fj<4 -> lP (kt 0..63); fj>=4 kept in hq regs, written pre-D.
    _Float16 hq[4][4];
    f32x4 rs = {0.f, 0.f, 0.f, 0.f};
#pragma unroll
    for (int fj = 0; fj < 8; fj++)
#pragma unroll
      for (int rr = 0; rr < 4; rr++) {
        _Float16 hp = (_Float16)__expf(acc_s[fj][rr] - m_v[rr]);
        rs[rr] += (float)hp;  // denominator sums the rounded p (consistency)
        int row = wave * 16 + q * 4 + rr;
        if (fj < 4) {
          int c8 = fj * 2 + (r16 >> 3);
          lP[row * 64 + (((c8 ^ (row & 7)) << 3) | (r16 & 7))] = *(const u16*)&hp;
        } else {
          hq[fj - 4][rr] = hp;
        }
      }
#pragma unroll
    for (int d = 1; d < 16; d <<= 1)
#pragma unroll
      for (int rr = 0; rr < 4; rr++) rs[rr] += __shfl_xor(rs[rr], d);
#pragma unroll
    for (int rr = 0; rr < 4; rr++) l_v[rr] += rs[rr];
    // ---- phase C: PV kt 0..63 from buf0; wave owns c [64w, 64w+64) ----
    WAITB(8);  // V0 ready; P(fj<4) + lFac visible (lgkm drained)
    f32x4 facv[4];
#pragma unroll
    for (int mt = 0; mt < 4; mt++)
      facv[mt] = *(const f32x4*)&lFac[mt * 16 + q * 4];
#pragma unroll
    for (int mt = 0; mt < 4; mt++)
#pragma unroll
      for (int fj = 0; fj < 4; fj++)
#pragma unroll
        for (int rr = 0; rr < 4; rr++) acc_o[mt][fj][rr] *= facv[mt][rr];
    __builtin_amdgcn_s_setprio(1);
#pragma unroll
    for (int ks = 0; ks < 64; ks += 32) {
      int k8 = (ks >> 3) + q;
      f16x8 ap[4];
#pragma unroll
      for (int mt = 0; mt < 4; mt++)
        ap[mt] = *(const f16x8*)&lP[(mt * 16 + r16) * 64 + ((k8 ^ (r16 & 7)) << 3)];
#pragma unroll
      for (int fj = 0; fj < 4; fj++) {
        int cr = wave * 64 + fj * 16 + r16;
        f16x8 bv = *(const f16x8*)&lS[0][cr * 64 + ((k8 ^ (cr & 7)) << 3)];
#pragma unroll
        for (int mt = 0; mt < 4; mt++)
          acc_o[mt][fj] = __builtin_amdgcn_mfma_f32_16x16x32_f16(
              ap[mt], bv, acc_o[mt][fj], 0, 0, 0);
      }
    }
    __builtin_amdgcn_s_setprio(0);
    CLOSEB();  // all C-phase lP/lS reads done before refill
    // ---- refill lP with kt 64..127 (hq), prefetch next tile's A ----
#pragma unroll
    for (int fj = 0; fj < 4; fj++)
#pragma unroll
      for (int rr = 0; rr < 4; rr++) {
        int row = wave * 16 + q * 4 + rr;
        int c8 = fj * 2 + (r16 >> 3);
        lP[row * 64 + (((c8 ^ (row & 7)) << 3) | (r16 & 7))] =
            *(const u16*)&hq[fj][rr];
      }
    if (kt0 + 128 < ktEnd) {
      STAGE_K(0, kt0 + 128, 0);
      WAITB(8);  // V1 ready; refilled P visible
    } else {
      WAITB(0);
    }
    __builtin_amdgcn_s_setprio(1);
#pragma unroll
    for (int ks = 0; ks < 64; ks += 32) {
      int k8 = (ks >> 3) + q;
      f16x8 ap[4];
#pragma unroll
      for (int mt = 0; mt < 4; mt++)
        ap[mt] = *(const f16x8*)&lP[(mt * 16 + r16) * 64 + ((k8 ^ (r16 & 7)) << 3)];
#pragma unroll
      for (int fj = 0; fj < 4; fj++) {
        int cr = wave * 64 + fj * 16 + r16;
        f16x8 bv = *(const f16x8*)&lS[1][cr * 64 + ((k8 ^ (cr & 7)) << 3)];
#pragma unroll
        for (int mt = 0; mt < 4; mt++)
          acc_o[mt][fj] = __builtin_amdgcn_mfma_f32_16x16x32_f16(
              ap[mt], bv, acc_o[mt][fj], 0, 0, 0);
      }
    }
    __builtin_amdgcn_s_setprio(0);
    CLOSEB();  // D-phase lP reads done before next tile's softmax writes
  }
#undef STAGE_K
#undef STAGE_V
#undef WAITB
#undef CLOSEB
  // ---- store partials: wave's c-slice for all 64 qt ----
  size_t obase = ((size_t)(h * 4 + b) * 4096 + qt0) * 256;
#pragma unroll
  for (int mt = 0; mt < 4; mt++)
#pragma unroll
    for (int rr = 0; rr < 4; rr++) {
      size_t rowo = obase + (size_t)(mt * 16 + q * 4 + rr) * 256;
#pragma unroll
      for (int fj = 0; fj < 4; fj++)
        Op[rowo + wave * 64 + fj * 16 + r16] = acc_o[mt][fj][rr];
    }
  if (r16 == 0) {
    int base = (h * 4 + b) * 4096 + qt0 + wave * 16 + q * 4;
    *(f32x4*)&ml[base] = m_v;
    *(f32x4*)&ml[32768 + base] = l_v;
  }
}

// ---- 9) merge two kt-half partials, divide, transpose to out[b][c][qt] ----
__global__ __launch_bounds__(256) void k_merge(const float* __restrict__ Op,
                                               const float* __restrict__ ml,
                                               const int* __restrict__ flag,
                                               void* __restrict__ out) {
  __shared__ float th[32][33];
  int b = blockIdx.z, qt0 = blockIdx.x * 32, c0 = blockIdx.y * 32;
  int tx = threadIdx.x, ty = threadIdx.y;
#pragma unroll
  for (int i = 0; i < 4; i++) {
    int qt = qt0 + ty + i * 8;
    float m0 = ml[b * 4096 + qt], m1 = ml[(4 + b) * 4096 + qt];
    float l0 = ml[32768 + b * 4096 + qt], l1 = ml[32768 + (4 + b) * 4096 + qt];
    float M = fmaxf(m0, m1);
    float e0 = __expf(m0 - M), e1 = __expf(m1 - M);
    float inv = 1.f / (l0 * e0 + l1 * e1);  // >= 1, safe
    float v = (Op[((size_t)b * 4096 + qt) * 256 + c0 + tx] * e0 +
               Op[((size_t)(4 + b) * 4096 + qt) * 256 + c0 + tx] * e1) * inv;
    v = (v == v) ? v : 0.f;  // NaN scrub: keep failures diagnostic
    th[ty + i * 8][tx] = v;
  }
  __syncthreads();
#pragma unroll
  for (int i = 0; i < 4; i++) {
    int c = c0 + ty + i * 8, qt = qt0 + tx;
    float v = th[tx][ty + i * 8];
    size_t oidx = ((size_t)b * 256 + c) * 4096 + qt;
    if (flag[0])
      ((float*)out)[oidx] = v;
    else
      ((u16*)out)[oidx] = f2bf(v);
  }
}

// ---------------------------------------------------------------------------
extern "C" void kernel_launch(void* const* d_in, const int* in_sizes, int n_in,
                              void* d_out, int out_size, void* d_ws, size_t ws_size,
                              hipStream_t stream) {
  const void* x = d_in[0];
  const void* Wq = d_in[1];
  const void* gq = d_in[3];
  const void* betaq = d_in[4];
  const void* Wk = d_in[5];
  const void* gk = d_in[7];
  const void* betak = d_in[8];
  const void* Wv = d_in[9];
  const void* gv = d_in[11];
  const void* betav = d_in[12];

  char* ws = (char*)d_ws;
  int* flag = (int*)ws;  // 256 B
  // Region A (conv phase; dead once qTs/kTs/vP built -> overlaid by Opart/ml):
  u16* xbTp = (u16*)(ws + 256);            //  8,921,088
  u16* WqB = (u16*)(ws + 8921344);         //  1,179,648
  u16* WkvB = (u16*)(ws + 10100992);       //    262,144
  float* bufQ = (float*)(ws + 10363136);   // 16,777,216
  float* bufKV = (float*)(ws + 27140352);  // 33,554,432 -> A ends 60,694,784
  u16* qTs = (u16*)(ws + 60694784);        //  8,388,608 (4*4096*256*2)
  u16* kTs = (u16*)(ws + 69083392);        //  9,175,040 (4*4480*256*2)
  u16* vP = (u16*)(ws + 78258432);         //  9,175,040
  float* nrm = (float*)(ws + 87433472);    //      6,144 -> total 87,439,616 B
  // Overlay region A (dead by flash time):
  float* Opart = (float*)(ws + 256);       // 33,554,432 (2*4*4096*256*4)
  float* mlbuf = (float*)(ws + 33554688);  //    262,144 (m: 32768 f, l: 32768 f)

  k_detect<<<1, 256, 0, stream>>>((const unsigned*)Wq, flag);
  // fused prep: txp (4384) | wq+bufQ-zero (2304) | wkv (512) = 7200 blocks
  k_prep<<<7200, 256, 0, stream>>>(x, Wq, Wk, Wv, flag, xbTp, WqB, WkvB, bufQ);
  // fused convs: [0,768) conv3x3 splitK x3 into zeroed bufQ; [768,1280) 1x1.
  k_convs<<<1280, 256, 0, stream>>>(WqB, WkvB, xbTp, bufQ, bufKV);
  k_stats<<<dim3(256, 3), 256, 0, stream>>>(bufQ, bufKV, gq, betaq, gk, betak,
                                            gv, betav, flag, nrm);
  // fused normalize: qTs (4096) | kTs (4480) | vP x8-vec (2240) = 10816 blocks
  k_norm<<<10816, 256, 0, stream>>>(bufQ, bufKV, nrm, qTs, kTs, vP);
  // fused attention: 512 blocks = 8 XCD-combos x 64 qt tiles, 2 blocks/CU
  k_flash<<<512, 256, 0, stream>>>(qTs, kTs, vP, Opart, mlbuf);
  k_merge<<<dim3(128, 8, 4), dim3(32, 8), 0, stream>>>(Opart, mlbuf, flag,
                                                       d_out);
}

// Round 10
// 308.711 us; speedup vs baseline: 1.3148x; 1.0416x over previous
//
#include <hip/hip_runtime.h>

// ---------------------------------------------------------------------------
// ChannelAttentionLayer on MI355X (gfx950). Input dtype (fp32 vs bf16) is
// DETECTED ON DEVICE (k_detect); core pipeline is FP16 MFMA + fp32 accumulate.
// R20->R21: conv GEMM was latency-bound (MfmaUtil 12%, 1.4TB/s, low VALU —
// each K-step's stage->syncthreads drained vmcnt(0) exposing full L3/HBM
// latency). Now BK=32 double-buffered: 2x8KB lA + 2x8KB lB = 32KB unchanged
// (occupancy 3 PRESERVED — R17's failed DB dropped it to 2), next step's 4
// gld16 issued BEFORE current compute, counted "s_waitcnt vmcnt(4)" + raw
// barrier. 4-chunk row swizzle: stage src chunk^=(row>>2)&3, read q^(r16>>2)
// — uniform 8 lanes/bank-group, conflict-free. K order unchanged -> bit-
// identical. splitK x3 kept. Everything else identical to R20 (flash 127us).
// ---------------------------------------------------------------------------

typedef unsigned short u16;
typedef _Float16 f16x8 __attribute__((ext_vector_type(8)));
typedef __attribute__((ext_vector_type(4))) float f32x4;
typedef __attribute__((ext_vector_type(8))) unsigned short u16x8;

__device__ __forceinline__ u16 f2h(float f) {
  _Float16 h = (_Float16)f;
  return *(const u16*)&h;
}
__device__ __forceinline__ float bf2f(u16 h) {
  return __uint_as_float(((unsigned)h) << 16);
}
__device__ __forceinline__ float ldin(const void* p, size_t i, int f32) {
  return f32 ? ((const float*)p)[i] : bf2f(((const u16*)p)[i]);
}
__device__ __forceinline__ u16 f2bf(float f) {
  unsigned u = __float_as_uint(f);
  u += 0x7fffu + ((u >> 16) & 1u);
  return (u16)(u >> 16);
}
__device__ __forceinline__ void gld16(const void* g, void* l) {
  __builtin_amdgcn_global_load_lds(
      (const __attribute__((address_space(1))) unsigned int*)g,
      (__attribute__((address_space(3))) unsigned int*)l, 16, 0, 0);
}

// ---- 1) dtype detection on Wq: 2048 sampled words, 8 independent loads ----
__global__ __launch_bounds__(256) void k_detect(const unsigned* __restrict__ w,
                                                int* __restrict__ flag) {
  __shared__ int red[4];
  int tid = threadIdx.x, cnt = 0;
#pragma unroll
  for (int j = 0; j < 8; j++) {
    unsigned e = (w[tid + j * 8192] >> 7) & 0xFFu;
    cnt += (e >= 118u && e <= 127u) ? 1 : 0;
  }
#pragma unroll
  for (int off = 32; off; off >>= 1) cnt += __shfl_down(cnt, off);
  if ((tid & 63) == 0) red[tid >> 6] = cnt;
  __syncthreads();
  if (tid == 0)
    flag[0] = (red[0] + red[1] + red[2] + red[3] < 625) ? 1 : 0;  // 1 = fp32
}

// ---- 2) fused prep: [0,4384) txp | [4384,6688) wq+zero | [6688,7200) wkv ---
__global__ __launch_bounds__(256) void k_prep(
    const void* __restrict__ x, const void* __restrict__ Wq,
    const void* __restrict__ Wk, const void* __restrict__ Wv,
    const int* __restrict__ flag, u16* __restrict__ xbTp,
    u16* __restrict__ WqB, u16* __restrict__ WkvB, float* __restrict__ bufQ) {
  __shared__ float tile[32][33];
  const int blk = blockIdx.x, tid = threadIdx.x;
  const int f32 = flag[0];
  if (blk < 4384) {
    int u = blk;
    int p0 = (u % 137) * 32;
    u /= 137;
    int c0 = (u % 8) * 32;
    int b = u / 8;
    int tx = tid & 31, ty = tid >> 5;
#pragma unroll
    for (int i = 0; i < 4; i++) {
      int c = c0 + ty + i * 8, pp = p0 + tx;
      float v = 0.f;
      if (pp < 4356) {
        int yy = pp / 66, xx = pp - yy * 66;
        if (yy >= 1 && yy <= 64 && xx >= 1 && xx <= 64)
          v = ldin(x, ((size_t)b * 256 + c) * 4096 + (yy - 1) * 64 + (xx - 1), f32);
      }
      tile[ty + i * 8][tx] = v;
    }
    __syncthreads();
#pragma unroll
    for (int i = 0; i < 4; i++) {
      int pp = p0 + ty + i * 8;
      if (pp >= 4356) continue;
      xbTp[((size_t)b * 4356 + pp) * 256 + c0 + tx] = f2h(tile[tx][ty + i * 8]);
    }
  } else if (blk < 6688) {
    int idx = (blk - 4384) * 256 + tid;  // 2304*256
    int oc = idx / 2304, rem = idx - oc * 2304;
    int tap = rem >> 8, c = rem & 255;
    WqB[idx] = f2h(ldin(Wq, oc * 2304 + c * 9 + tap, f32));
    // zero bufQ: 1,048,576 f32x4 over 589,824 threads
    f32x4* bz = (f32x4*)bufQ;
    for (int i = idx; i < 1048576; i += 589824)
      bz[i] = (f32x4){0.f, 0.f, 0.f, 0.f};
  } else {
    int idx = (blk - 6688) * 256 + tid;  // 512*256
    int m = idx >> 8, c = idx & 255;
    float w = (m < 256) ? ldin(Wk, m * 256 + c, f32)
                        : ldin(Wv, (m - 256) * 256 + c, f32);
    WkvB[idx] = f2h(w);
  }
}

// ---- 4) conv GEMM body (fp16), BK=32 double-buffered counted-vmcnt ----
// C[M][N] = A . im2col(xbTp). EPI 0: fp32 store. EPI 1: fp32 atomicAdd.
// SWZ-2 mapping: xcd = lin&7, per = lin>>3; tm = per%sw1, tn = xcd*sw2+per/sw1.
// LDS per buffer: 128 rows x 32 u16 (64B rows, 4 chunks of 8). Stage source
// pre-swizzled chunk ^= (row>>2)&3 (linear gld16 dest); read q ^ (r16>>2)&3.
template <int EPI>
__device__ __forceinline__ void gemm_body(
    const u16* __restrict__ A, const u16* __restrict__ Bt,
    float* __restrict__ C, u16* lA, u16* lB, int N, int K, int tapBase,
    int kChunk, int sw1, int sw2, int lin, int kz) {
  int xcd = lin & 7, per = lin >> 3;
  int tm = per % sw1;
  int tn = xcd * sw2 + per / sw1;
  int k0 = 0, k1 = K;
  if (kChunk) {
    k0 = kz * kChunk;
    k1 = min(k0 + kChunk, K);
  }
  const int tid = threadIdx.x, wave = tid >> 6, lane = tid & 63;
  const int sr4 = lane >> 2;                  // source row within 16-row group
  const int scw4 = (lane & 3) ^ (sr4 >> 2);   // XOR-swizzled source chunk (of 4)
  const int wm = (wave >> 1) * 64, wn = (wave & 1) * 64;
  const int r16 = lane & 15, q = lane >> 4;
  const int qsw = (r16 >> 2) & 3;             // read-side swizzle key
  const u16* gA = A + (size_t)(tm * 128 + wave * 32 + sr4) * K + scw4 * 8;
  int pyI[2], pxI[2];
  size_t bOffI[2];
#pragma unroll
  for (int i = 0; i < 2; i++) {
    int n = tn * 128 + wave * 32 + i * 16 + sr4;  // global output pixel
    int bb = n >> 12, pix = n & 4095;
    pyI[i] = pix >> 6;
    pxI[i] = pix & 63;
    bOffI[i] = (size_t)bb * 4356;
  }
  f32x4 acc[4][4] = {};

  // stage one 32-K chunk into buffer `buf` (4 gld16 / thread)
  auto stage = [&](int buf, int kt) {
    int tap = tapBase + (kt >> 8);
    int chunk = kt & 255;
    int dy = tap / 3, dx = tap - dy * 3;
#pragma unroll
    for (int i = 0; i < 2; i++) {
      gld16(gA + (size_t)(i * 16) * K + kt,
            &lA[buf * 4096 + (wave * 32 + i * 16) * 32]);
      int spix = (pyI[i] + dy) * 66 + pxI[i] + dx;
      gld16(Bt + (bOffI[i] + spix) * 256 + chunk + scw4 * 8,
            &lB[buf * 4096 + (wave * 32 + i * 16) * 32]);
    }
  };
  auto compute = [&](int buf) {
    f16x8 af[4], bfr[4];
#pragma unroll
    for (int f = 0; f < 4; f++) {
      int ma = wm + f * 16 + r16;
      af[f] = *(const f16x8*)&lA[buf * 4096 + ma * 32 + ((q ^ qsw) << 3)];
      int nb = wn + f * 16 + r16;
      bfr[f] = *(const f16x8*)&lB[buf * 4096 + nb * 32 + ((q ^ qsw) << 3)];
    }
#pragma unroll
    for (int fi = 0; fi < 4; fi++)
#pragma unroll
      for (int fj = 0; fj < 4; fj++)
        acc[fi][fj] = __builtin_amdgcn_mfma_f32_16x16x32_f16(
            af[fi], bfr[fj], acc[fi][fj], 0, 0, 0);
  };

  stage(0, k0);  // prologue
  int cur = 0;
  for (int kt = k0; kt < k1; kt += 32) {
    if (kt + 32 < k1) {
      stage(cur ^ 1, kt + 32);  // issue next BEFORE waiting on current
      asm volatile("s_waitcnt vmcnt(4)" ::: "memory");  // cur's 4 loads done
    } else {
      asm volatile("s_waitcnt vmcnt(0)" ::: "memory");
    }
    __builtin_amdgcn_s_barrier();
    __builtin_amdgcn_sched_barrier(0);
    compute(cur);
    __builtin_amdgcn_sched_barrier(0);
    asm volatile("s_waitcnt lgkmcnt(0)" ::: "memory");  // reads done
    __builtin_amdgcn_s_barrier();                       // before re-stage
    cur ^= 1;
  }

  const int colB = tn * 128 + wn + r16;
  const int rowB = tm * 128 + wm + q * 4;
  if (EPI == 0) {
#pragma unroll
    for (int fi = 0; fi < 4; fi++)
#pragma unroll
      for (int r = 0; r < 4; r++) {
        size_t ro = (size_t)(rowB + fi * 16 + r) * N;
#pragma unroll
        for (int fj = 0; fj < 4; fj++) C[ro + colB + fj * 16] = acc[fi][fj][r];
      }
  } else {
#pragma unroll
    for (int fi = 0; fi < 4; fi++)
#pragma unroll
      for (int r = 0; r < 4; r++) {
        size_t ro = (size_t)(rowB + fi * 16 + r) * N;
#pragma unroll
        for (int fj = 0; fj < 4; fj++)
          atomicAdd(&C[ro + colB + fj * 16], acc[fi][fj][r]);
      }
  }
}

// Fused conv dispatch: blocks [0,768) = conv3x3 (splitK x3: lin = idx&255,
// kz = idx>>8); blocks [768,1280) = conv1x1 (backfills as conv3x3 retires).
__global__ __launch_bounds__(256, 3) void k_convs(
    const u16* __restrict__ WqB, const u16* __restrict__ WkvB,
    const u16* __restrict__ xbTp, float* __restrict__ bufQ,
    float* __restrict__ bufKV) {
  __shared__ u16 lA[2 * 128 * 32];
  __shared__ u16 lB[2 * 128 * 32];
  int idx = blockIdx.x;
  if (idx < 768)
    gemm_body<1>(WqB, xbTp, bufQ, lA, lB, 16384, 2304, 0, 768, 2, 16,
                 idx & 255, idx >> 8);
  else
    gemm_body<0>(WkvB, xbTp, bufKV, lA, lB, 16384, 256, 4, 0, 4, 16,
                 idx - 768, 0);
}

// ---- 5) BN stats (biases cancel; K/V border conv-value 0, count 17424) ----
__global__ __launch_bounds__(256) void k_stats(
    const float* __restrict__ bufQ, const float* __restrict__ bufKV,
    const void* __restrict__ gq, const void* __restrict__ betaq,
    const void* __restrict__ gk, const void* __restrict__ betak,
    const void* __restrict__ gv, const void* __restrict__ betav,
    const int* __restrict__ flag, float* __restrict__ nrm) {
  int f32 = flag[0];
  int ch = blockIdx.x, t = blockIdx.y, tid = threadIdx.x;
  const float* row = (t == 0) ? bufQ + (size_t)ch * 16384
                              : bufKV + (size_t)(t == 1 ? ch : 256 + ch) * 16384;
  const f32x4* row4 = (const f32x4*)row;
  float s = 0.f, ss = 0.f;
  for (int i = tid; i < 4096; i += 256) {
    f32x4 v = row4[i];
    s += v[0] + v[1] + v[2] + v[3];
    ss += v[0] * v[0] + v[1] * v[1] + v[2] * v[2] + v[3] * v[3];
  }
#pragma unroll
  for (int off = 32; off; off >>= 1) {
    s += __shfl_down(s, off);
    ss += __shfl_down(ss, off);
  }
  __shared__ float ls[4], lss[4];
  if ((tid & 63) == 0) {
    ls[tid >> 6] = s;
    lss[tid >> 6] = ss;
  }
  __syncthreads();
  if (tid == 0) {
    s = ls[0] + ls[1] + ls[2] + ls[3];
    ss = lss[0] + lss[1] + lss[2] + lss[3];
    float cnt = (t == 0) ? 16384.f : 17424.f;
    float mean = s / cnt;
    float var = fmaxf(ss / cnt - mean * mean, 0.f);  // NaN-proof
    const void* g = (t == 0) ? gq : (t == 1 ? gk : gv);
    const void* be = (t == 0) ? betaq : (t == 1 ? betak : betav);
    float sc = ldin(g, ch, f32) * rsqrtf(var + 1e-5f);
    nrm[(t * 256 + ch) * 2] = sc;
    nrm[(t * 256 + ch) * 2 + 1] = ldin(be, ch, f32) - mean * sc;
  }
}

// ---- 6) fused normalize: [0,4096) qTs | [4096,8576) kTs | [8576,10816) vP --
__global__ __launch_bounds__(256) void k_norm(
    const float* __restrict__ bufQ, const float* __restrict__ bufKV,
    const float* __restrict__ nrm, u16* __restrict__ qTs,
    u16* __restrict__ kTs, u16* __restrict__ vP) {
  __shared__ u16 th[32][33];
  const int blk = blockIdx.x, tid = threadIdx.x;
  const int tx = tid & 31, ty = tid >> 5;
  if (blk < 4096) {
    int u = blk;
    int q0 = (u % 128) * 32;
    u /= 128;
    int c0 = (u % 8) * 32;
    int b = u / 8;
#pragma unroll
    for (int i = 0; i < 4; i++) {
      int c = c0 + ty + i * 8;
      float sc = nrm[c * 2], sh = nrm[c * 2 + 1];
      th[ty + i * 8][tx] =
          f2h(bufQ[(size_t)c * 16384 + b * 4096 + q0 + tx] * sc + sh);
    }
    __syncthreads();
#pragma unroll
    for (int i = 0; i < 4; i++)
      qTs[((size_t)b * 4096 + q0 + ty + i * 8) * 256 + c0 + tx] =
          th[tx][ty + i * 8];
  } else if (blk < 8576) {
    int u = blk - 4096;
    int k0 = (u % 140) * 32;
    u /= 140;
    int c0 = (u % 8) * 32;
    int b = u / 8;
#pragma unroll
    for (int i = 0; i < 4; i++) {
      int c = c0 + ty + i * 8;
      int kt = k0 + tx;
      float v = 0.f;
      if (kt < 4356) {
        float sc = nrm[(256 + c) * 2], sh = nrm[(256 + c) * 2 + 1];
        int yy = kt / 66, xx = kt - yy * 66;
        if (yy >= 1 && yy <= 64 && xx >= 1 && xx <= 64)
          v = bufKV[(size_t)c * 16384 + b * 4096 + (yy - 1) * 64 + (xx - 1)] * sc + sh;
        else
          v = sh;  // border: conv value 0
      }
      th[ty + i * 8][tx] = f2h(v);  // kt >= 4356 rows -> exact zeros
    }
    __syncthreads();
#pragma unroll
    for (int i = 0; i < 4; i++)
      kTs[((size_t)b * 4480 + k0 + ty + i * 8) * 256 + c0 + tx] =
          th[tx][ty + i * 8];
  } else {
    int idx = (blk - 8576) * 256 + tid;  // [b][ch][kt8]: 4*256*560
    int kt8 = idx % 560;
    int rem = idx / 560;
    int ch = rem & 255, b = rem >> 8;
    int kt0 = kt8 * 8;
    float sc = nrm[(512 + ch) * 2], sh = nrm[(512 + ch) * 2 + 1];
    u16x8 v8;
#pragma unroll
    for (int j = 0; j < 8; j++) {
      int kt = kt0 + j;
      float v = 0.f;
      if (kt < 4356) {
        int yy = kt / 66, xx = kt - yy * 66;
        if (yy >= 1 && yy <= 64 && xx >= 1 && xx <= 64)
          v = bufKV[(size_t)(256 + ch) * 16384 + b * 4096 + (yy - 1) * 64 + (xx - 1)] * sc + sh;
        else
          v = sh;
      }
      v8[j] = f2h(v);
    }
    *(u16x8*)&vP[((size_t)b * 256 + ch) * 4480 + kt0] = v8;
  }
}

// ---- 8) fused flash attention, 2-deep pipelined, PV split by CHANNELS ----
// (identical to R18/R19/R20 — 125-127us, VGPR 128, 0 conflicts)
__global__ __launch_bounds__(256, 2) void k_flash(
    const u16* __restrict__ qTs, const u16* __restrict__ kTs,
    const u16* __restrict__ vP, float* __restrict__ Op,
    float* __restrict__ ml) {
  __shared__ u16 lS[2][16384];  // 2 x 32KB staging (K-half or V-chunk)
  __shared__ u16 lP[64 * 64];   // 8KB P half-tile (64 qt x 64 kt), swizzled
  __shared__ float lFac[64];    // per-qt-row rescale factor broadcast
  const int lin = blockIdx.x;
  const int xcd = lin & 7, per = lin >> 3;
  const int h = xcd & 1, b = xcd >> 1;
  const int qt0 = per * 64;
  const int tid = threadIdx.x, wave = tid >> 6, lane = tid & 63;
  const int sr = lane >> 3, scw = (lane & 7) ^ sr;
  const int r16 = lane & 15, q = lane >> 4;

  // Q fragments in registers: aq[kk] = Q[qt0+wave*16+r16][kk*32 + q*8 ..+7]
  const u16* gQ = qTs + ((size_t)b * 4096 + qt0 + wave * 16 + r16) * 256;
  f16x8 aq[8];
#pragma unroll
  for (int kk = 0; kk < 8; kk++) aq[kk] = *(const f16x8*)&gQ[kk * 32 + q * 8];
  // drain Q loads so in-loop vmcnt counting is exact (one-time cost)
  asm volatile("s_waitcnt vmcnt(0)" ::: "memory");

  const u16* gK = kTs + (size_t)b * 4480 * 256 + (size_t)(wave * 32 + sr) * 256 + scw * 8;
  const u16* gV = vP + ((size_t)b * 256 + wave * 64 + sr) * 4480 + scw * 8;

// 8 gld16/thread per stage (32KB/block). K half c2: rows=kt, 2 kcL chunks.
#define STAGE_K(buf, kt, c2)                                                 \
  {                                                                          \
    _Pragma("unroll") for (int i = 0; i < 4; i++) {                          \
      const u16* src = gK + (size_t)((kt) + i * 8) * 256 + (c2) * 128;       \
      gld16(src, &lS[buf][(wave * 32 + i * 8) * 64]);                        \
      gld16(src + 64, &lS[buf][8192 + (wave * 32 + i * 8) * 64]);            \
    }                                                                        \
  }
#define STAGE_V(buf, kt, vc)                                                 \
  {                                                                          \
    _Pragma("unroll") for (int i = 0; i < 8; i++)                            \
        gld16(gV + (size_t)(i * 8) * 4480 + (kt) + (vc) * 64,                \
              &lS[buf][(wave * 64 + i * 8) * 64]);                           \
  }
#define WAITB(n)                                                             \
  asm volatile("s_waitcnt vmcnt(" #n ") lgkmcnt(0)" ::: "memory");           \
  __builtin_amdgcn_s_barrier();                                              \
  __builtin_amdgcn_sched_barrier(0);
#define CLOSEB()                                                             \
  __builtin_amdgcn_sched_barrier(0);                                         \
  asm volatile("s_waitcnt lgkmcnt(0)" ::: "memory");                         \
  __builtin_amdgcn_s_barrier();

  // acc_o[mt][fj]: qt-tile mt (rows mt*16+q*4+rr), c-tile fj (wave*64+fj*16+r16)
  f32x4 acc_o[4][4];
#pragma unroll
  for (int mt = 0; mt < 4; mt++)
#pragma unroll
    for (int fj = 0; fj < 4; fj++) acc_o[mt][fj] = (f32x4){0.f, 0.f, 0.f, 0.f};
  f32x4 m_v = {-3e38f, -3e38f, -3e38f, -3e38f};
  f32x4 l_v = {0.f, 0.f, 0.f, 0.f};

  const int ktBeg = h ? 2304 : 0, ktEnd = h ? 4480 : 2304;
  STAGE_K(0, ktBeg, 0);  // prologue: phase A of first tile
  for (int kt0 = ktBeg; kt0 < ktEnd; kt0 += 128) {
    f32x4 acc_s[8];
#pragma unroll
    for (int i = 0; i < 8; i++) acc_s[i] = (f32x4){0.f, 0.f, 0.f, 0.f};
    // ---- phase A: S (c 0..127) from buf0; prefetch B ----
    STAGE_K(1, kt0, 1);
    WAITB(8);
    __builtin_amdgcn_s_setprio(1);
#pragma unroll
    for (int kcL = 0; kcL < 2; kcL++)
#pragma unroll
      for (int ks = 0; ks < 64; ks += 32)
#pragma unroll
        for (int fj = 0; fj < 8; fj++) {
          int nb = fj * 16 + r16;
          int g = (ks >> 3) + q;
          f16x8 bf = *(const f16x8*)&lS[0][kcL * 8192 + nb * 64 + ((g ^ (nb & 7)) << 3)];
          acc_s[fj] = __builtin_amdgcn_mfma_f32_16x16x32_f16(
              aq[kcL * 2 + (ks >> 5)], bf, acc_s[fj], 0, 0, 0);
        }
    __builtin_amdgcn_s_setprio(0);
    CLOSEB();
    // ---- phase B: S (c 128..255) from buf1; prefetch C (V kt-chunk 0) ----
    STAGE_V(0, kt0, 0);
    WAITB(8);
    __builtin_amdgcn_s_setprio(1);
#pragma unroll
    for (int kcL = 0; kcL < 2; kcL++)
#pragma unroll
      for (int ks = 0; ks < 64; ks += 32)
#pragma unroll
        for (int fj = 0; fj < 8; fj++) {
          int nb = fj * 16 + r16;
          int g = (ks >> 3) + q;
          f16x8 bf = *(const f16x8*)&lS[1][kcL * 8192 + nb * 64 + ((g ^ (nb & 7)) << 3)];
          acc_s[fj] = __builtin_amdgcn_mfma_f32_16x16x32_f16(
              aq[4 + kcL * 2 + (ks >> 5)], bf, acc_s[fj], 0, 0, 0);
        }
    __builtin_amdgcn_s_setprio(0);
    CLOSEB();
    // ---- prefetch D (V kt-chunk 1) so it flies under the softmax VALU ----
    STAGE_V(1, kt0, 1);
    // ---- mask pad keys (only last tile; kTs pad rows are zeros, no NaN) ----
    if (kt0 + 128 > 4356) {
#pragma unroll
      for (int fj = 0; fj < 8; fj++)
        if (kt0 + fj * 16 + r16 >= 4356)
          acc_s[fj] = (f32x4){-1e30f, -1e30f, -1e30f, -1e30f};
    }
    // ---- online softmax; lane owns rows q*4+rr of wave's 16-qt strip ----
    f32x4 pm = acc_s[0];
#pragma unroll
    for (int fj = 1; fj < 8; fj++)
#pragma unroll
      for (int rr = 0; rr < 4; rr++) pm[rr] = fmaxf(pm[rr], acc_s[fj][rr]);
#pragma unroll
    for (int d = 1; d < 16; d <<= 1)
#pragma unroll
      for (int rr = 0; rr < 4; rr++)
        pm[rr] = fmaxf(pm[rr], __shfl_xor(pm[rr], d));
    // T13 defer-max: keep m while tile max grows <= 8; fac = 1.0 exactly then.
    int need = !__all(pm[0] - m_v[0] <= 8.f && pm[1] - m_v[1] <= 8.f &&
                      pm[2] - m_v[2] <= 8.f && pm[3] - m_v[3] <= 8.f);
    f32x4 fac = {1.f, 1.f, 1.f, 1.f};
    if (need) {
#pragma unroll
      for (int rr = 0; rr < 4; rr++) {
        float mn = fmaxf(m_v[rr], pm[rr]);
        fac[rr] = __expf(m_v[rr] - mn);
        m_v[rr] = mn;
        l_v[rr] *= fac[rr];
      }
    }
    if (r16 == 0) *(f32x4*)&lFac[wave * 16 + q * 4] = fac;  // broadcast
    // hp: fj<4 -> lP (kt 0..63); fj>=4 kept in hq regs, written pre-D.
    _Float16 hq[4][4];
    f32x4 rs = {0.f, 0.f, 0.f, 0.f};
#pragma unroll
    for (int fj = 0; fj < 8; fj++)
#pragma unroll
      for (int rr = 0; rr < 4; rr++) {
        _Float16 hp = (_Float16)__expf(acc_s[fj][rr] - m_v[rr]);
        rs[rr] += (float)hp;  // denominator sums the rounded p (consistency)
        int row = wave * 16 + q * 4 + rr;
        if (fj < 4) {
          int c8 = fj * 2 + (r16 >> 3);
          lP[row * 64 + (((c8 ^ (row & 7)) << 3) | (r16 & 7))] = *(const u16*)&hp;
        } else {
          hq[fj - 4][rr] = hp;
        }
      }
#pragma unroll
    for (int d = 1; d < 16; d <<= 1)
#pragma unroll
      for (int rr = 0; rr < 4; rr++) rs[rr] += __shfl_xor(rs[rr], d);
#pragma unroll
    for (int rr = 0; rr < 4; rr++) l_v[rr] += rs[rr];
    // ---- phase C: PV kt 0..63 from buf0; wave owns c [64w, 64w+64) ----
    WAITB(8);  // V0 ready; P(fj<4) + lFac visible (lgkm drained)
    f32x4 facv[4];
#pragma unroll
    for (int mt = 0; mt < 4; mt++)
      facv[mt] = *(const f32x4*)&lFac[mt * 16 + q * 4];
#pragma unroll
    for (int mt = 0; mt < 4; mt++)
#pragma unroll
      for (int fj = 0; fj < 4; fj++)
#pragma unroll
        for (int rr = 0; rr < 4; rr++) acc_o[mt][fj][rr] *= facv[mt][rr];
    __builtin_amdgcn_s_setprio(1);
#pragma unroll
    for (int ks = 0; ks < 64; ks += 32) {
      int k8 = (ks >> 3) + q;
      f16x8 ap[4];
#pragma unroll
      for (int mt = 0; mt < 4; mt++)
        ap[mt] = *(const f16x8*)&lP[(mt * 16 + r16) * 64 + ((k8 ^ (r16 & 7)) << 3)];
#pragma unroll
      for (int fj = 0; fj < 4; fj++) {
        int cr = wave * 64 + fj * 16 + r16;
        f16x8 bv = *(const f16x8*)&lS[0][cr * 64 + ((k8 ^ (cr & 7)) << 3)];
#pragma unroll
        for (int mt = 0; mt < 4; mt++)
          acc_o[mt][fj] = __builtin_amdgcn_mfma_f32_16x16x32_f16(
              ap[mt], bv, acc_o[mt][fj], 0, 0, 0);
      }
    }
    __builtin_amdgcn_s_setprio(0);
    CLOSEB();  // all C-phase lP/lS reads done before refill
    // ---- refill lP with kt 64..127 (hq), prefetch next tile's A ----
#pragma unroll
    for (int fj = 0; fj < 4; fj++)
#pragma unroll
      for (int rr = 0; rr < 4; rr++) {
        int row = wave * 16 + q * 4 + rr;
        int c8 = fj * 2 + (r16 >> 3);
        lP[row * 64 + (((c8 ^ (row & 7)) << 3) | (r16 & 7))] =
            *(const u16*)&hq[fj][rr];
      }
    if (kt0 + 128 < ktEnd) {
      STAGE_K(0, kt0 + 128, 0);
      WAITB(8);  // V1 ready; refilled P visible
    } else {
      WAITB(0);
    }
    __builtin_amdgcn_s_setprio(1);
#pragma unroll
    for (int ks = 0; ks < 64; ks += 32) {
      int k8 = (ks >> 3) + q;
      f16x8 ap[4];
#pragma unroll
      for (int mt = 0; mt < 4; mt++)
        ap[mt] = *(const f16x8*)&lP[(mt * 16 + r16) * 64 + ((k8 ^ (r16 & 7)) << 3)];
#pragma unroll
      for (int fj = 0; fj < 4; fj++) {
        int cr = wave * 64 + fj * 16 + r16;
        f16x8 bv = *(const f16x8*)&lS[1][cr * 64 + ((k8 ^ (cr & 7)) << 3)];
#pragma unroll
        for (int mt = 0; mt < 4; mt++)
          acc_o[mt][fj] = __builtin_amdgcn_mfma_f32_16x16x32_f16(
              ap[mt], bv, acc_o[mt][fj], 0, 0, 0);
      }
    }
    __builtin_amdgcn_s_setprio(0);
    CLOSEB();  // D-phase lP reads done before next tile's softmax writes
  }
#undef STAGE_K
#undef STAGE_V
#undef WAITB
#undef CLOSEB
  // ---- store partials: wave's c-slice for all 64 qt ----
  size_t obase = ((size_t)(h * 4 + b) * 4096 + qt0) * 256;
#pragma unroll
  for (int mt = 0; mt < 4; mt++)
#pragma unroll
    for (int rr = 0; rr < 4; rr++) {
      size_t rowo = obase + (size_t)(mt * 16 + q * 4 + rr) * 256;
#pragma unroll
      for (int fj = 0; fj < 4; fj++)
        Op[rowo + wave * 64 + fj * 16 + r16] = acc_o[mt][fj][rr];
    }
  if (r16 == 0) {
    int base = (h * 4 + b) * 4096 + qt0 + wave * 16 + q * 4;
    *(f32x4*)&ml[base] = m_v;
    *(f32x4*)&ml[32768 + base] = l_v;
  }
}

// ---- 9) merge two kt-half partials, divide, transpose to out[b][c][qt] ----
__global__ __launch_bounds__(256) void k_merge(const float* __restrict__ Op,
                                               const float* __restrict__ ml,
                                               const int* __restrict__ flag,
                                               void* __restrict__ out) {
  __shared__ float th[32][33];
  int b = blockIdx.z, qt0 = blockIdx.x * 32, c0 = blockIdx.y * 32;
  int tx = threadIdx.x, ty = threadIdx.y;
#pragma unroll
  for (int i = 0; i < 4; i++) {
    int qt = qt0 + ty + i * 8;
    float m0 = ml[b * 4096 + qt], m1 = ml[(4 + b) * 4096 + qt];
    float l0 = ml[32768 + b * 4096 + qt], l1 = ml[32768 + (4 + b) * 4096 + qt];
    float M = fmaxf(m0, m1);
    float e0 = __expf(m0 - M), e1 = __expf(m1 - M);
    float inv = 1.f / (l0 * e0 + l1 * e1);  // >= 1, safe
    float v = (Op[((size_t)b * 4096 + qt) * 256 + c0 + tx] * e0 +
               Op[((size_t)(4 + b) * 4096 + qt) * 256 + c0 + tx] * e1) * inv;
    v = (v == v) ? v : 0.f;  // NaN scrub: keep failures diagnostic
    th[ty + i * 8][tx] = v;
  }
  __syncthreads();
#pragma unroll
  for (int i = 0; i < 4; i++) {
    int c = c0 + ty + i * 8, qt = qt0 + tx;
    float v = th[tx][ty + i * 8];
    size_t oidx = ((size_t)b * 256 + c) * 4096 + qt;
    if (flag[0])
      ((float*)out)[oidx] = v;
    else
      ((u16*)out)[oidx] = f2bf(v);
  }
}

// ---------------------------------------------------------------------------
extern "C" void kernel_launch(void* const* d_in, const int* in_sizes, int n_in,
                              void* d_out, int out_size, void* d_ws, size_t ws_size,
                              hipStream_t stream) {
  const void* x = d_in[0];
  const void* Wq = d_in[1];
  const void* gq = d_in[3];
  const void* betaq = d_in[4];
  const void* Wk = d_in[5];
  const void* gk = d_in[7];
  const void* betak = d_in[8];
  const void* Wv = d_in[9];
  const void* gv = d_in[11];
  const void* betav = d_in[12];

  char* ws = (char*)d_ws;
  int* flag = (int*)ws;  // 256 B
  // Region A (conv phase; dead once qTs/kTs/vP built -> overlaid by Opart/ml):
  u16* xbTp = (u16*)(ws + 256);            //  8,921,088
  u16* WqB = (u16*)(ws + 8921344);         //  1,179,648
  u16* WkvB = (u16*)(ws + 10100992);       //    262,144
  float* bufQ = (float*)(ws + 10363136);   // 16,777,216
  float* bufKV = (float*)(ws + 27140352);  // 33,554,432 -> A ends 60,694,784
  u16* qTs = (u16*)(ws + 60694784);        //  8,388,608 (4*4096*256*2)
  u16* kTs = (u16*)(ws + 69083392);        //  9,175,040 (4*4480*256*2)
  u16* vP = (u16*)(ws + 78258432);         //  9,175,040
  float* nrm = (float*)(ws + 87433472);    //      6,144 -> total 87,439,616 B
  // Overlay region A (dead by flash time):
  float* Opart = (float*)(ws + 256);       // 33,554,432 (2*4*4096*256*4)
  float* mlbuf = (float*)(ws + 33554688);  //    262,144 (m: 32768 f, l: 32768 f)

  k_detect<<<1, 256, 0, stream>>>((const unsigned*)Wq, flag);
  // fused prep: txp (4384) | wq+bufQ-zero (2304) | wkv (512) = 7200 blocks
  k_prep<<<7200, 256, 0, stream>>>(x, Wq, Wk, Wv, flag, xbTp, WqB, WkvB, bufQ);
  // fused convs: [0,768) conv3x3 splitK x3 into zeroed bufQ; [768,1280) 1x1.
  k_convs<<<1280, 256, 0, stream>>>(WqB, WkvB, xbTp, bufQ, bufKV);
  k_stats<<<dim3(256, 3), 256, 0, stream>>>(bufQ, bufKV, gq, betaq, gk, betak,
                                            gv, betav, flag, nrm);
  // fused normalize: qTs (4096) | kTs (4480) | vP x8-vec (2240) = 10816 blocks
  k_norm<<<10816, 256, 0, stream>>>(bufQ, bufKV, nrm, qTs, kTs, vP);
  // fused attention: 512 blocks = 8 XCD-combos x 64 qt tiles, 2 blocks/CU
  k_flash<<<512, 256, 0, stream>>>(qTs, kTs, vP, Opart, mlbuf);
  k_merge<<<dim3(128, 8, 4), dim3(32, 8), 0, stream>>>(Opart, mlbuf, flag,
                                                       d_out);
}